// Round 4
// baseline (6993.593 us; speedup 1.0000x reference)
//
#include <hip/hip_runtime.h>
#include <hip/hip_bf16.h>

// Problem constants
constexpr int N_  = 50000;
constexpr int E_  = 800000;
constexpr int E2_ = 850000;   // E + N self loops
constexpr int FIN = 128;
constexpr int FH  = 256;      // H * C = 4 * 64
constexpr float BN_EPS = 1e-5f;
constexpr float NEG_ATT = 0.2f;
constexpr float NEG_OUT = 0.1f;
constexpr size_t OUT0 = (size_t)N_ * FH;   // 12.8M feature elems (fp32)
constexpr size_t OUT1 = (size_t)2 * E_;    // 1.6M edge elems (fp32)

static inline int cdiv(int a, int b){ return (a + b - 1) / b; }

// monotone float<->uint encoding for atomicMax-based segment max
__device__ inline unsigned fenc(float f){
    unsigned u = __float_as_uint(f);
    return (u & 0x80000000u) ? ~u : (u | 0x80000000u);
}
__device__ inline float fdec(unsigned e){
    unsigned u = (e & 0x80000000u) ? (e & 0x7fffffffu) : ~e;
    return __uint_as_float(u);
}
__device__ inline float lrelu(float v, float ns){ return v > 0.f ? v : ns * v; }

__global__ void k_sentinel(float* out, float v){ out[0] = v; }

__global__ void k_zero32(unsigned* p, int n){
    int i = blockIdx.x * blockDim.x + threadIdx.x;
    if (i < n) p[i] = 0u;
}

// ---------- BatchNorm ----------
__global__ void k_bn_stats(const float* __restrict__ x, int F,
                           float* __restrict__ sum, float* __restrict__ sumsq){
    int gid = blockIdx.x * blockDim.x + threadIdx.x;
    int T = gridDim.x * blockDim.x;      // 65536, divisible by 128 and 256
    int c = gid % F;
    int r0 = gid / F;
    int rstep = T / F;
    float s = 0.f, s2 = 0.f;
    for (int r = r0; r < N_; r += rstep){
        float v = x[(size_t)r * F + c];
        s += v; s2 += v * v;
    }
    atomicAdd(&sum[c], s);
    atomicAdd(&sumsq[c], s2);
}

__global__ void k_bn_apply(const float* __restrict__ x, const float* __restrict__ sum,
                           const float* __restrict__ sumsq, const float* __restrict__ gamma,
                           const float* __restrict__ beta, float* __restrict__ out, int F){
    size_t tot = (size_t)N_ * F;
    size_t step = (size_t)gridDim.x * blockDim.x;
    for (size_t i = blockIdx.x * (size_t)blockDim.x + threadIdx.x; i < tot; i += step){
        int c = (int)(i % F);
        float mean = sum[c] / (float)N_;
        float var = sumsq[c] / (float)N_ - mean * mean;
        float v = (x[i] - mean) * rsqrtf(var + BN_EPS) * gamma[c] + beta[c];
        out[i] = lrelu(v, NEG_OUT);
    }
}

// ---------- naive row-per-block GEMM: C[n][0..255] = A[n][:] @ B ----------
__global__ __launch_bounds__(256) void k_gemm_row(const float* __restrict__ A,
                                                  const float* __restrict__ B,
                                                  float* __restrict__ C, int K){
    int n = blockIdx.x;
    int f = threadIdx.x;
    const float* a = A + (size_t)n * K;
    float s = 0.f;
    for (int k = 0; k < K; k += 4){
        float a0 = a[k], a1 = a[k+1], a2 = a[k+2], a3 = a[k+3];
        s += a0 * B[(size_t)(k+0) * 256 + f];
        s += a1 * B[(size_t)(k+1) * 256 + f];
        s += a2 * B[(size_t)(k+2) * 256 + f];
        s += a3 * B[(size_t)(k+3) * 256 + f];
    }
    C[(size_t)n * 256 + f] = s;
}

// ---------- per-node attention terms ----------
__global__ void k_al(const float* __restrict__ h, const float* __restrict__ asrc,
                     const float* __restrict__ adst,
                     float* __restrict__ als, float* __restrict__ ald){
    int idx = blockIdx.x * blockDim.x + threadIdx.x;  // N*4
    if (idx >= N_ * 4) return;
    int n = idx >> 2, hd = idx & 3;
    const float* hp = h + (size_t)n * 256 + hd * 64;
    const float* ap = asrc + hd * 64;
    const float* dp = adst + hd * 64;
    float s = 0.f, d = 0.f;
    for (int c = 0; c < 64; ++c){
        float v = hp[c];
        s += v * ap[c];
        d += v * dp[c];
    }
    als[idx] = s;
    ald[idx] = d;
}

// ---------- edge_attr column sums ----------
__global__ void k_attr_sum(const float* __restrict__ ea, float* __restrict__ asum){
    int gid = blockIdx.x * blockDim.x + threadIdx.x;
    int c = gid & 15;
    int r0 = gid >> 4;
    int rstep = (gridDim.x * blockDim.x) >> 4;   // 1024
    float s = 0.f;
    for (int r = r0; r < E_; r += rstep) s += ea[(size_t)r * 16 + c];
    atomicAdd(&asum[c], s);
}

// ---------- V[k][h] = sum_c We[k][h*64+c]*aedge[h][c]; alloop[h] = mean_attr . V[:,h] ----------
__global__ void k_prep(const float* __restrict__ We, const float* __restrict__ aedge,
                       const float* __restrict__ asum, float* __restrict__ V,
                       float* __restrict__ alloop){
    __shared__ float Vs[64];
    int t = threadIdx.x;  // 64 threads
    int k = t >> 2, hd = t & 3;
    float s = 0.f;
    for (int c = 0; c < 64; ++c) s += We[k * 256 + hd * 64 + c] * aedge[hd * 64 + c];
    Vs[t] = s;
    V[t] = s;
    __syncthreads();
    if (t < 4){
        float r = 0.f;
        for (int kk = 0; kk < 16; ++kk) r += (asum[kk] / (float)E_) * Vs[kk * 4 + t];
        alloop[t] = r;
    }
}

// ---------- al_edge for real edges: lg[e*4+h] = eattr[e] . V[:,h] ----------
__global__ void k_al_edge(const float* __restrict__ ea, const float* __restrict__ V,
                          float* __restrict__ lg){
    int idx = blockIdx.x * blockDim.x + threadIdx.x;   // E*4
    if (idx >= E_ * 4) return;
    int e = idx >> 2, hd = idx & 3;
    const float* ep = ea + (size_t)e * 16;
    float s = 0.f;
    #pragma unroll
    for (int k = 0; k < 16; ++k) s += ep[k] * V[k * 4 + hd];
    lg[idx] = s;
}

// ---------- pass 1: full logits (in-place over lg) + segment max ----------
__global__ void k_logit_max(const int* __restrict__ ei, const float* __restrict__ als,
                            const float* __restrict__ ald, const float* __restrict__ alloop,
                            float* __restrict__ lg, unsigned* __restrict__ mx){
    int idx = blockIdx.x * blockDim.x + threadIdx.x;   // E2*4
    if (idx >= E2_ * 4) return;
    int e = idx >> 2, hd = idx & 3;
    int s, d; float alE;
    if (e < E_){ s = ei[e]; d = ei[E_ + e]; alE = lg[idx]; }
    else       { s = e - E_; d = s;         alE = alloop[hd]; }
    float v = als[s * 4 + hd] + ald[d * 4 + hd] + alE;
    v = lrelu(v, NEG_ATT);
    lg[idx] = v;
    atomicMax(&mx[d * 4 + hd], fenc(v));
}

// ---------- pass 2: exp-sum per (dst, head) ----------
__global__ void k_exp_sum(const int* __restrict__ ei, const float* __restrict__ lg,
                          const unsigned* __restrict__ mx, float* __restrict__ den){
    int idx = blockIdx.x * blockDim.x + threadIdx.x;   // E2*4
    if (idx >= E2_ * 4) return;
    int e = idx >> 2, hd = idx & 3;
    int d = (e < E_) ? ei[E_ + e] : (e - E_);
    float p = expf(lg[idx] - fdec(mx[d * 4 + hd]));
    atomicAdd(&den[d * 4 + hd], p);
}

// ---------- pass 3: unnormalized message accumulation ----------
__global__ void k_msg(const int* __restrict__ ei, const float* __restrict__ lg,
                      const unsigned* __restrict__ mx, const float* __restrict__ h,
                      float* __restrict__ acc){
    size_t idx = blockIdx.x * (size_t)blockDim.x + threadIdx.x;   // E2*64
    if (idx >= (size_t)E2_ * 64) return;
    int e = (int)(idx >> 6);
    int f4 = (int)(idx & 63);
    int hd = f4 >> 4;
    int s, d;
    if (e < E_){ s = ei[e]; d = ei[E_ + e]; }
    else       { s = e - E_; d = s; }
    float w = expf(lg[(size_t)e * 4 + hd] - fdec(mx[d * 4 + hd]));
    float4 hv = *reinterpret_cast<const float4*>(h + (size_t)s * 256 + f4 * 4);
    float* ap = acc + (size_t)d * 256 + f4 * 4;
    atomicAdd(ap + 0, w * hv.x);
    atomicAdd(ap + 1, w * hv.y);
    atomicAdd(ap + 2, w * hv.z);
    atomicAdd(ap + 3, w * hv.w);
}

// ---------- finalize layer 1 (in place): acc = lrelu(acc/den + b) ----------
__global__ void k_finalize(float* __restrict__ acc, const float* __restrict__ den,
                           const float* __restrict__ bias){
    int idx = blockIdx.x * blockDim.x + threadIdx.x;   // N*256
    if (idx >= N_ * 256) return;
    int n = idx >> 8, f = idx & 255, hd = f >> 6;
    float v = acc[idx] / den[n * 4 + hd] + bias[f];
    acc[idx] = lrelu(v, NEG_OUT);
}

// ---------- finalize layer 2 straight to fp32 output ----------
__global__ void k_final_store(const float* __restrict__ acc, const float* __restrict__ den,
                              const float* __restrict__ bias, float* __restrict__ out){
    int idx = blockIdx.x * blockDim.x + threadIdx.x;   // N*256
    if (idx >= N_ * 256) return;
    int n = idx >> 8, f = idx & 255, hd = f >> 6;
    float v = acc[idx] / den[n * 4 + hd] + bias[f];
    out[idx] = lrelu(v, NEG_OUT);
}

// ---------- edge_index passthrough (fp32, bit-exact) ----------
__global__ void k_edge_store(const int* __restrict__ ei, float* __restrict__ out){
    int j = blockIdx.x * blockDim.x + threadIdx.x;     // 2E
    if (j >= (int)OUT1) return;
    out[j] = (float)ei[j];
}

extern "C" void kernel_launch(void* const* d_in, const int* in_sizes, int n_in,
                              void* d_out, int out_size, void* d_ws, size_t ws_size,
                              hipStream_t stream){
    const float* x    = (const float*)d_in[0];
    const int*   ei   = (const int*)d_in[1];
    const float* ea   = (const float*)d_in[2];
    const float* bn1g = (const float*)d_in[3];
    const float* bn1b = (const float*)d_in[4];
    const float* W1   = (const float*)d_in[5];
    const float* We1  = (const float*)d_in[6];
    const float* as1  = (const float*)d_in[7];
    const float* ad1  = (const float*)d_in[8];
    const float* ae1  = (const float*)d_in[9];
    const float* b1   = (const float*)d_in[10];
    const float* bn2g = (const float*)d_in[11];
    const float* bn2b = (const float*)d_in[12];
    const float* W2   = (const float*)d_in[13];
    const float* We2  = (const float*)d_in[14];
    const float* as2  = (const float*)d_in[15];
    const float* ad2  = (const float*)d_in[16];
    const float* ae2  = (const float*)d_in[17];
    const float* b2   = (const float*)d_in[18];
    float* out = (float*)d_out;

    // ---- runtime guards with distinct sentinels ----
    bool ok = (n_in >= 19)
           && (in_sizes[0] == N_ * FIN)
           && (in_sizes[1] == 2 * E_)
           && (in_sizes[2] == E_ * 16)
           && (out_size == (int)(OUT0 + OUT1));
    if (!ok){ k_sentinel<<<1,1,0,stream>>>(out, 7777.f); return; }

    char* w = (char*)d_ws;
    size_t off = 0;
    auto alloc = [&](size_t bytes) -> void* {
        off = (off + 255) & ~(size_t)255;
        void* p = w + off;
        off += bytes;
        return p;
    };
    float*    stats  = (float*)alloc(512 * 4);          // sum[256], sumsq[256]
    float*    asum   = (float*)alloc(16 * 4);
    float*    Vbuf   = (float*)alloc(64 * 4);
    float*    alloop = (float*)alloc(4 * 4);
    float*    als    = (float*)alloc((size_t)N_ * 4 * 4);
    float*    ald    = (float*)alloc((size_t)N_ * 4 * 4);
    float*    lg     = (float*)alloc((size_t)E2_ * 4 * 4);   // 13.6MB
    unsigned* mx     = (unsigned*)alloc((size_t)N_ * 4 * 4);
    float*    den    = (float*)alloc((size_t)N_ * 4 * 4);
    float*    acc    = (float*)alloc((size_t)N_ * 256 * 4);  // 51.2MB
    float*    bufC   = (float*)alloc((size_t)N_ * 128 * 4);  // 25.6MB
    float*    hbuf   = (float*)alloc((size_t)N_ * 256 * 4);  // 51.2MB
    float*    bufB   = (float*)alloc((size_t)N_ * 256 * 4);  // 51.2MB
    if (off > ws_size){ k_sentinel<<<1,1,0,stream>>>(out, 5555.f); return; }

    float* ssum = stats;
    float* ssq  = stats + 256;
    const int NA = N_ * 4;          // 200000
    const int EA = E2_ * 4;         // 3400000
    const int NF = N_ * 256;        // 12800000

    // shared precompute
    k_zero32<<<2,256,0,stream>>>((unsigned*)stats, 512);
    k_zero32<<<1,64,0,stream>>>((unsigned*)asum, 16);
    k_attr_sum<<<64,256,0,stream>>>(ea, asum);

    // BN1 + lrelu
    k_bn_stats<<<256,256,0,stream>>>(x, FIN, ssum, ssq);
    k_bn_apply<<<2048,256,0,stream>>>(x, ssum, ssq, bn1g, bn1b, bufC, FIN);

    // ---- GAT layer 1 ----
    k_gemm_row<<<N_,256,0,stream>>>(bufC, W1, hbuf, FIN);
    k_al<<<cdiv(NA,256),256,0,stream>>>(hbuf, as1, ad1, als, ald);
    k_prep<<<1,64,0,stream>>>(We1, ae1, asum, Vbuf, alloop);
    k_al_edge<<<cdiv(E_*4,256),256,0,stream>>>(ea, Vbuf, lg);
    k_zero32<<<cdiv(NA,256),256,0,stream>>>(mx, NA);
    k_zero32<<<cdiv(NA,256),256,0,stream>>>((unsigned*)den, NA);
    k_zero32<<<cdiv(NF,256),256,0,stream>>>((unsigned*)acc, NF);
    k_logit_max<<<cdiv(EA,256),256,0,stream>>>(ei, als, ald, alloop, lg, mx);
    k_exp_sum<<<cdiv(EA,256),256,0,stream>>>(ei, lg, mx, den);
    {
        size_t tot = (size_t)E2_ * 64;
        k_msg<<<(int)((tot + 255) / 256),256,0,stream>>>(ei, lg, mx, hbuf, acc);
    }
    k_finalize<<<cdiv(NF,256),256,0,stream>>>(acc, den, b1);

    // BN2 + lrelu
    k_zero32<<<2,256,0,stream>>>((unsigned*)stats, 512);
    k_bn_stats<<<256,256,0,stream>>>(acc, FH, ssum, ssq);
    k_bn_apply<<<2048,256,0,stream>>>(acc, ssum, ssq, bn2g, bn2b, bufB, FH);

    // ---- GAT layer 2 ----
    k_gemm_row<<<N_,256,0,stream>>>(bufB, W2, hbuf, FH);
    k_al<<<cdiv(NA,256),256,0,stream>>>(hbuf, as2, ad2, als, ald);
    k_prep<<<1,64,0,stream>>>(We2, ae2, asum, Vbuf, alloop);
    k_al_edge<<<cdiv(E_*4,256),256,0,stream>>>(ea, Vbuf, lg);
    k_zero32<<<cdiv(NA,256),256,0,stream>>>(mx, NA);
    k_zero32<<<cdiv(NA,256),256,0,stream>>>((unsigned*)den, NA);
    k_zero32<<<cdiv(NF,256),256,0,stream>>>((unsigned*)acc, NF);
    k_logit_max<<<cdiv(EA,256),256,0,stream>>>(ei, als, ald, alloop, lg, mx);
    k_exp_sum<<<cdiv(EA,256),256,0,stream>>>(ei, lg, mx, den);
    {
        size_t tot = (size_t)E2_ * 64;
        k_msg<<<(int)((tot + 255) / 256),256,0,stream>>>(ei, lg, mx, hbuf, acc);
    }

    // final stores
    k_final_store<<<cdiv(NF,256),256,0,stream>>>(acc, den, b2, out);
    k_edge_store<<<cdiv((int)OUT1,256),256,0,stream>>>(ei, out + OUT0);
}

// Round 5
// 1589.565 us; speedup vs baseline: 4.3997x; 4.3997x over previous
//
#include <hip/hip_runtime.h>
#include <hip/hip_bf16.h>

// Problem constants
constexpr int N_  = 50000;
constexpr int E_  = 800000;
constexpr int E2_ = 850000;   // E + N self loops
constexpr int FIN = 128;
constexpr int FH  = 256;      // H * C = 4 * 64
constexpr float BN_EPS = 1e-5f;
constexpr float NEG_ATT = 0.2f;
constexpr float NEG_OUT = 0.1f;
constexpr size_t OUT0 = (size_t)N_ * FH;   // 12.8M feature elems (fp32)
constexpr size_t OUT1 = (size_t)2 * E_;    // 1.6M edge elems (fp32)

static inline int cdiv(int a, int b){ return (a + b - 1) / b; }

__device__ inline float lrelu(float v, float ns){ return v > 0.f ? v : ns * v; }

__global__ void k_sentinel(float* out, float v){ out[0] = v; }

__global__ void k_zero32(unsigned* p, int n){
    int i = blockIdx.x * blockDim.x + threadIdx.x;
    if (i < n) p[i] = 0u;
}

// ---------- BatchNorm ----------
__global__ void k_bn_stats(const float* __restrict__ x, int F,
                           float* __restrict__ sum, float* __restrict__ sumsq){
    int gid = blockIdx.x * blockDim.x + threadIdx.x;
    int T = gridDim.x * blockDim.x;      // 65536, divisible by 128 and 256
    int c = gid % F;
    int r0 = gid / F;
    int rstep = T / F;
    float s = 0.f, s2 = 0.f;
    for (int r = r0; r < N_; r += rstep){
        float v = x[(size_t)r * F + c];
        s += v; s2 += v * v;
    }
    atomicAdd(&sum[c], s);
    atomicAdd(&sumsq[c], s2);
}

__global__ void k_bn_apply(const float* __restrict__ x, const float* __restrict__ sum,
                           const float* __restrict__ sumsq, const float* __restrict__ gamma,
                           const float* __restrict__ beta, float* __restrict__ out, int F){
    size_t tot = (size_t)N_ * F;
    size_t step = (size_t)gridDim.x * blockDim.x;
    for (size_t i = blockIdx.x * (size_t)blockDim.x + threadIdx.x; i < tot; i += step){
        int c = (int)(i % F);
        float mean = sum[c] / (float)N_;
        float var = sumsq[c] / (float)N_ - mean * mean;
        float v = (x[i] - mean) * rsqrtf(var + BN_EPS) * gamma[c] + beta[c];
        out[i] = lrelu(v, NEG_OUT);
    }
}

// ---------- naive row-per-block GEMM: C[n][0..255] = A[n][:] @ B ----------
__global__ __launch_bounds__(256) void k_gemm_row(const float* __restrict__ A,
                                                  const float* __restrict__ B,
                                                  float* __restrict__ C, int K){
    int n = blockIdx.x;
    int f = threadIdx.x;
    const float* a = A + (size_t)n * K;
    float s = 0.f;
    for (int k = 0; k < K; k += 4){
        float a0 = a[k], a1 = a[k+1], a2 = a[k+2], a3 = a[k+3];
        s += a0 * B[(size_t)(k+0) * 256 + f];
        s += a1 * B[(size_t)(k+1) * 256 + f];
        s += a2 * B[(size_t)(k+2) * 256 + f];
        s += a3 * B[(size_t)(k+3) * 256 + f];
    }
    C[(size_t)n * 256 + f] = s;
}

// ---------- per-node attention terms ----------
__global__ void k_al(const float* __restrict__ h, const float* __restrict__ asrc,
                     const float* __restrict__ adst,
                     float* __restrict__ als, float* __restrict__ ald){
    int idx = blockIdx.x * blockDim.x + threadIdx.x;  // N*4
    if (idx >= N_ * 4) return;
    int n = idx >> 2, hd = idx & 3;
    const float* hp = h + (size_t)n * 256 + hd * 64;
    const float* ap = asrc + hd * 64;
    const float* dp = adst + hd * 64;
    float s = 0.f, d = 0.f;
    for (int c = 0; c < 64; ++c){
        float v = hp[c];
        s += v * ap[c];
        d += v * dp[c];
    }
    als[idx] = s;
    ald[idx] = d;
}

// ---------- edge_attr column sums ----------
__global__ void k_attr_sum(const float* __restrict__ ea, float* __restrict__ asum){
    int gid = blockIdx.x * blockDim.x + threadIdx.x;
    int c = gid & 15;
    int r0 = gid >> 4;
    int rstep = (gridDim.x * blockDim.x) >> 4;   // 1024
    float s = 0.f;
    for (int r = r0; r < E_; r += rstep) s += ea[(size_t)r * 16 + c];
    atomicAdd(&asum[c], s);
}

// ---------- V[k][h] = sum_c We[k][h*64+c]*aedge[h][c]; alloop[h] = mean_attr . V[:,h] ----------
__global__ void k_prep(const float* __restrict__ We, const float* __restrict__ aedge,
                       const float* __restrict__ asum, float* __restrict__ V,
                       float* __restrict__ alloop){
    __shared__ float Vs[64];
    int t = threadIdx.x;  // 64 threads
    int k = t >> 2, hd = t & 3;
    float s = 0.f;
    for (int c = 0; c < 64; ++c) s += We[k * 256 + hd * 64 + c] * aedge[hd * 64 + c];
    Vs[t] = s;
    V[t] = s;
    __syncthreads();
    if (t < 4){
        float r = 0.f;
        for (int kk = 0; kk < 16; ++kk) r += (asum[kk] / (float)E_) * Vs[kk * 4 + t];
        alloop[t] = r;
    }
}

// ---------- al_edge for real edges: ale[e*4+h] = eattr[e] . V[:,h] ----------
__global__ void k_al_edge(const float* __restrict__ ea, const float* __restrict__ V,
                          float* __restrict__ ale){
    int idx = blockIdx.x * blockDim.x + threadIdx.x;   // E*4
    if (idx >= E_ * 4) return;
    int e = idx >> 2, hd = idx & 3;
    const float* ep = ea + (size_t)e * 16;
    float s = 0.f;
    #pragma unroll
    for (int k = 0; k < 16; ++k) s += ep[k] * V[k * 4 + hd];
    ale[idx] = s;
}

// ---------- CSR build ----------
__global__ void k_count(const int* __restrict__ ei, int* __restrict__ counts){
    int e = blockIdx.x * blockDim.x + threadIdx.x;
    if (e >= E2_) return;
    int d = (e < E_) ? ei[E_ + e] : (e - E_);
    atomicAdd(&counts[d], 1);
}

// single-block exclusive scan of counts[N] -> rs[N+1]
__global__ __launch_bounds__(1024) void k_scan(const int* __restrict__ counts, int* __restrict__ rs){
    __shared__ int sdata[1024];
    int t = threadIdx.x;
    const int CH = (N_ + 1023) / 1024;   // 49
    int base = t * CH;
    int s = 0;
    for (int i = 0; i < CH; ++i){
        int idx = base + i;
        if (idx < N_) s += counts[idx];
    }
    sdata[t] = s;
    __syncthreads();
    for (int off = 1; off < 1024; off <<= 1){
        int v = (t >= off) ? sdata[t - off] : 0;
        __syncthreads();
        sdata[t] += v;
        __syncthreads();
    }
    int run = (t > 0) ? sdata[t - 1] : 0;
    for (int i = 0; i < CH; ++i){
        int idx = base + i;
        if (idx < N_){ rs[idx] = run; run += counts[idx]; }
    }
    if (t == 1023) rs[N_] = E2_;
}

__global__ void k_scatter(const int* __restrict__ ei, const int* __restrict__ rs,
                          int* __restrict__ cursor, int* __restrict__ ssrc, int* __restrict__ seid){
    int e = blockIdx.x * blockDim.x + threadIdx.x;
    if (e >= E2_) return;
    int s, d;
    if (e < E_){ s = ei[e]; d = ei[E_ + e]; }
    else { s = e - E_; d = s; }
    int slot = rs[d] + atomicAdd(&cursor[d], 1);
    ssrc[slot] = s;
    seid[slot] = e;
}

// ---------- one wave per dst node: online softmax + weighted accumulation + bias + lrelu ----------
__global__ __launch_bounds__(256) void k_aggregate(const float* __restrict__ h,
        const float* __restrict__ als, const float* __restrict__ ald,
        const float* __restrict__ ale, const float* __restrict__ alloop,
        const int* __restrict__ rs, const int* __restrict__ ssrc, const int* __restrict__ seid,
        const float* __restrict__ bias, float* __restrict__ outbuf){
    int n = blockIdx.x * 4 + (threadIdx.x >> 6);
    if (n >= N_) return;
    int lane = threadIdx.x & 63;
    int hd = lane >> 4;
    float aldn = ald[(size_t)n * 4 + hd];
    float alp  = alloop[hd];
    int i0 = rs[n], i1 = rs[n + 1];
    float m = -3.0e38f, denom = 0.f;
    float ax = 0.f, ay = 0.f, az = 0.f, aw = 0.f;
    for (int i = i0; i < i1; ++i){
        int s   = ssrc[i];
        int eid = seid[i];
        float alE = (eid < E_) ? ale[(size_t)eid * 4 + hd] : alp;
        float lg = als[(size_t)s * 4 + hd] + aldn + alE;
        lg = lrelu(lg, NEG_ATT);
        float mn = fmaxf(m, lg);
        float sc = __expf(m - mn);
        float p  = __expf(lg - mn);
        denom = denom * sc + p;
        float4 hv = *reinterpret_cast<const float4*>(h + (size_t)s * 256 + lane * 4);
        ax = ax * sc + p * hv.x;
        ay = ay * sc + p * hv.y;
        az = az * sc + p * hv.z;
        aw = aw * sc + p * hv.w;
        m = mn;
    }
    float inv = 1.f / denom;
    float4 b4 = *reinterpret_cast<const float4*>(bias + lane * 4);
    float ox = lrelu(ax * inv + b4.x, NEG_OUT);
    float oy = lrelu(ay * inv + b4.y, NEG_OUT);
    float oz = lrelu(az * inv + b4.z, NEG_OUT);
    float ow = lrelu(aw * inv + b4.w, NEG_OUT);
    *reinterpret_cast<float4*>(outbuf + (size_t)n * 256 + lane * 4) = make_float4(ox, oy, oz, ow);
}

// ---------- edge_index passthrough (fp32, bit-exact) ----------
__global__ void k_edge_store(const int* __restrict__ ei, float* __restrict__ out){
    int j = blockIdx.x * blockDim.x + threadIdx.x;     // 2E
    if (j >= (int)OUT1) return;
    out[j] = (float)ei[j];
}

extern "C" void kernel_launch(void* const* d_in, const int* in_sizes, int n_in,
                              void* d_out, int out_size, void* d_ws, size_t ws_size,
                              hipStream_t stream){
    const float* x    = (const float*)d_in[0];
    const int*   ei   = (const int*)d_in[1];
    const float* ea   = (const float*)d_in[2];
    const float* bn1g = (const float*)d_in[3];
    const float* bn1b = (const float*)d_in[4];
    const float* W1   = (const float*)d_in[5];
    const float* We1  = (const float*)d_in[6];
    const float* as1  = (const float*)d_in[7];
    const float* ad1  = (const float*)d_in[8];
    const float* ae1  = (const float*)d_in[9];
    const float* b1   = (const float*)d_in[10];
    const float* bn2g = (const float*)d_in[11];
    const float* bn2b = (const float*)d_in[12];
    const float* W2   = (const float*)d_in[13];
    const float* We2  = (const float*)d_in[14];
    const float* as2  = (const float*)d_in[15];
    const float* ad2  = (const float*)d_in[16];
    const float* ae2  = (const float*)d_in[17];
    const float* b2   = (const float*)d_in[18];
    float* out = (float*)d_out;

    // ---- runtime guards with distinct sentinels ----
    bool ok = (n_in >= 19)
           && (in_sizes[0] == N_ * FIN)
           && (in_sizes[1] == 2 * E_)
           && (in_sizes[2] == E_ * 16)
           && (out_size == (int)(OUT0 + OUT1));
    if (!ok){ k_sentinel<<<1,1,0,stream>>>(out, 7777.f); return; }

    char* w = (char*)d_ws;
    size_t off = 0;
    auto alloc = [&](size_t bytes) -> void* {
        off = (off + 255) & ~(size_t)255;
        void* p = w + off;
        off += bytes;
        return p;
    };
    float* stats  = (float*)alloc(512 * 4);           // sum[256], sumsq[256]
    float* asum   = (float*)alloc(16 * 4);
    float* Vbuf   = (float*)alloc(64 * 4);
    float* alloop = (float*)alloc(4 * 4);
    float* als    = (float*)alloc((size_t)N_ * 4 * 4);
    float* ald    = (float*)alloc((size_t)N_ * 4 * 4);
    float* ale    = (float*)alloc((size_t)E_ * 4 * 4);    // 12.8MB
    int*   rs     = (int*)alloc((size_t)(N_ + 1) * 4);
    int*   counts = (int*)alloc((size_t)N_ * 4);
    int*   cursor = (int*)alloc((size_t)N_ * 4);
    int*   ssrc   = (int*)alloc((size_t)E2_ * 4);
    int*   seid   = (int*)alloc((size_t)E2_ * 4);
    float* bufC   = (float*)alloc((size_t)N_ * 256 * 4);  // 51.2MB (BN out, both layers)
    float* hbuf   = (float*)alloc((size_t)N_ * 256 * 4);  // 51.2MB (projections)
    float* bufB   = (float*)alloc((size_t)N_ * 256 * 4);  // 51.2MB (layer-1 out)
    if (off > ws_size){ k_sentinel<<<1,1,0,stream>>>(out, 5555.f); return; }

    float* ssum = stats;
    float* ssq  = stats + 256;
    const int NA = N_ * 4;          // 200000

    // ---- CSR build (shared by both layers) ----
    k_zero32<<<cdiv(N_,256),256,0,stream>>>((unsigned*)counts, N_);
    k_zero32<<<cdiv(N_,256),256,0,stream>>>((unsigned*)cursor, N_);
    k_count<<<cdiv(E2_,256),256,0,stream>>>(ei, counts);
    k_scan<<<1,1024,0,stream>>>(counts, rs);
    k_scatter<<<cdiv(E2_,256),256,0,stream>>>(ei, rs, cursor, ssrc, seid);

    // ---- shared precompute ----
    k_zero32<<<2,256,0,stream>>>((unsigned*)stats, 512);
    k_zero32<<<1,64,0,stream>>>((unsigned*)asum, 16);
    k_attr_sum<<<64,256,0,stream>>>(ea, asum);

    // ---- BN1 + lrelu ----
    k_bn_stats<<<256,256,0,stream>>>(x, FIN, ssum, ssq);
    k_bn_apply<<<2048,256,0,stream>>>(x, ssum, ssq, bn1g, bn1b, bufC, FIN);

    // ---- GAT layer 1 ----
    k_gemm_row<<<N_,256,0,stream>>>(bufC, W1, hbuf, FIN);
    k_al<<<cdiv(NA,256),256,0,stream>>>(hbuf, as1, ad1, als, ald);
    k_prep<<<1,64,0,stream>>>(We1, ae1, asum, Vbuf, alloop);
    k_al_edge<<<cdiv(E_*4,256),256,0,stream>>>(ea, Vbuf, ale);
    k_aggregate<<<cdiv(N_,4),256,0,stream>>>(hbuf, als, ald, ale, alloop,
                                             rs, ssrc, seid, b1, bufB);

    // ---- BN2 + lrelu ----
    k_zero32<<<2,256,0,stream>>>((unsigned*)stats, 512);
    k_bn_stats<<<256,256,0,stream>>>(bufB, FH, ssum, ssq);
    k_bn_apply<<<2048,256,0,stream>>>(bufB, ssum, ssq, bn2g, bn2b, bufC, FH);

    // ---- GAT layer 2 ----
    k_gemm_row<<<N_,256,0,stream>>>(bufC, W2, hbuf, FH);
    k_al<<<cdiv(NA,256),256,0,stream>>>(hbuf, as2, ad2, als, ald);
    k_prep<<<1,64,0,stream>>>(We2, ae2, asum, Vbuf, alloop);
    k_al_edge<<<cdiv(E_*4,256),256,0,stream>>>(ea, Vbuf, ale);
    k_aggregate<<<cdiv(N_,4),256,0,stream>>>(hbuf, als, ald, ale, alloop,
                                             rs, ssrc, seid, b2, out);

    // ---- edge_index passthrough ----
    k_edge_store<<<cdiv((int)OUT1,256),256,0,stream>>>(ei, out + OUT0);
}

// Round 6
// 1131.896 us; speedup vs baseline: 6.1787x; 1.4043x over previous
//
#include <hip/hip_runtime.h>
#include <hip/hip_bf16.h>

// Problem constants
constexpr int N_  = 50000;
constexpr int E_  = 800000;
constexpr int E2_ = 850000;   // E + N self loops
constexpr int FIN = 128;
constexpr int FH  = 256;      // H * C = 4 * 64
constexpr float BN_EPS = 1e-5f;
constexpr float NEG_ATT = 0.2f;
constexpr float NEG_OUT = 0.1f;
constexpr size_t OUT0 = (size_t)N_ * FH;   // 12.8M feature elems (fp32)
constexpr size_t OUT1 = (size_t)2 * E_;    // 1.6M edge elems (fp32)

static inline int cdiv(int a, int b){ return (a + b - 1) / b; }

__device__ inline float lrelu(float v, float ns){ return v > 0.f ? v : ns * v; }

__global__ void k_sentinel(float* out, float v){ out[0] = v; }

__global__ void k_zero32(unsigned* p, int n){
    int i = blockIdx.x * blockDim.x + threadIdx.x;
    if (i < n) p[i] = 0u;
}

// ---------- BatchNorm ----------
__global__ void k_bn_stats(const float* __restrict__ x, int F,
                           float* __restrict__ sum, float* __restrict__ sumsq){
    int gid = blockIdx.x * blockDim.x + threadIdx.x;
    int T = gridDim.x * blockDim.x;      // 65536, divisible by 128 and 256
    int c = gid % F;
    int r0 = gid / F;
    int rstep = T / F;
    float s = 0.f, s2 = 0.f;
    for (int r = r0; r < N_; r += rstep){
        float v = x[(size_t)r * F + c];
        s += v; s2 += v * v;
    }
    atomicAdd(&sum[c], s);
    atomicAdd(&sumsq[c], s2);
}

__global__ void k_bn_apply(const float* __restrict__ x, const float* __restrict__ sum,
                           const float* __restrict__ sumsq, const float* __restrict__ gamma,
                           const float* __restrict__ beta, float* __restrict__ out, int F){
    size_t tot = (size_t)N_ * F;
    size_t step = (size_t)gridDim.x * blockDim.x;
    for (size_t i = blockIdx.x * (size_t)blockDim.x + threadIdx.x; i < tot; i += step){
        int c = (int)(i % F);
        float mean = sum[c] / (float)N_;
        float var = sumsq[c] / (float)N_ - mean * mean;
        float v = (x[i] - mean) * rsqrtf(var + BN_EPS) * gamma[c] + beta[c];
        out[i] = lrelu(v, NEG_OUT);
    }
}

// ---------- LDS-tiled GEMM: C[M x 256] = A[M x K] @ B[K x 256] ----------
// 64x64 tile per block, 256 threads, 4x4 micro-tile.
// tx = tid%16 (column group of 4), ty = tid/16 (row group of 4, 0..15).
__global__ __launch_bounds__(256) void k_gemm_tile(const float* __restrict__ A,
                                                   const float* __restrict__ B,
                                                   float* __restrict__ C, int M, int K){
    __shared__ float As[16][65];   // [k][row], +1 pad
    __shared__ float Bs[16][64];   // [k][col]
    int tid = threadIdx.x;
    int tx = tid % 16, ty = tid / 16;
    int row0 = blockIdx.x * 64;
    int col0 = blockIdx.y * 64;
    float acc[4][4] = {};
    for (int k0 = 0; k0 < K; k0 += 16){
        {   // A tile: 64 rows x 16 k; thread -> row r = tid/4, k-quad = tid%4
            int r  = tid >> 2;
            int kk = (tid & 3) * 4;
            int row = row0 + r;
            float4 v = make_float4(0.f, 0.f, 0.f, 0.f);
            if (row < M) v = *reinterpret_cast<const float4*>(A + (size_t)row * K + k0 + kk);
            As[kk+0][r] = v.x; As[kk+1][r] = v.y; As[kk+2][r] = v.z; As[kk+3][r] = v.w;
        }
        {   // B tile: 16 k x 64 cols; thread -> k = tid/16, col quad = (tid%16)*4
            int kk = tid >> 4;
            int c  = (tid & 15) * 4;
            float4 v = *reinterpret_cast<const float4*>(B + (size_t)(k0 + kk) * 256 + col0 + c);
            *reinterpret_cast<float4*>(&Bs[kk][c]) = v;
        }
        __syncthreads();
        #pragma unroll
        for (int k = 0; k < 16; ++k){
            float a0 = As[k][ty*4+0], a1 = As[k][ty*4+1], a2 = As[k][ty*4+2], a3 = As[k][ty*4+3];
            float b0 = Bs[k][tx*4+0], b1 = Bs[k][tx*4+1], b2 = Bs[k][tx*4+2], b3 = Bs[k][tx*4+3];
            acc[0][0] += a0*b0; acc[0][1] += a0*b1; acc[0][2] += a0*b2; acc[0][3] += a0*b3;
            acc[1][0] += a1*b0; acc[1][1] += a1*b1; acc[1][2] += a1*b2; acc[1][3] += a1*b3;
            acc[2][0] += a2*b0; acc[2][1] += a2*b1; acc[2][2] += a2*b2; acc[2][3] += a2*b3;
            acc[3][0] += a3*b0; acc[3][1] += a3*b1; acc[3][2] += a3*b2; acc[3][3] += a3*b3;
        }
        __syncthreads();
    }
    #pragma unroll
    for (int i = 0; i < 4; ++i){
        int row = row0 + ty*4 + i;
        if (row < M){
            *reinterpret_cast<float4*>(C + (size_t)row * 256 + col0 + tx*4) =
                make_float4(acc[i][0], acc[i][1], acc[i][2], acc[i][3]);
        }
    }
}

// ---------- per-node attention terms ----------
__global__ void k_al(const float* __restrict__ h, const float* __restrict__ asrc,
                     const float* __restrict__ adst,
                     float* __restrict__ als, float* __restrict__ ald){
    int idx = blockIdx.x * blockDim.x + threadIdx.x;  // N*4
    if (idx >= N_ * 4) return;
    int n = idx >> 2, hd = idx & 3;
    const float* hp = h + (size_t)n * 256 + hd * 64;
    const float* ap = asrc + hd * 64;
    const float* dp = adst + hd * 64;
    float s = 0.f, d = 0.f;
    for (int c = 0; c < 64; ++c){
        float v = hp[c];
        s += v * ap[c];
        d += v * dp[c];
    }
    als[idx] = s;
    ald[idx] = d;
}

// ---------- edge_attr column sums ----------
__global__ void k_attr_sum(const float* __restrict__ ea, float* __restrict__ asum){
    int gid = blockIdx.x * blockDim.x + threadIdx.x;
    int c = gid & 15;
    int r0 = gid >> 4;
    int rstep = (gridDim.x * blockDim.x) >> 4;   // 1024
    float s = 0.f;
    for (int r = r0; r < E_; r += rstep) s += ea[(size_t)r * 16 + c];
    atomicAdd(&asum[c], s);
}

// ---------- V[k][h] = sum_c We[k][h*64+c]*aedge[h][c]; alloop[h] = mean_attr . V[:,h] ----------
__global__ void k_prep(const float* __restrict__ We, const float* __restrict__ aedge,
                       const float* __restrict__ asum, float* __restrict__ V,
                       float* __restrict__ alloop){
    __shared__ float Vs[64];
    int t = threadIdx.x;  // 64 threads
    int k = t >> 2, hd = t & 3;
    float s = 0.f;
    for (int c = 0; c < 64; ++c) s += We[k * 256 + hd * 64 + c] * aedge[hd * 64 + c];
    Vs[t] = s;
    V[t] = s;
    __syncthreads();
    if (t < 4){
        float r = 0.f;
        for (int kk = 0; kk < 16; ++kk) r += (asum[kk] / (float)E_) * Vs[kk * 4 + t];
        alloop[t] = r;
    }
}

// ---------- al_edge for real edges: ale[e*4+h] = eattr[e] . V[:,h] ----------
__global__ void k_al_edge(const float* __restrict__ ea, const float* __restrict__ V,
                          float* __restrict__ ale){
    int idx = blockIdx.x * blockDim.x + threadIdx.x;   // E*4
    if (idx >= E_ * 4) return;
    int e = idx >> 2, hd = idx & 3;
    const float* ep = ea + (size_t)e * 16;
    float s = 0.f;
    #pragma unroll
    for (int k = 0; k < 16; ++k) s += ep[k] * V[k * 4 + hd];
    ale[idx] = s;
}

// ---------- CSR build ----------
__global__ void k_count(const int* __restrict__ ei, int* __restrict__ counts){
    int e = blockIdx.x * blockDim.x + threadIdx.x;
    if (e >= E2_) return;
    int d = (e < E_) ? ei[E_ + e] : (e - E_);
    atomicAdd(&counts[d], 1);
}

// single-block exclusive scan of counts[N] -> rs[N+1]
__global__ __launch_bounds__(1024) void k_scan(const int* __restrict__ counts, int* __restrict__ rs){
    __shared__ int sdata[1024];
    int t = threadIdx.x;
    const int CH = (N_ + 1023) / 1024;   // 49
    int base = t * CH;
    int s = 0;
    for (int i = 0; i < CH; ++i){
        int idx = base + i;
        if (idx < N_) s += counts[idx];
    }
    sdata[t] = s;
    __syncthreads();
    for (int off = 1; off < 1024; off <<= 1){
        int v = (t >= off) ? sdata[t - off] : 0;
        __syncthreads();
        sdata[t] += v;
        __syncthreads();
    }
    int run = (t > 0) ? sdata[t - 1] : 0;
    for (int i = 0; i < CH; ++i){
        int idx = base + i;
        if (idx < N_){ rs[idx] = run; run += counts[idx]; }
    }
    if (t == 1023) rs[N_] = E2_;
}

__global__ void k_scatter(const int* __restrict__ ei, const int* __restrict__ rs,
                          int* __restrict__ cursor, int* __restrict__ ssrc, int* __restrict__ seid){
    int e = blockIdx.x * blockDim.x + threadIdx.x;
    if (e >= E2_) return;
    int s, d;
    if (e < E_){ s = ei[e]; d = ei[E_ + e]; }
    else { s = e - E_; d = s; }
    int slot = rs[d] + atomicAdd(&cursor[d], 1);
    ssrc[slot] = s;
    seid[slot] = e;
}

// ---------- one wave per dst node: online softmax + weighted accumulation + bias + lrelu ----------
__global__ __launch_bounds__(256) void k_aggregate(const float* __restrict__ h,
        const float* __restrict__ als, const float* __restrict__ ald,
        const float* __restrict__ ale, const float* __restrict__ alloop,
        const int* __restrict__ rs, const int* __restrict__ ssrc, const int* __restrict__ seid,
        const float* __restrict__ bias, float* __restrict__ outbuf){
    int n = blockIdx.x * 4 + (threadIdx.x >> 6);
    if (n >= N_) return;
    int lane = threadIdx.x & 63;
    int hd = lane >> 4;
    float aldn = ald[(size_t)n * 4 + hd];
    float alp  = alloop[hd];
    int i0 = rs[n], i1 = rs[n + 1];
    float m = -3.0e38f, denom = 0.f;
    float ax = 0.f, ay = 0.f, az = 0.f, aw = 0.f;
    for (int i = i0; i < i1; ++i){
        int s   = ssrc[i];
        int eid = seid[i];
        float alE = (eid < E_) ? ale[(size_t)eid * 4 + hd] : alp;
        float lg = als[(size_t)s * 4 + hd] + aldn + alE;
        lg = lrelu(lg, NEG_ATT);
        float mn = fmaxf(m, lg);
        float sc = __expf(m - mn);
        float p  = __expf(lg - mn);
        denom = denom * sc + p;
        float4 hv = *reinterpret_cast<const float4*>(h + (size_t)s * 256 + lane * 4);
        ax = ax * sc + p * hv.x;
        ay = ay * sc + p * hv.y;
        az = az * sc + p * hv.z;
        aw = aw * sc + p * hv.w;
        m = mn;
    }
    float inv = 1.f / denom;
    float4 b4 = *reinterpret_cast<const float4*>(bias + lane * 4);
    float ox = lrelu(ax * inv + b4.x, NEG_OUT);
    float oy = lrelu(ay * inv + b4.y, NEG_OUT);
    float oz = lrelu(az * inv + b4.z, NEG_OUT);
    float ow = lrelu(aw * inv + b4.w, NEG_OUT);
    *reinterpret_cast<float4*>(outbuf + (size_t)n * 256 + lane * 4) = make_float4(ox, oy, oz, ow);
}

// ---------- edge_index passthrough (fp32, bit-exact) ----------
__global__ void k_edge_store(const int* __restrict__ ei, float* __restrict__ out){
    int j = blockIdx.x * blockDim.x + threadIdx.x;     // 2E
    if (j >= (int)OUT1) return;
    out[j] = (float)ei[j];
}

extern "C" void kernel_launch(void* const* d_in, const int* in_sizes, int n_in,
                              void* d_out, int out_size, void* d_ws, size_t ws_size,
                              hipStream_t stream){
    const float* x    = (const float*)d_in[0];
    const int*   ei   = (const int*)d_in[1];
    const float* ea   = (const float*)d_in[2];
    const float* bn1g = (const float*)d_in[3];
    const float* bn1b = (const float*)d_in[4];
    const float* W1   = (const float*)d_in[5];
    const float* We1  = (const float*)d_in[6];
    const float* as1  = (const float*)d_in[7];
    const float* ad1  = (const float*)d_in[8];
    const float* ae1  = (const float*)d_in[9];
    const float* b1   = (const float*)d_in[10];
    const float* bn2g = (const float*)d_in[11];
    const float* bn2b = (const float*)d_in[12];
    const float* W2   = (const float*)d_in[13];
    const float* We2  = (const float*)d_in[14];
    const float* as2  = (const float*)d_in[15];
    const float* ad2  = (const float*)d_in[16];
    const float* ae2  = (const float*)d_in[17];
    const float* b2   = (const float*)d_in[18];
    float* out = (float*)d_out;

    // ---- runtime guards with distinct sentinels ----
    bool ok = (n_in >= 19)
           && (in_sizes[0] == N_ * FIN)
           && (in_sizes[1] == 2 * E_)
           && (in_sizes[2] == E_ * 16)
           && (out_size == (int)(OUT0 + OUT1));
    if (!ok){ k_sentinel<<<1,1,0,stream>>>(out, 7777.f); return; }

    char* w = (char*)d_ws;
    size_t off = 0;
    auto alloc = [&](size_t bytes) -> void* {
        off = (off + 255) & ~(size_t)255;
        void* p = w + off;
        off += bytes;
        return p;
    };
    float* stats  = (float*)alloc(512 * 4);           // sum[256], sumsq[256]
    float* asum   = (float*)alloc(16 * 4);
    float* Vbuf   = (float*)alloc(64 * 4);
    float* alloop = (float*)alloc(4 * 4);
    float* als    = (float*)alloc((size_t)N_ * 4 * 4);
    float* ald    = (float*)alloc((size_t)N_ * 4 * 4);
    float* ale    = (float*)alloc((size_t)E_ * 4 * 4);    // 12.8MB
    int*   rs     = (int*)alloc((size_t)(N_ + 1) * 4);
    int*   counts = (int*)alloc((size_t)N_ * 4);
    int*   cursor = (int*)alloc((size_t)N_ * 4);
    int*   ssrc   = (int*)alloc((size_t)E2_ * 4);
    int*   seid   = (int*)alloc((size_t)E2_ * 4);
    float* bufC   = (float*)alloc((size_t)N_ * 256 * 4);  // 51.2MB (BN out, both layers)
    float* hbuf   = (float*)alloc((size_t)N_ * 256 * 4);  // 51.2MB (projections)
    float* bufB   = (float*)alloc((size_t)N_ * 256 * 4);  // 51.2MB (layer-1 out)
    if (off > ws_size){ k_sentinel<<<1,1,0,stream>>>(out, 5555.f); return; }

    float* ssum = stats;
    float* ssq  = stats + 256;
    const int NA = N_ * 4;          // 200000
    const int GX = cdiv(N_, 64);    // 782

    // ---- CSR build (shared by both layers) ----
    k_zero32<<<cdiv(N_,256),256,0,stream>>>((unsigned*)counts, N_);
    k_zero32<<<cdiv(N_,256),256,0,stream>>>((unsigned*)cursor, N_);
    k_count<<<cdiv(E2_,256),256,0,stream>>>(ei, counts);
    k_scan<<<1,1024,0,stream>>>(counts, rs);
    k_scatter<<<cdiv(E2_,256),256,0,stream>>>(ei, rs, cursor, ssrc, seid);

    // ---- shared precompute ----
    k_zero32<<<2,256,0,stream>>>((unsigned*)stats, 512);
    k_zero32<<<1,64,0,stream>>>((unsigned*)asum, 16);
    k_attr_sum<<<64,256,0,stream>>>(ea, asum);

    // ---- BN1 + lrelu ----
    k_bn_stats<<<256,256,0,stream>>>(x, FIN, ssum, ssq);
    k_bn_apply<<<2048,256,0,stream>>>(x, ssum, ssq, bn1g, bn1b, bufC, FIN);

    // ---- GAT layer 1 ----
    k_gemm_tile<<<dim3(GX,4),256,0,stream>>>(bufC, W1, hbuf, N_, FIN);
    k_al<<<cdiv(NA,256),256,0,stream>>>(hbuf, as1, ad1, als, ald);
    k_prep<<<1,64,0,stream>>>(We1, ae1, asum, Vbuf, alloop);
    k_al_edge<<<cdiv(E_*4,256),256,0,stream>>>(ea, Vbuf, ale);
    k_aggregate<<<cdiv(N_,4),256,0,stream>>>(hbuf, als, ald, ale, alloop,
                                             rs, ssrc, seid, b1, bufB);

    // ---- BN2 + lrelu ----
    k_zero32<<<2,256,0,stream>>>((unsigned*)stats, 512);
    k_bn_stats<<<256,256,0,stream>>>(bufB, FH, ssum, ssq);
    k_bn_apply<<<2048,256,0,stream>>>(bufB, ssum, ssq, bn2g, bn2b, bufC, FH);

    // ---- GAT layer 2 ----
    k_gemm_tile<<<dim3(GX,4),256,0,stream>>>(bufC, W2, hbuf, N_, FH);
    k_al<<<cdiv(NA,256),256,0,stream>>>(hbuf, as2, ad2, als, ald);
    k_prep<<<1,64,0,stream>>>(We2, ae2, asum, Vbuf, alloop);
    k_al_edge<<<cdiv(E_*4,256),256,0,stream>>>(ea, Vbuf, ale);
    k_aggregate<<<cdiv(N_,4),256,0,stream>>>(hbuf, als, ald, ale, alloop,
                                             rs, ssrc, seid, b2, out);

    // ---- edge_index passthrough ----
    k_edge_store<<<cdiv((int)OUT1,256),256,0,stream>>>(ei, out + OUT0);
}

// Round 7
// 942.965 us; speedup vs baseline: 7.4166x; 1.2004x over previous
//
#include <hip/hip_runtime.h>
#include <hip/hip_bf16.h>

// Problem constants
constexpr int N_  = 50000;
constexpr int E_  = 800000;
constexpr int E2_ = 850000;   // E + N self loops
constexpr int FIN = 128;
constexpr int FH  = 256;      // H * C = 4 * 64
constexpr float BN_EPS = 1e-5f;
constexpr float NEG_ATT = 0.2f;
constexpr float NEG_OUT = 0.1f;
constexpr size_t OUT0 = (size_t)N_ * FH;   // 12.8M feature elems (fp32)
constexpr size_t OUT1 = (size_t)2 * E_;    // 1.6M edge elems (fp32)

static inline int cdiv(int a, int b){ return (a + b - 1) / b; }

__device__ inline float lrelu(float v, float ns){ return v > 0.f ? v : ns * v; }

__global__ void k_sentinel(float* out, float v){ out[0] = v; }

__global__ void k_zero32(unsigned* p, int n){
    int i = blockIdx.x * blockDim.x + threadIdx.x;
    if (i < n) p[i] = 0u;
}

// ---------- BatchNorm ----------
__global__ void k_bn_stats(const float* __restrict__ x, int F,
                           float* __restrict__ sum, float* __restrict__ sumsq){
    int gid = blockIdx.x * blockDim.x + threadIdx.x;
    int T = gridDim.x * blockDim.x;      // 65536, divisible by 128 and 256
    int c = gid % F;
    int r0 = gid / F;
    int rstep = T / F;
    float s = 0.f, s2 = 0.f;
    for (int r = r0; r < N_; r += rstep){
        float v = x[(size_t)r * F + c];
        s += v; s2 += v * v;
    }
    atomicAdd(&sum[c], s);
    atomicAdd(&sumsq[c], s2);
}

__global__ void k_bn_apply(const float* __restrict__ x, const float* __restrict__ sum,
                           const float* __restrict__ sumsq, const float* __restrict__ gamma,
                           const float* __restrict__ beta, float* __restrict__ out, int F){
    size_t tot = (size_t)N_ * F;
    size_t step = (size_t)gridDim.x * blockDim.x;
    for (size_t i = blockIdx.x * (size_t)blockDim.x + threadIdx.x; i < tot; i += step){
        int c = (int)(i % F);
        float mean = sum[c] / (float)N_;
        float var = sumsq[c] / (float)N_ - mean * mean;
        float v = (x[i] - mean) * rsqrtf(var + BN_EPS) * gamma[c] + beta[c];
        out[i] = lrelu(v, NEG_OUT);
    }
}

// ---------- LDS-tiled GEMM: C[M x 256] = A[M x K] @ B[K x 256] ----------
__global__ __launch_bounds__(256) void k_gemm_tile(const float* __restrict__ A,
                                                   const float* __restrict__ B,
                                                   float* __restrict__ C, int M, int K){
    __shared__ float As[16][65];   // [k][row], +1 pad
    __shared__ float Bs[16][64];   // [k][col]
    int tid = threadIdx.x;
    int tx = tid % 16, ty = tid / 16;
    int row0 = blockIdx.x * 64;
    int col0 = blockIdx.y * 64;
    float acc[4][4] = {};
    for (int k0 = 0; k0 < K; k0 += 16){
        {   // A tile: 64 rows x 16 k
            int r  = tid >> 2;
            int kk = (tid & 3) * 4;
            int row = row0 + r;
            float4 v = make_float4(0.f, 0.f, 0.f, 0.f);
            if (row < M) v = *reinterpret_cast<const float4*>(A + (size_t)row * K + k0 + kk);
            As[kk+0][r] = v.x; As[kk+1][r] = v.y; As[kk+2][r] = v.z; As[kk+3][r] = v.w;
        }
        {   // B tile: 16 k x 64 cols
            int kk = tid >> 4;
            int c  = (tid & 15) * 4;
            float4 v = *reinterpret_cast<const float4*>(B + (size_t)(k0 + kk) * 256 + col0 + c);
            *reinterpret_cast<float4*>(&Bs[kk][c]) = v;
        }
        __syncthreads();
        #pragma unroll
        for (int k = 0; k < 16; ++k){
            float a0 = As[k][ty*4+0], a1 = As[k][ty*4+1], a2 = As[k][ty*4+2], a3 = As[k][ty*4+3];
            float b0 = Bs[k][tx*4+0], b1 = Bs[k][tx*4+1], b2 = Bs[k][tx*4+2], b3 = Bs[k][tx*4+3];
            acc[0][0] += a0*b0; acc[0][1] += a0*b1; acc[0][2] += a0*b2; acc[0][3] += a0*b3;
            acc[1][0] += a1*b0; acc[1][1] += a1*b1; acc[1][2] += a1*b2; acc[1][3] += a1*b3;
            acc[2][0] += a2*b0; acc[2][1] += a2*b1; acc[2][2] += a2*b2; acc[2][3] += a2*b3;
            acc[3][0] += a3*b0; acc[3][1] += a3*b1; acc[3][2] += a3*b2; acc[3][3] += a3*b3;
        }
        __syncthreads();
    }
    #pragma unroll
    for (int i = 0; i < 4; ++i){
        int row = row0 + ty*4 + i;
        if (row < M){
            *reinterpret_cast<float4*>(C + (size_t)row * 256 + col0 + tx*4) =
                make_float4(acc[i][0], acc[i][1], acc[i][2], acc[i][3]);
        }
    }
}

// ---------- per-node attention terms: one wave per node, coalesced float4 ----------
__global__ __launch_bounds__(256) void k_al(const float* __restrict__ h,
                                            const float* __restrict__ asrc,
                                            const float* __restrict__ adst,
                                            float* __restrict__ als, float* __restrict__ ald){
    int n = blockIdx.x * 4 + (threadIdx.x >> 6);
    if (n >= N_) return;
    int lane = threadIdx.x & 63;
    float4 hv = *reinterpret_cast<const float4*>(h + (size_t)n * 256 + lane * 4);
    float4 as = *reinterpret_cast<const float4*>(asrc + lane * 4);
    float4 ad = *reinterpret_cast<const float4*>(adst + lane * 4);
    float ps = hv.x*as.x + hv.y*as.y + hv.z*as.z + hv.w*as.w;
    float pd = hv.x*ad.x + hv.y*ad.y + hv.z*ad.z + hv.w*ad.w;
    #pragma unroll
    for (int m = 1; m < 16; m <<= 1){
        ps += __shfl_xor(ps, m, 64);
        pd += __shfl_xor(pd, m, 64);
    }
    if ((lane & 15) == 0){
        int hd = lane >> 4;
        als[(size_t)n*4 + hd] = ps;
        ald[(size_t)n*4 + hd] = pd;
    }
}

// ---------- edge_attr column sums: hierarchical float4 reduction ----------
// grid*block divisible by 4 -> each thread owns fixed column-quad tid&3.
__global__ __launch_bounds__(256) void k_attr_sum(const float* __restrict__ ea,
                                                  float* __restrict__ asum){
    __shared__ float4 sdata[256];
    int tid = threadIdx.x;
    size_t gid = (size_t)blockIdx.x * 256 + tid;
    size_t step = (size_t)gridDim.x * 256;
    const float4* p = reinterpret_cast<const float4*>(ea);
    float4 acc = make_float4(0.f, 0.f, 0.f, 0.f);
    for (size_t j = gid; j < (size_t)E_ * 4; j += step){
        float4 v = p[j];
        acc.x += v.x; acc.y += v.y; acc.z += v.z; acc.w += v.w;
    }
    sdata[tid] = acc;
    __syncthreads();
    #pragma unroll
    for (int s = 128; s >= 4; s >>= 1){
        if (tid < s){
            float4 o = sdata[tid + s];
            float4 m = sdata[tid];
            m.x += o.x; m.y += o.y; m.z += o.z; m.w += o.w;
            sdata[tid] = m;
        }
        __syncthreads();
    }
    if (tid < 4){   // thread tid holds column-quad tid -> columns [tid*4, tid*4+4)
        float4 m = sdata[tid];
        atomicAdd(&asum[tid*4+0], m.x);
        atomicAdd(&asum[tid*4+1], m.y);
        atomicAdd(&asum[tid*4+2], m.z);
        atomicAdd(&asum[tid*4+3], m.w);
    }
}

// ---------- V[k][h] = sum_c We[k][h*64+c]*aedge[h][c]; alloop[h] = mean_attr . V[:,h] ----------
__global__ void k_prep(const float* __restrict__ We, const float* __restrict__ aedge,
                       const float* __restrict__ asum, float* __restrict__ V,
                       float* __restrict__ alloop){
    __shared__ float Vs[64];
    int t = threadIdx.x;  // 64 threads
    int k = t >> 2, hd = t & 3;
    float s = 0.f;
    for (int c = 0; c < 64; ++c) s += We[k * 256 + hd * 64 + c] * aedge[hd * 64 + c];
    Vs[t] = s;
    V[t] = s;
    __syncthreads();
    if (t < 4){
        float r = 0.f;
        for (int kk = 0; kk < 16; ++kk) r += (asum[kk] / (float)E_) * Vs[kk * 4 + t];
        alloop[t] = r;
    }
}

// ---------- al_edge for real edges: ale[e*4+h] = eattr[e] . V[:,h] ----------
__global__ void k_al_edge(const float* __restrict__ ea, const float* __restrict__ V,
                          float* __restrict__ ale){
    int idx = blockIdx.x * blockDim.x + threadIdx.x;   // E*4
    if (idx >= E_ * 4) return;
    int e = idx >> 2, hd = idx & 3;
    const float* ep = ea + (size_t)e * 16;
    float s = 0.f;
    #pragma unroll
    for (int k = 0; k < 16; ++k) s += ep[k] * V[k * 4 + hd];
    ale[idx] = s;
}

// ---------- CSR build ----------
__global__ void k_count(const int* __restrict__ ei, int* __restrict__ counts){
    int e = blockIdx.x * blockDim.x + threadIdx.x;
    if (e >= E2_) return;
    int d = (e < E_) ? ei[E_ + e] : (e - E_);
    atomicAdd(&counts[d], 1);
}

// single-block exclusive scan of counts[N] -> rs[N+1]
__global__ __launch_bounds__(1024) void k_scan(const int* __restrict__ counts, int* __restrict__ rs){
    __shared__ int sdata[1024];
    int t = threadIdx.x;
    const int CH = (N_ + 1023) / 1024;   // 49
    int base = t * CH;
    int s = 0;
    for (int i = 0; i < CH; ++i){
        int idx = base + i;
        if (idx < N_) s += counts[idx];
    }
    sdata[t] = s;
    __syncthreads();
    for (int off = 1; off < 1024; off <<= 1){
        int v = (t >= off) ? sdata[t - off] : 0;
        __syncthreads();
        sdata[t] += v;
        __syncthreads();
    }
    int run = (t > 0) ? sdata[t - 1] : 0;
    for (int i = 0; i < CH; ++i){
        int idx = base + i;
        if (idx < N_){ rs[idx] = run; run += counts[idx]; }
    }
    if (t == 1023) rs[N_] = E2_;
}

__global__ void k_scatter(const int* __restrict__ ei, const int* __restrict__ rs,
                          int* __restrict__ cursor, int* __restrict__ ssrc, int* __restrict__ seid){
    int e = blockIdx.x * blockDim.x + threadIdx.x;
    if (e >= E2_) return;
    int s, d;
    if (e < E_){ s = ei[e]; d = ei[E_ + e]; }
    else { s = e - E_; d = s; }
    int slot = rs[d] + atomicAdd(&cursor[d], 1);
    ssrc[slot] = s;
    seid[slot] = e;
}

// ---------- one wave per dst node: online softmax + weighted accumulation + bias + lrelu ----------
__global__ __launch_bounds__(256) void k_aggregate(const float* __restrict__ h,
        const float* __restrict__ als, const float* __restrict__ ald,
        const float* __restrict__ ale, const float* __restrict__ alloop,
        const int* __restrict__ rs, const int* __restrict__ ssrc, const int* __restrict__ seid,
        const float* __restrict__ bias, float* __restrict__ outbuf){
    int n = blockIdx.x * 4 + (threadIdx.x >> 6);
    if (n >= N_) return;
    int lane = threadIdx.x & 63;
    int hd = lane >> 4;
    float aldn = ald[(size_t)n * 4 + hd];
    float alp  = alloop[hd];
    int i0 = rs[n], i1 = rs[n + 1];
    float m = -3.0e38f, denom = 0.f;
    float ax = 0.f, ay = 0.f, az = 0.f, aw = 0.f;
    for (int i = i0; i < i1; ++i){
        int s   = ssrc[i];
        int eid = seid[i];
        float alE = (eid < E_) ? ale[(size_t)eid * 4 + hd] : alp;
        float lg = als[(size_t)s * 4 + hd] + aldn + alE;
        lg = lrelu(lg, NEG_ATT);
        float mn = fmaxf(m, lg);
        float sc = __expf(m - mn);
        float p  = __expf(lg - mn);
        denom = denom * sc + p;
        float4 hv = *reinterpret_cast<const float4*>(h + (size_t)s * 256 + lane * 4);
        ax = ax * sc + p * hv.x;
        ay = ay * sc + p * hv.y;
        az = az * sc + p * hv.z;
        aw = aw * sc + p * hv.w;
        m = mn;
    }
    float inv = 1.f / denom;
    float4 b4 = *reinterpret_cast<const float4*>(bias + lane * 4);
    float ox = lrelu(ax * inv + b4.x, NEG_OUT);
    float oy = lrelu(ay * inv + b4.y, NEG_OUT);
    float oz = lrelu(az * inv + b4.z, NEG_OUT);
    float ow = lrelu(aw * inv + b4.w, NEG_OUT);
    *reinterpret_cast<float4*>(outbuf + (size_t)n * 256 + lane * 4) = make_float4(ox, oy, oz, ow);
}

// ---------- edge_index passthrough (fp32, bit-exact) ----------
__global__ void k_edge_store(const int* __restrict__ ei, float* __restrict__ out){
    int j = blockIdx.x * blockDim.x + threadIdx.x;     // 2E
    if (j >= (int)OUT1) return;
    out[j] = (float)ei[j];
}

extern "C" void kernel_launch(void* const* d_in, const int* in_sizes, int n_in,
                              void* d_out, int out_size, void* d_ws, size_t ws_size,
                              hipStream_t stream){
    const float* x    = (const float*)d_in[0];
    const int*   ei   = (const int*)d_in[1];
    const float* ea   = (const float*)d_in[2];
    const float* bn1g = (const float*)d_in[3];
    const float* bn1b = (const float*)d_in[4];
    const float* W1   = (const float*)d_in[5];
    const float* We1  = (const float*)d_in[6];
    const float* as1  = (const float*)d_in[7];
    const float* ad1  = (const float*)d_in[8];
    const float* ae1  = (const float*)d_in[9];
    const float* b1   = (const float*)d_in[10];
    const float* bn2g = (const float*)d_in[11];
    const float* bn2b = (const float*)d_in[12];
    const float* W2   = (const float*)d_in[13];
    const float* We2  = (const float*)d_in[14];
    const float* as2  = (const float*)d_in[15];
    const float* ad2  = (const float*)d_in[16];
    const float* ae2  = (const float*)d_in[17];
    const float* b2   = (const float*)d_in[18];
    float* out = (float*)d_out;

    // ---- runtime guards with distinct sentinels ----
    bool ok = (n_in >= 19)
           && (in_sizes[0] == N_ * FIN)
           && (in_sizes[1] == 2 * E_)
           && (in_sizes[2] == E_ * 16)
           && (out_size == (int)(OUT0 + OUT1));
    if (!ok){ k_sentinel<<<1,1,0,stream>>>(out, 7777.f); return; }

    char* w = (char*)d_ws;
    size_t off = 0;
    auto alloc = [&](size_t bytes) -> void* {
        off = (off + 255) & ~(size_t)255;
        void* p = w + off;
        off += bytes;
        return p;
    };
    float* stats  = (float*)alloc(512 * 4);           // sum[256], sumsq[256]
    float* asum   = (float*)alloc(16 * 4);
    float* Vbuf   = (float*)alloc(64 * 4);
    float* alloop = (float*)alloc(4 * 4);
    float* als    = (float*)alloc((size_t)N_ * 4 * 4);
    float* ald    = (float*)alloc((size_t)N_ * 4 * 4);
    float* ale    = (float*)alloc((size_t)E_ * 4 * 4);    // 12.8MB
    int*   rs     = (int*)alloc((size_t)(N_ + 1) * 4);
    int*   counts = (int*)alloc((size_t)N_ * 4);
    int*   cursor = (int*)alloc((size_t)N_ * 4);
    int*   ssrc   = (int*)alloc((size_t)E2_ * 4);
    int*   seid   = (int*)alloc((size_t)E2_ * 4);
    float* bufC   = (float*)alloc((size_t)N_ * 256 * 4);  // 51.2MB (BN out, both layers)
    float* hbuf   = (float*)alloc((size_t)N_ * 256 * 4);  // 51.2MB (projections)
    float* bufB   = (float*)alloc((size_t)N_ * 256 * 4);  // 51.2MB (layer-1 out)
    if (off > ws_size){ k_sentinel<<<1,1,0,stream>>>(out, 5555.f); return; }

    float* ssum = stats;
    float* ssq  = stats + 256;
    const int NA = N_ * 4;          // 200000
    const int GX = cdiv(N_, 64);    // 782

    // ---- CSR build (shared by both layers) ----
    k_zero32<<<cdiv(N_,256),256,0,stream>>>((unsigned*)counts, N_);
    k_zero32<<<cdiv(N_,256),256,0,stream>>>((unsigned*)cursor, N_);
    k_count<<<cdiv(E2_,256),256,0,stream>>>(ei, counts);
    k_scan<<<1,1024,0,stream>>>(counts, rs);
    k_scatter<<<cdiv(E2_,256),256,0,stream>>>(ei, rs, cursor, ssrc, seid);

    // ---- shared precompute ----
    k_zero32<<<2,256,0,stream>>>((unsigned*)stats, 512);
    k_zero32<<<1,64,0,stream>>>((unsigned*)asum, 16);
    k_attr_sum<<<1024,256,0,stream>>>(ea, asum);

    // ---- BN1 + lrelu ----
    k_bn_stats<<<256,256,0,stream>>>(x, FIN, ssum, ssq);
    k_bn_apply<<<2048,256,0,stream>>>(x, ssum, ssq, bn1g, bn1b, bufC, FIN);

    // ---- GAT layer 1 ----
    k_gemm_tile<<<dim3(GX,4),256,0,stream>>>(bufC, W1, hbuf, N_, FIN);
    k_al<<<cdiv(N_,4),256,0,stream>>>(hbuf, as1, ad1, als, ald);
    k_prep<<<1,64,0,stream>>>(We1, ae1, asum, Vbuf, alloop);
    k_al_edge<<<cdiv(E_*4,256),256,0,stream>>>(ea, Vbuf, ale);
    k_aggregate<<<cdiv(N_,4),256,0,stream>>>(hbuf, als, ald, ale, alloop,
                                             rs, ssrc, seid, b1, bufB);

    // ---- BN2 + lrelu ----
    k_zero32<<<2,256,0,stream>>>((unsigned*)stats, 512);
    k_bn_stats<<<256,256,0,stream>>>(bufB, FH, ssum, ssq);
    k_bn_apply<<<2048,256,0,stream>>>(bufB, ssum, ssq, bn2g, bn2b, bufC, FH);

    // ---- GAT layer 2 ----
    k_gemm_tile<<<dim3(GX,4),256,0,stream>>>(bufC, W2, hbuf, N_, FH);
    k_al<<<cdiv(N_,4),256,0,stream>>>(hbuf, as2, ad2, als, ald);
    k_prep<<<1,64,0,stream>>>(We2, ae2, asum, Vbuf, alloop);
    k_al_edge<<<cdiv(E_*4,256),256,0,stream>>>(ea, Vbuf, ale);
    k_aggregate<<<cdiv(N_,4),256,0,stream>>>(hbuf, als, ald, ale, alloop,
                                             rs, ssrc, seid, b2, out);

    // ---- edge_index passthrough ----
    k_edge_store<<<cdiv((int)OUT1,256),256,0,stream>>>(ei, out + OUT0);
}

// Round 8
// 764.176 us; speedup vs baseline: 9.1518x; 1.2340x over previous
//
#include <hip/hip_runtime.h>
#include <hip/hip_bf16.h>

// Problem constants
constexpr int N_  = 50000;
constexpr int E_  = 800000;
constexpr int E2_ = 850000;   // E + N self loops
constexpr int FIN = 128;
constexpr int FH  = 256;      // H * C = 4 * 64
constexpr float BN_EPS = 1e-5f;
constexpr float NEG_ATT = 0.2f;
constexpr float NEG_OUT = 0.1f;
constexpr size_t OUT0 = (size_t)N_ * FH;   // 12.8M feature elems (fp32)
constexpr size_t OUT1 = (size_t)2 * E_;    // 1.6M edge elems (fp32)

static inline int cdiv(int a, int b){ return (a + b - 1) / b; }

using short8 = __attribute__((ext_vector_type(8))) short;
using f32x4  = __attribute__((ext_vector_type(4))) float;

__device__ inline float lrelu(float v, float ns){ return v > 0.f ? v : ns * v; }

// bf16 round-to-nearest-even encode
__device__ inline unsigned short bf16rne(float f){
    unsigned u = __float_as_uint(f);
    u += 0x7fffu + ((u >> 16) & 1u);
    return (unsigned short)(u >> 16);
}
// decode 2 bf16 packed in a uint (little-endian: elem0 = low half)
__device__ inline float bf16lo(unsigned u){ return __uint_as_float(u << 16); }
__device__ inline float bf16hi(unsigned u){ return __uint_as_float(u & 0xffff0000u); }

__global__ void k_sentinel(float* out, float v){ out[0] = v; }

__global__ void k_zero32(unsigned* p, int n){
    int i = blockIdx.x * blockDim.x + threadIdx.x;
    if (i < n) p[i] = 0u;
}

// ---------- W [K][256] fp32 -> WT [256][K] bf16 ----------
__global__ void k_w2t(const float* __restrict__ W, unsigned short* __restrict__ WT, int K){
    int i = blockIdx.x * blockDim.x + threadIdx.x;
    if (i >= K * 256) return;
    int k = i >> 8, c = i & 255;
    WT[(size_t)c * K + k] = bf16rne(W[i]);
}

// ---------- BatchNorm ----------
__global__ void k_bn_stats(const float* __restrict__ x, int F,
                           float* __restrict__ sum, float* __restrict__ sumsq){
    int gid = blockIdx.x * blockDim.x + threadIdx.x;
    int T = gridDim.x * blockDim.x;      // 65536
    int c = gid % F;
    int r0 = gid / F;
    int rstep = T / F;
    float s = 0.f, s2 = 0.f;
    for (int r = r0; r < N_; r += rstep){
        float v = x[(size_t)r * F + c];
        s += v; s2 += v * v;
    }
    atomicAdd(&sum[c], s);
    atomicAdd(&sumsq[c], s2);
}

// BN + lrelu, bf16 output
__global__ void k_bn_apply_bf(const float* __restrict__ x, const float* __restrict__ sum,
                              const float* __restrict__ sumsq, const float* __restrict__ gamma,
                              const float* __restrict__ beta, unsigned short* __restrict__ out, int F){
    size_t tot = (size_t)N_ * F;
    size_t step = (size_t)gridDim.x * blockDim.x;
    for (size_t i = blockIdx.x * (size_t)blockDim.x + threadIdx.x; i < tot; i += step){
        int c = (int)(i % F);
        float mean = sum[c] / (float)N_;
        float var = sumsq[c] / (float)N_ - mean * mean;
        float v = (x[i] - mean) * rsqrtf(var + BN_EPS) * gamma[c] + beta[c];
        out[i] = bf16rne(lrelu(v, NEG_OUT));
    }
}

// ---------- MFMA GEMM: C[M x 256] = A[M x K] @ B[K x 256] (A,WT,C all bf16) ----------
// WT = B transposed [256][K]. 64x64 tile, 4 waves; wave w -> cols [w*16, w*16+16).
// mfma_f32_16x16x32_bf16: A-frag row=l&15, k=8*(l>>4)+j ; B-frag col=l&15 same k;
// D: col=l&15, row=(l>>4)*4+r  [guide m89/m91 verified]
__global__ __launch_bounds__(256) void k_gemm_mfma(const unsigned short* __restrict__ A,
                                                   const unsigned short* __restrict__ WT,
                                                   unsigned short* __restrict__ C, int M, int K){
    __shared__ unsigned short Al[64][32];   // 4KB
    __shared__ unsigned short Bl[64][32];   // 4KB  (Bl[col][k])
    int tid = threadIdx.x;
    int w = tid >> 6;          // wave 0..3
    int l = tid & 63;          // lane
    int row0 = blockIdx.x * 64;
    int col0 = blockIdx.y * 64;
    f32x4 acc[4];
    #pragma unroll
    for (int m = 0; m < 4; ++m) acc[m] = (f32x4){0.f, 0.f, 0.f, 0.f};

    int srow = tid >> 2;             // 0..63
    int skq  = (tid & 3) * 8;        // k offset 0,8,16,24

    for (int k0 = 0; k0 < K; k0 += 32){
        {   // stage A tile 64x32
            short8 v = {0,0,0,0,0,0,0,0};
            if (row0 + srow < M)
                v = *reinterpret_cast<const short8*>(A + (size_t)(row0 + srow) * K + k0 + skq);
            *reinterpret_cast<short8*>(&Al[srow][skq]) = v;
        }
        {   // stage B tile (cols 64 x k 32) from WT
            short8 v = *reinterpret_cast<const short8*>(WT + (size_t)(col0 + srow) * K + k0 + skq);
            *reinterpret_cast<short8*>(&Bl[srow][skq]) = v;
        }
        __syncthreads();
        short8 b = *reinterpret_cast<const short8*>(&Bl[w * 16 + (l & 15)][8 * (l >> 4)]);
        #pragma unroll
        for (int m = 0; m < 4; ++m){
            short8 a = *reinterpret_cast<const short8*>(&Al[m * 16 + (l & 15)][8 * (l >> 4)]);
            acc[m] = __builtin_amdgcn_mfma_f32_16x16x32_bf16(a, b, acc[m], 0, 0, 0);
        }
        __syncthreads();
    }
    // epilogue: D col=l&15, row=(l>>4)*4+r
    int ccol = col0 + w * 16 + (l & 15);
    #pragma unroll
    for (int m = 0; m < 4; ++m){
        #pragma unroll
        for (int r = 0; r < 4; ++r){
            int row = row0 + m * 16 + (l >> 4) * 4 + r;
            if (row < M) C[(size_t)row * 256 + ccol] = bf16rne(acc[m][r]);
        }
    }
}

// ---------- per-node attention terms: one wave per node, bf16 h ----------
__global__ __launch_bounds__(256) void k_al(const unsigned short* __restrict__ hb,
                                            const float* __restrict__ asrc,
                                            const float* __restrict__ adst,
                                            float* __restrict__ als, float* __restrict__ ald){
    int n = blockIdx.x * 4 + (threadIdx.x >> 6);
    if (n >= N_) return;
    int lane = threadIdx.x & 63;
    uint2 g = *reinterpret_cast<const uint2*>(hb + (size_t)n * 256 + lane * 4);
    float h0 = bf16lo(g.x), h1 = bf16hi(g.x), h2 = bf16lo(g.y), h3 = bf16hi(g.y);
    float4 as = *reinterpret_cast<const float4*>(asrc + lane * 4);
    float4 ad = *reinterpret_cast<const float4*>(adst + lane * 4);
    float ps = h0*as.x + h1*as.y + h2*as.z + h3*as.w;
    float pd = h0*ad.x + h1*ad.y + h2*ad.z + h3*ad.w;
    #pragma unroll
    for (int m = 1; m < 16; m <<= 1){
        ps += __shfl_xor(ps, m, 64);
        pd += __shfl_xor(pd, m, 64);
    }
    if ((lane & 15) == 0){
        int hd = lane >> 4;
        als[(size_t)n*4 + hd] = ps;
        ald[(size_t)n*4 + hd] = pd;
    }
}

// ---------- edge_attr column sums: hierarchical float4 reduction ----------
__global__ __launch_bounds__(256) void k_attr_sum(const float* __restrict__ ea,
                                                  float* __restrict__ asum){
    __shared__ float4 sdata[256];
    int tid = threadIdx.x;
    size_t gid = (size_t)blockIdx.x * 256 + tid;
    size_t step = (size_t)gridDim.x * 256;
    const float4* p = reinterpret_cast<const float4*>(ea);
    float4 acc = make_float4(0.f, 0.f, 0.f, 0.f);
    for (size_t j = gid; j < (size_t)E_ * 4; j += step){
        float4 v = p[j];
        acc.x += v.x; acc.y += v.y; acc.z += v.z; acc.w += v.w;
    }
    sdata[tid] = acc;
    __syncthreads();
    #pragma unroll
    for (int s = 128; s >= 4; s >>= 1){
        if (tid < s){
            float4 o = sdata[tid + s];
            float4 m = sdata[tid];
            m.x += o.x; m.y += o.y; m.z += o.z; m.w += o.w;
            sdata[tid] = m;
        }
        __syncthreads();
    }
    if (tid < 4){
        float4 m = sdata[tid];
        atomicAdd(&asum[tid*4+0], m.x);
        atomicAdd(&asum[tid*4+1], m.y);
        atomicAdd(&asum[tid*4+2], m.z);
        atomicAdd(&asum[tid*4+3], m.w);
    }
}

// ---------- V[k][h] = sum_c We[k][h*64+c]*aedge[h][c]; alloop[h] = mean_attr . V[:,h] ----------
__global__ void k_prep(const float* __restrict__ We, const float* __restrict__ aedge,
                       const float* __restrict__ asum, float* __restrict__ V,
                       float* __restrict__ alloop){
    __shared__ float Vs[64];
    int t = threadIdx.x;  // 64 threads
    int k = t >> 2, hd = t & 3;
    float s = 0.f;
    for (int c = 0; c < 64; ++c) s += We[k * 256 + hd * 64 + c] * aedge[hd * 64 + c];
    Vs[t] = s;
    V[t] = s;
    __syncthreads();
    if (t < 4){
        float r = 0.f;
        for (int kk = 0; kk < 16; ++kk) r += (asum[kk] / (float)E_) * Vs[kk * 4 + t];
        alloop[t] = r;
    }
}

// ---------- al_edge for real edges: ale[e*4+h] = eattr[e] . V[:,h] ----------
__global__ void k_al_edge(const float* __restrict__ ea, const float* __restrict__ V,
                          float* __restrict__ ale){
    int idx = blockIdx.x * blockDim.x + threadIdx.x;   // E*4
    if (idx >= E_ * 4) return;
    int e = idx >> 2, hd = idx & 3;
    const float* ep = ea + (size_t)e * 16;
    float s = 0.f;
    #pragma unroll
    for (int k = 0; k < 16; ++k) s += ep[k] * V[k * 4 + hd];
    ale[idx] = s;
}

// ---------- CSR build ----------
__global__ void k_count(const int* __restrict__ ei, int* __restrict__ counts){
    int e = blockIdx.x * blockDim.x + threadIdx.x;
    if (e >= E2_) return;
    int d = (e < E_) ? ei[E_ + e] : (e - E_);
    atomicAdd(&counts[d], 1);
}

__global__ __launch_bounds__(1024) void k_scan(const int* __restrict__ counts, int* __restrict__ rs){
    __shared__ int sdata[1024];
    int t = threadIdx.x;
    const int CH = (N_ + 1023) / 1024;   // 49
    int base = t * CH;
    int s = 0;
    for (int i = 0; i < CH; ++i){
        int idx = base + i;
        if (idx < N_) s += counts[idx];
    }
    sdata[t] = s;
    __syncthreads();
    for (int off = 1; off < 1024; off <<= 1){
        int v = (t >= off) ? sdata[t - off] : 0;
        __syncthreads();
        sdata[t] += v;
        __syncthreads();
    }
    int run = (t > 0) ? sdata[t - 1] : 0;
    for (int i = 0; i < CH; ++i){
        int idx = base + i;
        if (idx < N_){ rs[idx] = run; run += counts[idx]; }
    }
    if (t == 1023) rs[N_] = E2_;
}

__global__ void k_scatter(const int* __restrict__ ei, const int* __restrict__ rs,
                          int* __restrict__ cursor, int* __restrict__ ssrc, int* __restrict__ seid){
    int e = blockIdx.x * blockDim.x + threadIdx.x;
    if (e >= E2_) return;
    int s, d;
    if (e < E_){ s = ei[e]; d = ei[E_ + e]; }
    else { s = e - E_; d = s; }
    int slot = rs[d] + atomicAdd(&cursor[d], 1);
    ssrc[slot] = s;
    seid[slot] = e;
}

// ---------- one wave per dst node: online softmax over bf16 h rows ----------
__global__ __launch_bounds__(256) void k_aggregate(const unsigned short* __restrict__ hb,
        const float* __restrict__ als, const float* __restrict__ ald,
        const float* __restrict__ ale, const float* __restrict__ alloop,
        const int* __restrict__ rs, const int* __restrict__ ssrc, const int* __restrict__ seid,
        const float* __restrict__ bias, float* __restrict__ outbuf){
    int n = blockIdx.x * 4 + (threadIdx.x >> 6);
    if (n >= N_) return;
    int lane = threadIdx.x & 63;
    int hd = lane >> 4;
    float aldn = ald[(size_t)n * 4 + hd];
    float alp  = alloop[hd];
    int i0 = rs[n], i1 = rs[n + 1];
    float m = -3.0e38f, denom = 0.f;
    float ax = 0.f, ay = 0.f, az = 0.f, aw = 0.f;
    for (int i = i0; i < i1; ++i){
        int s   = ssrc[i];
        int eid = seid[i];
        float alE = (eid < E_) ? ale[(size_t)eid * 4 + hd] : alp;
        float lg = als[(size_t)s * 4 + hd] + aldn + alE;
        lg = lrelu(lg, NEG_ATT);
        float mn = fmaxf(m, lg);
        float sc = __expf(m - mn);
        float p  = __expf(lg - mn);
        denom = denom * sc + p;
        uint2 g = *reinterpret_cast<const uint2*>(hb + (size_t)s * 256 + lane * 4);
        ax = ax * sc + p * bf16lo(g.x);
        ay = ay * sc + p * bf16hi(g.x);
        az = az * sc + p * bf16lo(g.y);
        aw = aw * sc + p * bf16hi(g.y);
        m = mn;
    }
    float inv = 1.f / denom;
    float4 b4 = *reinterpret_cast<const float4*>(bias + lane * 4);
    float ox = lrelu(ax * inv + b4.x, NEG_OUT);
    float oy = lrelu(ay * inv + b4.y, NEG_OUT);
    float oz = lrelu(az * inv + b4.z, NEG_OUT);
    float ow = lrelu(aw * inv + b4.w, NEG_OUT);
    *reinterpret_cast<float4*>(outbuf + (size_t)n * 256 + lane * 4) = make_float4(ox, oy, oz, ow);
}

// ---------- edge_index passthrough (fp32, bit-exact) ----------
__global__ void k_edge_store(const int* __restrict__ ei, float* __restrict__ out){
    int j = blockIdx.x * blockDim.x + threadIdx.x;     // 2E
    if (j >= (int)OUT1) return;
    out[j] = (float)ei[j];
}

extern "C" void kernel_launch(void* const* d_in, const int* in_sizes, int n_in,
                              void* d_out, int out_size, void* d_ws, size_t ws_size,
                              hipStream_t stream){
    const float* x    = (const float*)d_in[0];
    const int*   ei   = (const int*)d_in[1];
    const float* ea   = (const float*)d_in[2];
    const float* bn1g = (const float*)d_in[3];
    const float* bn1b = (const float*)d_in[4];
    const float* W1   = (const float*)d_in[5];
    const float* We1  = (const float*)d_in[6];
    const float* as1  = (const float*)d_in[7];
    const float* ad1  = (const float*)d_in[8];
    const float* ae1  = (const float*)d_in[9];
    const float* b1   = (const float*)d_in[10];
    const float* bn2g = (const float*)d_in[11];
    const float* bn2b = (const float*)d_in[12];
    const float* W2   = (const float*)d_in[13];
    const float* We2  = (const float*)d_in[14];
    const float* as2  = (const float*)d_in[15];
    const float* ad2  = (const float*)d_in[16];
    const float* ae2  = (const float*)d_in[17];
    const float* b2   = (const float*)d_in[18];
    float* out = (float*)d_out;

    bool ok = (n_in >= 19)
           && (in_sizes[0] == N_ * FIN)
           && (in_sizes[1] == 2 * E_)
           && (in_sizes[2] == E_ * 16)
           && (out_size == (int)(OUT0 + OUT1));
    if (!ok){ k_sentinel<<<1,1,0,stream>>>(out, 7777.f); return; }

    char* w = (char*)d_ws;
    size_t off = 0;
    auto alloc = [&](size_t bytes) -> void* {
        off = (off + 255) & ~(size_t)255;
        void* p = w + off;
        off += bytes;
        return p;
    };
    float* stats  = (float*)alloc(512 * 4);
    float* asum   = (float*)alloc(16 * 4);
    float* Vbuf   = (float*)alloc(64 * 4);
    float* alloop = (float*)alloc(4 * 4);
    float* als    = (float*)alloc((size_t)N_ * 4 * 4);
    float* ald    = (float*)alloc((size_t)N_ * 4 * 4);
    float* ale    = (float*)alloc((size_t)E_ * 4 * 4);          // 12.8MB
    int*   rs     = (int*)alloc((size_t)(N_ + 1) * 4);
    int*   counts = (int*)alloc((size_t)N_ * 4);
    int*   cursor = (int*)alloc((size_t)N_ * 4);
    int*   ssrc   = (int*)alloc((size_t)E2_ * 4);
    int*   seid   = (int*)alloc((size_t)E2_ * 4);
    unsigned short* WT1 = (unsigned short*)alloc((size_t)256 * FIN * 2);  // 64KB
    unsigned short* WT2 = (unsigned short*)alloc((size_t)256 * FH * 2);   // 128KB
    unsigned short* bufC = (unsigned short*)alloc((size_t)N_ * 256 * 2);  // 25.6MB bf16 (BN out)
    unsigned short* hbuf = (unsigned short*)alloc((size_t)N_ * 256 * 2);  // 25.6MB bf16 (projections)
    float* bufB   = (float*)alloc((size_t)N_ * 256 * 4);                  // 51.2MB (layer-1 out)
    if (off > ws_size){ k_sentinel<<<1,1,0,stream>>>(out, 5555.f); return; }

    float* ssum = stats;
    float* ssq  = stats + 256;
    const int GX = cdiv(N_, 64);    // 782

    // ---- CSR build (shared by both layers) ----
    k_zero32<<<cdiv(N_,256),256,0,stream>>>((unsigned*)counts, N_);
    k_zero32<<<cdiv(N_,256),256,0,stream>>>((unsigned*)cursor, N_);
    k_count<<<cdiv(E2_,256),256,0,stream>>>(ei, counts);
    k_scan<<<1,1024,0,stream>>>(counts, rs);
    k_scatter<<<cdiv(E2_,256),256,0,stream>>>(ei, rs, cursor, ssrc, seid);

    // ---- shared precompute ----
    k_zero32<<<2,256,0,stream>>>((unsigned*)stats, 512);
    k_zero32<<<1,64,0,stream>>>((unsigned*)asum, 16);
    k_attr_sum<<<1024,256,0,stream>>>(ea, asum);
    k_w2t<<<FIN,256,0,stream>>>(W1, WT1, FIN);
    k_w2t<<<FH,256,0,stream>>>(W2, WT2, FH);

    // ---- BN1 + lrelu (bf16 out) ----
    k_bn_stats<<<256,256,0,stream>>>(x, FIN, ssum, ssq);
    k_bn_apply_bf<<<2048,256,0,stream>>>(x, ssum, ssq, bn1g, bn1b, bufC, FIN);

    // ---- GAT layer 1 ----
    k_gemm_mfma<<<dim3(GX,4),256,0,stream>>>(bufC, WT1, hbuf, N_, FIN);
    k_al<<<cdiv(N_,4),256,0,stream>>>(hbuf, as1, ad1, als, ald);
    k_prep<<<1,64,0,stream>>>(We1, ae1, asum, Vbuf, alloop);
    k_al_edge<<<cdiv(E_*4,256),256,0,stream>>>(ea, Vbuf, ale);
    k_aggregate<<<cdiv(N_,4),256,0,stream>>>(hbuf, als, ald, ale, alloop,
                                             rs, ssrc, seid, b1, bufB);

    // ---- BN2 + lrelu (bf16 out) ----
    k_zero32<<<2,256,0,stream>>>((unsigned*)stats, 512);
    k_bn_stats<<<256,256,0,stream>>>(bufB, FH, ssum, ssq);
    k_bn_apply_bf<<<2048,256,0,stream>>>(bufB, ssum, ssq, bn2g, bn2b, bufC, FH);

    // ---- GAT layer 2 ----
    k_gemm_mfma<<<dim3(GX,4),256,0,stream>>>(bufC, WT2, hbuf, N_, FH);
    k_al<<<cdiv(N_,4),256,0,stream>>>(hbuf, as2, ad2, als, ald);
    k_prep<<<1,64,0,stream>>>(We2, ae2, asum, Vbuf, alloop);
    k_al_edge<<<cdiv(E_*4,256),256,0,stream>>>(ea, Vbuf, ale);
    k_aggregate<<<cdiv(N_,4),256,0,stream>>>(hbuf, als, ald, ale, alloop,
                                             rs, ssrc, seid, b2, out);

    // ---- edge_index passthrough ----
    k_edge_store<<<cdiv((int)OUT1,256),256,0,stream>>>(ei, out + OUT0);
}

// Round 9
// 683.281 us; speedup vs baseline: 10.2353x; 1.1184x over previous
//
#include <hip/hip_runtime.h>
#include <hip/hip_bf16.h>

// Problem constants
constexpr int N_  = 50000;
constexpr int E_  = 800000;
constexpr int E2_ = 850000;   // E + N self loops
constexpr int FIN = 128;
constexpr int FH  = 256;      // H * C = 4 * 64
constexpr float BN_EPS = 1e-5f;
constexpr float NEG_ATT = 0.2f;
constexpr float NEG_OUT = 0.1f;
constexpr size_t OUT0 = (size_t)N_ * FH;   // 12.8M feature elems (fp32)
constexpr size_t OUT1 = (size_t)2 * E_;    // 1.6M edge elems (fp32)

static inline int cdiv(int a, int b){ return (a + b - 1) / b; }

using short8 = __attribute__((ext_vector_type(8))) short;
using f32x4  = __attribute__((ext_vector_type(4))) float;

__device__ inline float lrelu(float v, float ns){ return v > 0.f ? v : ns * v; }

// bf16 round-to-nearest-even encode
__device__ inline unsigned short bf16rne(float f){
    unsigned u = __float_as_uint(f);
    u += 0x7fffu + ((u >> 16) & 1u);
    return (unsigned short)(u >> 16);
}
__device__ inline float bf16lo(unsigned u){ return __uint_as_float(u << 16); }
__device__ inline float bf16hi(unsigned u){ return __uint_as_float(u & 0xffff0000u); }

__global__ void k_sentinel(float* out, float v){ out[0] = v; }

__global__ void k_zero32(unsigned* p, int n){
    int i = blockIdx.x * blockDim.x + threadIdx.x;
    if (i < n) p[i] = 0u;
}

// ---------- W [K][256] fp32 -> WT [256][K] bf16 ----------
__global__ void k_w2t(const float* __restrict__ W, unsigned short* __restrict__ WT, int K){
    int i = blockIdx.x * blockDim.x + threadIdx.x;
    if (i >= K * 256) return;
    int k = i >> 8, c = i & 255;
    WT[(size_t)c * K + k] = bf16rne(W[i]);
}

// ---------- BatchNorm ----------
__global__ void k_bn_stats(const float* __restrict__ x, int F,
                           float* __restrict__ sum, float* __restrict__ sumsq){
    int gid = blockIdx.x * blockDim.x + threadIdx.x;
    int T = gridDim.x * blockDim.x;      // 65536
    int c = gid % F;
    int r0 = gid / F;
    int rstep = T / F;
    float s = 0.f, s2 = 0.f;
    for (int r = r0; r < N_; r += rstep){
        float v = x[(size_t)r * F + c];
        s += v; s2 += v * v;
    }
    atomicAdd(&sum[c], s);
    atomicAdd(&sumsq[c], s2);
}

// BN + lrelu, bf16 output
__global__ void k_bn_apply_bf(const float* __restrict__ x, const float* __restrict__ sum,
                              const float* __restrict__ sumsq, const float* __restrict__ gamma,
                              const float* __restrict__ beta, unsigned short* __restrict__ out, int F){
    size_t tot = (size_t)N_ * F;
    size_t step = (size_t)gridDim.x * blockDim.x;
    for (size_t i = blockIdx.x * (size_t)blockDim.x + threadIdx.x; i < tot; i += step){
        int c = (int)(i % F);
        float mean = sum[c] / (float)N_;
        float var = sumsq[c] / (float)N_ - mean * mean;
        float v = (x[i] - mean) * rsqrtf(var + BN_EPS) * gamma[c] + beta[c];
        out[i] = bf16rne(lrelu(v, NEG_OUT));
    }
}

// ---------- MFMA GEMM: C[M x 256] = A[M x K] @ B[K x 256] (A,WT,C all bf16) ----------
__global__ __launch_bounds__(256) void k_gemm_mfma(const unsigned short* __restrict__ A,
                                                   const unsigned short* __restrict__ WT,
                                                   unsigned short* __restrict__ C, int M, int K){
    __shared__ unsigned short Al[64][32];   // 4KB
    __shared__ unsigned short Bl[64][32];   // 4KB  (Bl[col][k])
    int tid = threadIdx.x;
    int w = tid >> 6;
    int l = tid & 63;
    int row0 = blockIdx.x * 64;
    int col0 = blockIdx.y * 64;
    f32x4 acc[4];
    #pragma unroll
    for (int m = 0; m < 4; ++m) acc[m] = (f32x4){0.f, 0.f, 0.f, 0.f};

    int srow = tid >> 2;
    int skq  = (tid & 3) * 8;

    for (int k0 = 0; k0 < K; k0 += 32){
        {
            short8 v = {0,0,0,0,0,0,0,0};
            if (row0 + srow < M)
                v = *reinterpret_cast<const short8*>(A + (size_t)(row0 + srow) * K + k0 + skq);
            *reinterpret_cast<short8*>(&Al[srow][skq]) = v;
        }
        {
            short8 v = *reinterpret_cast<const short8*>(WT + (size_t)(col0 + srow) * K + k0 + skq);
            *reinterpret_cast<short8*>(&Bl[srow][skq]) = v;
        }
        __syncthreads();
        short8 b = *reinterpret_cast<const short8*>(&Bl[w * 16 + (l & 15)][8 * (l >> 4)]);
        #pragma unroll
        for (int m = 0; m < 4; ++m){
            short8 a = *reinterpret_cast<const short8*>(&Al[m * 16 + (l & 15)][8 * (l >> 4)]);
            acc[m] = __builtin_amdgcn_mfma_f32_16x16x32_bf16(a, b, acc[m], 0, 0, 0);
        }
        __syncthreads();
    }
    int ccol = col0 + w * 16 + (l & 15);
    #pragma unroll
    for (int m = 0; m < 4; ++m){
        #pragma unroll
        for (int r = 0; r < 4; ++r){
            int row = row0 + m * 16 + (l >> 4) * 4 + r;
            if (row < M) C[(size_t)row * 256 + ccol] = bf16rne(acc[m][r]);
        }
    }
}

// ---------- per-node attention terms: one wave per node, bf16 h ----------
__global__ __launch_bounds__(256) void k_al(const unsigned short* __restrict__ hb,
                                            const float* __restrict__ asrc,
                                            const float* __restrict__ adst,
                                            float* __restrict__ als, float* __restrict__ ald){
    int n = blockIdx.x * 4 + (threadIdx.x >> 6);
    if (n >= N_) return;
    int lane = threadIdx.x & 63;
    uint2 g = *reinterpret_cast<const uint2*>(hb + (size_t)n * 256 + lane * 4);
    float h0 = bf16lo(g.x), h1 = bf16hi(g.x), h2 = bf16lo(g.y), h3 = bf16hi(g.y);
    float4 as = *reinterpret_cast<const float4*>(asrc + lane * 4);
    float4 ad = *reinterpret_cast<const float4*>(adst + lane * 4);
    float ps = h0*as.x + h1*as.y + h2*as.z + h3*as.w;
    float pd = h0*ad.x + h1*ad.y + h2*ad.z + h3*ad.w;
    #pragma unroll
    for (int m = 1; m < 16; m <<= 1){
        ps += __shfl_xor(ps, m, 64);
        pd += __shfl_xor(pd, m, 64);
    }
    if ((lane & 15) == 0){
        int hd = lane >> 4;
        als[(size_t)n*4 + hd] = ps;
        ald[(size_t)n*4 + hd] = pd;
    }
}

// ---------- edge_attr column sums: hierarchical float4 reduction ----------
__global__ __launch_bounds__(256) void k_attr_sum(const float* __restrict__ ea,
                                                  float* __restrict__ asum){
    __shared__ float4 sdata[256];
    int tid = threadIdx.x;
    size_t gid = (size_t)blockIdx.x * 256 + tid;
    size_t step = (size_t)gridDim.x * 256;
    const float4* p = reinterpret_cast<const float4*>(ea);
    float4 acc = make_float4(0.f, 0.f, 0.f, 0.f);
    for (size_t j = gid; j < (size_t)E_ * 4; j += step){
        float4 v = p[j];
        acc.x += v.x; acc.y += v.y; acc.z += v.z; acc.w += v.w;
    }
    sdata[tid] = acc;
    __syncthreads();
    #pragma unroll
    for (int s = 128; s >= 4; s >>= 1){
        if (tid < s){
            float4 o = sdata[tid + s];
            float4 m = sdata[tid];
            m.x += o.x; m.y += o.y; m.z += o.z; m.w += o.w;
            sdata[tid] = m;
        }
        __syncthreads();
    }
    if (tid < 4){
        float4 m = sdata[tid];
        atomicAdd(&asum[tid*4+0], m.x);
        atomicAdd(&asum[tid*4+1], m.y);
        atomicAdd(&asum[tid*4+2], m.z);
        atomicAdd(&asum[tid*4+3], m.w);
    }
}

// ---------- V[k][h]; alloop[h] ----------
__global__ void k_prep(const float* __restrict__ We, const float* __restrict__ aedge,
                       const float* __restrict__ asum, float* __restrict__ V,
                       float* __restrict__ alloop){
    __shared__ float Vs[64];
    int t = threadIdx.x;  // 64 threads
    int k = t >> 2, hd = t & 3;
    float s = 0.f;
    for (int c = 0; c < 64; ++c) s += We[k * 256 + hd * 64 + c] * aedge[hd * 64 + c];
    Vs[t] = s;
    V[t] = s;
    __syncthreads();
    if (t < 4){
        float r = 0.f;
        for (int kk = 0; kk < 16; ++kk) r += (asum[kk] / (float)E_) * Vs[kk * 4 + t];
        alloop[t] = r;
    }
}

// ---------- al_edge ----------
__global__ void k_al_edge(const float* __restrict__ ea, const float* __restrict__ V,
                          float* __restrict__ ale){
    int idx = blockIdx.x * blockDim.x + threadIdx.x;   // E*4
    if (idx >= E_ * 4) return;
    int e = idx >> 2, hd = idx & 3;
    const float* ep = ea + (size_t)e * 16;
    float s = 0.f;
    #pragma unroll
    for (int k = 0; k < 16; ++k) s += ep[k] * V[k * 4 + hd];
    ale[idx] = s;
}

// ---------- CSR build ----------
__global__ void k_count(const int* __restrict__ ei, int* __restrict__ counts){
    int e = blockIdx.x * blockDim.x + threadIdx.x;
    if (e >= E2_) return;
    int d = (e < E_) ? ei[E_ + e] : (e - E_);
    atomicAdd(&counts[d], 1);
}

__global__ __launch_bounds__(1024) void k_scan(const int* __restrict__ counts, int* __restrict__ rs){
    __shared__ int sdata[1024];
    int t = threadIdx.x;
    const int CH = (N_ + 1023) / 1024;   // 49
    int base = t * CH;
    int s = 0;
    for (int i = 0; i < CH; ++i){
        int idx = base + i;
        if (idx < N_) s += counts[idx];
    }
    sdata[t] = s;
    __syncthreads();
    for (int off = 1; off < 1024; off <<= 1){
        int v = (t >= off) ? sdata[t - off] : 0;
        __syncthreads();
        sdata[t] += v;
        __syncthreads();
    }
    int run = (t > 0) ? sdata[t - 1] : 0;
    for (int i = 0; i < CH; ++i){
        int idx = base + i;
        if (idx < N_){ rs[idx] = run; run += counts[idx]; }
    }
    if (t == 1023) rs[N_] = E2_;
}

__global__ void k_scatter(const int* __restrict__ ei, const int* __restrict__ rs,
                          int* __restrict__ cursor, int* __restrict__ ssrc, int* __restrict__ seid){
    int e = blockIdx.x * blockDim.x + threadIdx.x;
    if (e >= E2_) return;
    int s, d;
    if (e < E_){ s = ei[e]; d = ei[E_ + e]; }
    else { s = e - E_; d = s; }
    int slot = rs[d] + atomicAdd(&cursor[d], 1);
    ssrc[slot] = s;
    seid[slot] = e;
}

// ---------- one wave per dst node, TWO independent edge streams (32 lanes each) ----------
// half = lane>>5 processes CSR slots i0+half, i0+half+2, ... with its own online-softmax
// state; lane covers 8 feature cols [sl*8, sl*8+8) via one uint4 (8 bf16). States merged
// at the end with __shfl_xor(...,32): doubles gather/FMA ILP vs the serial single stream.
__global__ __launch_bounds__(256) void k_aggregate(const unsigned short* __restrict__ hb,
        const float* __restrict__ als, const float* __restrict__ ald,
        const float* __restrict__ ale, const float* __restrict__ alloop,
        const int* __restrict__ rs, const int* __restrict__ ssrc, const int* __restrict__ seid,
        const float* __restrict__ bias, float* __restrict__ outbuf){
    int n = blockIdx.x * 4 + (threadIdx.x >> 6);
    if (n >= N_) return;
    int lane = threadIdx.x & 63;
    int half = lane >> 5;
    int sl   = lane & 31;
    int col0 = sl * 8;          // 8 cols per lane
    int hd   = col0 >> 6;       // head (8 sublanes per head)
    float aldn = ald[(size_t)n * 4 + hd];
    float alp  = alloop[hd];
    int i0 = rs[n], i1 = rs[n + 1];
    float m = -3.0e38f, den = 0.f;
    float a0=0.f,a1=0.f,a2=0.f,a3=0.f,a4=0.f,a5=0.f,a6=0.f,a7=0.f;
    for (int i = i0 + half; i < i1; i += 2){
        int s   = ssrc[i];
        int eid = seid[i];
        float alE = (eid < E_) ? ale[(size_t)eid * 4 + hd] : alp;
        float lg = als[(size_t)s * 4 + hd] + aldn + alE;
        lg = lrelu(lg, NEG_ATT);
        float mn = fmaxf(m, lg);
        float sc = __expf(m - mn);
        float p  = __expf(lg - mn);
        den = den * sc + p;
        uint4 g = *reinterpret_cast<const uint4*>(hb + (size_t)s * 256 + col0);
        a0 = a0 * sc + p * bf16lo(g.x);  a1 = a1 * sc + p * bf16hi(g.x);
        a2 = a2 * sc + p * bf16lo(g.y);  a3 = a3 * sc + p * bf16hi(g.y);
        a4 = a4 * sc + p * bf16lo(g.z);  a5 = a5 * sc + p * bf16hi(g.z);
        a6 = a6 * sc + p * bf16lo(g.w);  a7 = a7 * sc + p * bf16hi(g.w);
        m = mn;
    }
    // merge the two half-streams (read partner state first, then combine)
    float mo  = __shfl_xor(m,   32, 64);
    float dno = __shfl_xor(den, 32, 64);
    float o0 = __shfl_xor(a0, 32, 64), o1 = __shfl_xor(a1, 32, 64);
    float o2 = __shfl_xor(a2, 32, 64), o3 = __shfl_xor(a3, 32, 64);
    float o4 = __shfl_xor(a4, 32, 64), o5 = __shfl_xor(a5, 32, 64);
    float o6 = __shfl_xor(a6, 32, 64), o7 = __shfl_xor(a7, 32, 64);
    float M   = fmaxf(m, mo);
    float scS = __expf(m - M);      // 0 if this stream empty
    float scO = __expf(mo - M);     // 0 if other stream empty
    den = den * scS + dno * scO;
    a0 = a0*scS + o0*scO;  a1 = a1*scS + o1*scO;
    a2 = a2*scS + o2*scO;  a3 = a3*scS + o3*scO;
    a4 = a4*scS + o4*scO;  a5 = a5*scS + o5*scO;
    a6 = a6*scS + o6*scO;  a7 = a7*scS + o7*scO;
    float inv = 1.f / den;
    // both halves hold identical merged results; half 0 writes cols [col0,col0+4),
    // half 1 writes [col0+4,col0+8): one coalesced 1KB store per wave.
    float v0, v1, v2, v3;
    if (half == 0){ v0 = a0; v1 = a1; v2 = a2; v3 = a3; }
    else          { v0 = a4; v1 = a5; v2 = a6; v3 = a7; }
    int wc = col0 + half * 4;
    float4 b4 = *reinterpret_cast<const float4*>(bias + wc);
    float4 r;
    r.x = lrelu(v0 * inv + b4.x, NEG_OUT);
    r.y = lrelu(v1 * inv + b4.y, NEG_OUT);
    r.z = lrelu(v2 * inv + b4.z, NEG_OUT);
    r.w = lrelu(v3 * inv + b4.w, NEG_OUT);
    *reinterpret_cast<float4*>(outbuf + (size_t)n * 256 + wc) = r;
}

// ---------- edge_index passthrough (fp32, bit-exact) ----------
__global__ void k_edge_store(const int* __restrict__ ei, float* __restrict__ out){
    int j = blockIdx.x * blockDim.x + threadIdx.x;     // 2E
    if (j >= (int)OUT1) return;
    out[j] = (float)ei[j];
}

extern "C" void kernel_launch(void* const* d_in, const int* in_sizes, int n_in,
                              void* d_out, int out_size, void* d_ws, size_t ws_size,
                              hipStream_t stream){
    const float* x    = (const float*)d_in[0];
    const int*   ei   = (const int*)d_in[1];
    const float* ea   = (const float*)d_in[2];
    const float* bn1g = (const float*)d_in[3];
    const float* bn1b = (const float*)d_in[4];
    const float* W1   = (const float*)d_in[5];
    const float* We1  = (const float*)d_in[6];
    const float* as1  = (const float*)d_in[7];
    const float* ad1  = (const float*)d_in[8];
    const float* ae1  = (const float*)d_in[9];
    const float* b1   = (const float*)d_in[10];
    const float* bn2g = (const float*)d_in[11];
    const float* bn2b = (const float*)d_in[12];
    const float* W2   = (const float*)d_in[13];
    const float* We2  = (const float*)d_in[14];
    const float* as2  = (const float*)d_in[15];
    const float* ad2  = (const float*)d_in[16];
    const float* ae2  = (const float*)d_in[17];
    const float* b2   = (const float*)d_in[18];
    float* out = (float*)d_out;

    bool ok = (n_in >= 19)
           && (in_sizes[0] == N_ * FIN)
           && (in_sizes[1] == 2 * E_)
           && (in_sizes[2] == E_ * 16)
           && (out_size == (int)(OUT0 + OUT1));
    if (!ok){ k_sentinel<<<1,1,0,stream>>>(out, 7777.f); return; }

    char* w = (char*)d_ws;
    size_t off = 0;
    auto alloc = [&](size_t bytes) -> void* {
        off = (off + 255) & ~(size_t)255;
        void* p = w + off;
        off += bytes;
        return p;
    };
    float* stats  = (float*)alloc(512 * 4);
    float* asum   = (float*)alloc(16 * 4);
    float* Vbuf   = (float*)alloc(64 * 4);
    float* alloop = (float*)alloc(4 * 4);
    float* als    = (float*)alloc((size_t)N_ * 4 * 4);
    float* ald    = (float*)alloc((size_t)N_ * 4 * 4);
    float* ale    = (float*)alloc((size_t)E_ * 4 * 4);          // 12.8MB
    int*   rs     = (int*)alloc((size_t)(N_ + 1) * 4);
    int*   counts = (int*)alloc((size_t)N_ * 4);
    int*   cursor = (int*)alloc((size_t)N_ * 4);
    int*   ssrc   = (int*)alloc((size_t)E2_ * 4);
    int*   seid   = (int*)alloc((size_t)E2_ * 4);
    unsigned short* WT1 = (unsigned short*)alloc((size_t)256 * FIN * 2);  // 64KB
    unsigned short* WT2 = (unsigned short*)alloc((size_t)256 * FH * 2);   // 128KB
    unsigned short* bufC = (unsigned short*)alloc((size_t)N_ * 256 * 2);  // 25.6MB bf16
    unsigned short* hbuf = (unsigned short*)alloc((size_t)N_ * 256 * 2);  // 25.6MB bf16
    float* bufB   = (float*)alloc((size_t)N_ * 256 * 4);                  // 51.2MB
    if (off > ws_size){ k_sentinel<<<1,1,0,stream>>>(out, 5555.f); return; }

    float* ssum = stats;
    float* ssq  = stats + 256;
    const int GX = cdiv(N_, 64);    // 782

    // ---- CSR build (shared by both layers) ----
    k_zero32<<<cdiv(N_,256),256,0,stream>>>((unsigned*)counts, N_);
    k_zero32<<<cdiv(N_,256),256,0,stream>>>((unsigned*)cursor, N_);
    k_count<<<cdiv(E2_,256),256,0,stream>>>(ei, counts);
    k_scan<<<1,1024,0,stream>>>(counts, rs);
    k_scatter<<<cdiv(E2_,256),256,0,stream>>>(ei, rs, cursor, ssrc, seid);

    // ---- shared precompute ----
    k_zero32<<<2,256,0,stream>>>((unsigned*)stats, 512);
    k_zero32<<<1,64,0,stream>>>((unsigned*)asum, 16);
    k_attr_sum<<<1024,256,0,stream>>>(ea, asum);
    k_w2t<<<FIN,256,0,stream>>>(W1, WT1, FIN);
    k_w2t<<<FH,256,0,stream>>>(W2, WT2, FH);

    // ---- BN1 + lrelu (bf16 out) ----
    k_bn_stats<<<256,256,0,stream>>>(x, FIN, ssum, ssq);
    k_bn_apply_bf<<<2048,256,0,stream>>>(x, ssum, ssq, bn1g, bn1b, bufC, FIN);

    // ---- GAT layer 1 ----
    k_gemm_mfma<<<dim3(GX,4),256,0,stream>>>(bufC, WT1, hbuf, N_, FIN);
    k_al<<<cdiv(N_,4),256,0,stream>>>(hbuf, as1, ad1, als, ald);
    k_prep<<<1,64,0,stream>>>(We1, ae1, asum, Vbuf, alloop);
    k_al_edge<<<cdiv(E_*4,256),256,0,stream>>>(ea, Vbuf, ale);
    k_aggregate<<<cdiv(N_,4),256,0,stream>>>(hbuf, als, ald, ale, alloop,
                                             rs, ssrc, seid, b1, bufB);

    // ---- BN2 + lrelu (bf16 out) ----
    k_zero32<<<2,256,0,stream>>>((unsigned*)stats, 512);
    k_bn_stats<<<256,256,0,stream>>>(bufB, FH, ssum, ssq);
    k_bn_apply_bf<<<2048,256,0,stream>>>(bufB, ssum, ssq, bn2g, bn2b, bufC, FH);

    // ---- GAT layer 2 ----
    k_gemm_mfma<<<dim3(GX,4),256,0,stream>>>(bufC, WT2, hbuf, N_, FH);
    k_al<<<cdiv(N_,4),256,0,stream>>>(hbuf, as2, ad2, als, ald);
    k_prep<<<1,64,0,stream>>>(We2, ae2, asum, Vbuf, alloop);
    k_al_edge<<<cdiv(E_*4,256),256,0,stream>>>(ea, Vbuf, ale);
    k_aggregate<<<cdiv(N_,4),256,0,stream>>>(hbuf, als, ald, ale, alloop,
                                             rs, ssrc, seid, b2, out);

    // ---- edge_index passthrough ----
    k_edge_store<<<cdiv((int)OUT1,256),256,0,stream>>>(ei, out + OUT0);
}

// Round 10
// 656.901 us; speedup vs baseline: 10.6463x; 1.0402x over previous
//
#include <hip/hip_runtime.h>
#include <hip/hip_bf16.h>

// Problem constants
constexpr int N_  = 50000;
constexpr int E_  = 800000;
constexpr int E2_ = 850000;   // E + N self loops
constexpr int FIN = 128;
constexpr int FH  = 256;      // H * C = 4 * 64
constexpr float BN_EPS = 1e-5f;
constexpr float NEG_ATT = 0.2f;
constexpr float NEG_OUT = 0.1f;
constexpr size_t OUT0 = (size_t)N_ * FH;   // 12.8M feature elems (fp32)
constexpr size_t OUT1 = (size_t)2 * E_;    // 1.6M edge elems (fp32)

static inline int cdiv(int a, int b){ return (a + b - 1) / b; }

using short8 = __attribute__((ext_vector_type(8))) short;
using f32x4  = __attribute__((ext_vector_type(4))) float;

__device__ inline float lrelu(float v, float ns){ return v > 0.f ? v : ns * v; }

__device__ inline unsigned short bf16rne(float f){
    unsigned u = __float_as_uint(f);
    u += 0x7fffu + ((u >> 16) & 1u);
    return (unsigned short)(u >> 16);
}
__device__ inline float bf16lo(unsigned u){ return __uint_as_float(u << 16); }
__device__ inline float bf16hi(unsigned u){ return __uint_as_float(u & 0xffff0000u); }
__device__ inline float bf16f(unsigned short v){ return __uint_as_float((unsigned)v << 16); }

__global__ void k_sentinel(float* out, float v){ out[0] = v; }

__global__ void k_zero32(unsigned* p, int n){
    int i = blockIdx.x * blockDim.x + threadIdx.x;
    if (i < n) p[i] = 0u;
}

// ---------- W [K][256] fp32 -> WT [256][K] bf16 ----------
__global__ void k_w2t(const float* __restrict__ W, unsigned short* __restrict__ WT, int K){
    int i = blockIdx.x * blockDim.x + threadIdx.x;
    if (i >= K * 256) return;
    int k = i >> 8, c = i & 255;
    WT[(size_t)c * K + k] = bf16rne(W[i]);
}

// ---------- BatchNorm stats (fp32 input) ----------
__global__ void k_bn_stats(const float* __restrict__ x, int F,
                           float* __restrict__ sum, float* __restrict__ sumsq){
    int gid = blockIdx.x * blockDim.x + threadIdx.x;
    int T = gridDim.x * blockDim.x;      // 65536
    int c = gid % F;
    int r0 = gid / F;
    int rstep = T / F;
    float s = 0.f, s2 = 0.f;
    for (int r = r0; r < N_; r += rstep){
        float v = x[(size_t)r * F + c];
        s += v; s2 += v * v;
    }
    atomicAdd(&sum[c], s);
    atomicAdd(&sumsq[c], s2);
}

// ---------- BatchNorm stats (bf16 input) ----------
__global__ void k_bn_stats_b16(const unsigned short* __restrict__ x, int F,
                               float* __restrict__ sum, float* __restrict__ sumsq){
    int gid = blockIdx.x * blockDim.x + threadIdx.x;
    int T = gridDim.x * blockDim.x;
    int c = gid % F;
    int r0 = gid / F;
    int rstep = T / F;
    float s = 0.f, s2 = 0.f;
    for (int r = r0; r < N_; r += rstep){
        float v = bf16f(x[(size_t)r * F + c]);
        s += v; s2 += v * v;
    }
    atomicAdd(&sum[c], s);
    atomicAdd(&sumsq[c], s2);
}

// BN + lrelu, fp32 in -> bf16 out
__global__ void k_bn_apply_bf(const float* __restrict__ x, const float* __restrict__ sum,
                              const float* __restrict__ sumsq, const float* __restrict__ gamma,
                              const float* __restrict__ beta, unsigned short* __restrict__ out, int F){
    size_t tot = (size_t)N_ * F;
    size_t step = (size_t)gridDim.x * blockDim.x;
    for (size_t i = blockIdx.x * (size_t)blockDim.x + threadIdx.x; i < tot; i += step){
        int c = (int)(i % F);
        float mean = sum[c] / (float)N_;
        float var = sumsq[c] / (float)N_ - mean * mean;
        float v = (x[i] - mean) * rsqrtf(var + BN_EPS) * gamma[c] + beta[c];
        out[i] = bf16rne(lrelu(v, NEG_OUT));
    }
}

// BN + lrelu, bf16 in -> bf16 out
__global__ void k_bn_apply_b16(const unsigned short* __restrict__ x, const float* __restrict__ sum,
                               const float* __restrict__ sumsq, const float* __restrict__ gamma,
                               const float* __restrict__ beta, unsigned short* __restrict__ out, int F){
    size_t tot = (size_t)N_ * F;
    size_t step = (size_t)gridDim.x * blockDim.x;
    for (size_t i = blockIdx.x * (size_t)blockDim.x + threadIdx.x; i < tot; i += step){
        int c = (int)(i % F);
        float mean = sum[c] / (float)N_;
        float var = sumsq[c] / (float)N_ - mean * mean;
        float v = (bf16f(x[i]) - mean) * rsqrtf(var + BN_EPS) * gamma[c] + beta[c];
        out[i] = bf16rne(lrelu(v, NEG_OUT));
    }
}

// ---------- MFMA GEMM: C[M x 256] = A[M x K] @ B[K x 256] (A,WT,C all bf16) ----------
__global__ __launch_bounds__(256) void k_gemm_mfma(const unsigned short* __restrict__ A,
                                                   const unsigned short* __restrict__ WT,
                                                   unsigned short* __restrict__ C, int M, int K){
    __shared__ unsigned short Al[64][32];   // 4KB
    __shared__ unsigned short Bl[64][32];   // 4KB  (Bl[col][k])
    int tid = threadIdx.x;
    int w = tid >> 6;
    int l = tid & 63;
    int row0 = blockIdx.x * 64;
    int col0 = blockIdx.y * 64;
    f32x4 acc[4];
    #pragma unroll
    for (int m = 0; m < 4; ++m) acc[m] = (f32x4){0.f, 0.f, 0.f, 0.f};

    int srow = tid >> 2;
    int skq  = (tid & 3) * 8;

    for (int k0 = 0; k0 < K; k0 += 32){
        {
            short8 v = {0,0,0,0,0,0,0,0};
            if (row0 + srow < M)
                v = *reinterpret_cast<const short8*>(A + (size_t)(row0 + srow) * K + k0 + skq);
            *reinterpret_cast<short8*>(&Al[srow][skq]) = v;
        }
        {
            short8 v = *reinterpret_cast<const short8*>(WT + (size_t)(col0 + srow) * K + k0 + skq);
            *reinterpret_cast<short8*>(&Bl[srow][skq]) = v;
        }
        __syncthreads();
        short8 b = *reinterpret_cast<const short8*>(&Bl[w * 16 + (l & 15)][8 * (l >> 4)]);
        #pragma unroll
        for (int m = 0; m < 4; ++m){
            short8 a = *reinterpret_cast<const short8*>(&Al[m * 16 + (l & 15)][8 * (l >> 4)]);
            acc[m] = __builtin_amdgcn_mfma_f32_16x16x32_bf16(a, b, acc[m], 0, 0, 0);
        }
        __syncthreads();
    }
    int ccol = col0 + w * 16 + (l & 15);
    #pragma unroll
    for (int m = 0; m < 4; ++m){
        #pragma unroll
        for (int r = 0; r < 4; ++r){
            int row = row0 + m * 16 + (l >> 4) * 4 + r;
            if (row < M) C[(size_t)row * 256 + ccol] = bf16rne(acc[m][r]);
        }
    }
}

// ---------- per-node attention terms: one wave per node, bf16 h ----------
__global__ __launch_bounds__(256) void k_al(const unsigned short* __restrict__ hb,
                                            const float* __restrict__ asrc,
                                            const float* __restrict__ adst,
                                            float* __restrict__ als, float* __restrict__ ald){
    int n = blockIdx.x * 4 + (threadIdx.x >> 6);
    if (n >= N_) return;
    int lane = threadIdx.x & 63;
    uint2 g = *reinterpret_cast<const uint2*>(hb + (size_t)n * 256 + lane * 4);
    float h0 = bf16lo(g.x), h1 = bf16hi(g.x), h2 = bf16lo(g.y), h3 = bf16hi(g.y);
    float4 as = *reinterpret_cast<const float4*>(asrc + lane * 4);
    float4 ad = *reinterpret_cast<const float4*>(adst + lane * 4);
    float ps = h0*as.x + h1*as.y + h2*as.z + h3*as.w;
    float pd = h0*ad.x + h1*ad.y + h2*ad.z + h3*ad.w;
    #pragma unroll
    for (int m = 1; m < 16; m <<= 1){
        ps += __shfl_xor(ps, m, 64);
        pd += __shfl_xor(pd, m, 64);
    }
    if ((lane & 15) == 0){
        int hd = lane >> 4;
        als[(size_t)n*4 + hd] = ps;
        ald[(size_t)n*4 + hd] = pd;
    }
}

// ---------- edge_attr column sums ----------
__global__ __launch_bounds__(256) void k_attr_sum(const float* __restrict__ ea,
                                                  float* __restrict__ asum){
    __shared__ float4 sdata[256];
    int tid = threadIdx.x;
    size_t gid = (size_t)blockIdx.x * 256 + tid;
    size_t step = (size_t)gridDim.x * 256;
    const float4* p = reinterpret_cast<const float4*>(ea);
    float4 acc = make_float4(0.f, 0.f, 0.f, 0.f);
    for (size_t j = gid; j < (size_t)E_ * 4; j += step){
        float4 v = p[j];
        acc.x += v.x; acc.y += v.y; acc.z += v.z; acc.w += v.w;
    }
    sdata[tid] = acc;
    __syncthreads();
    #pragma unroll
    for (int s = 128; s >= 4; s >>= 1){
        if (tid < s){
            float4 o = sdata[tid + s];
            float4 m = sdata[tid];
            m.x += o.x; m.y += o.y; m.z += o.z; m.w += o.w;
            sdata[tid] = m;
        }
        __syncthreads();
    }
    if (tid < 4){
        float4 m = sdata[tid];
        atomicAdd(&asum[tid*4+0], m.x);
        atomicAdd(&asum[tid*4+1], m.y);
        atomicAdd(&asum[tid*4+2], m.z);
        atomicAdd(&asum[tid*4+3], m.w);
    }
}

// ---------- V[k][h]; alloop[h] ----------
__global__ void k_prep(const float* __restrict__ We, const float* __restrict__ aedge,
                       const float* __restrict__ asum, float* __restrict__ V,
                       float* __restrict__ alloop){
    __shared__ float Vs[64];
    int t = threadIdx.x;  // 64 threads
    int k = t >> 2, hd = t & 3;
    float s = 0.f;
    for (int c = 0; c < 64; ++c) s += We[k * 256 + hd * 64 + c] * aedge[hd * 64 + c];
    Vs[t] = s;
    V[t] = s;
    __syncthreads();
    if (t < 4){
        float r = 0.f;
        for (int kk = 0; kk < 16; ++kk) r += (asum[kk] / (float)E_) * Vs[kk * 4 + t];
        alloop[t] = r;
    }
}

// ---------- al_edge ----------
__global__ void k_al_edge(const float* __restrict__ ea, const float* __restrict__ V,
                          float* __restrict__ ale){
    int idx = blockIdx.x * blockDim.x + threadIdx.x;   // E*4
    if (idx >= E_ * 4) return;
    int e = idx >> 2, hd = idx & 3;
    const float* ep = ea + (size_t)e * 16;
    float s = 0.f;
    #pragma unroll
    for (int k = 0; k < 16; ++k) s += ep[k] * V[k * 4 + hd];
    ale[idx] = s;
}

// ---------- CSR build ----------
__global__ void k_count(const int* __restrict__ ei, int* __restrict__ counts){
    int e = blockIdx.x * blockDim.x + threadIdx.x;
    if (e >= E2_) return;
    int d = (e < E_) ? ei[E_ + e] : (e - E_);
    atomicAdd(&counts[d], 1);
}

__global__ __launch_bounds__(1024) void k_scan(const int* __restrict__ counts, int* __restrict__ rs){
    __shared__ int sdata[1024];
    int t = threadIdx.x;
    const int CH = (N_ + 1023) / 1024;   // 49
    int base = t * CH;
    int s = 0;
    for (int i = 0; i < CH; ++i){
        int idx = base + i;
        if (idx < N_) s += counts[idx];
    }
    sdata[t] = s;
    __syncthreads();
    for (int off = 1; off < 1024; off <<= 1){
        int v = (t >= off) ? sdata[t - off] : 0;
        __syncthreads();
        sdata[t] += v;
        __syncthreads();
    }
    int run = (t > 0) ? sdata[t - 1] : 0;
    for (int i = 0; i < CH; ++i){
        int idx = base + i;
        if (idx < N_){ rs[idx] = run; run += counts[idx]; }
    }
    if (t == 1023) rs[N_] = E2_;
}

__global__ void k_scatter(const int* __restrict__ ei, const int* __restrict__ rs,
                          int* __restrict__ cursor, int* __restrict__ ssrc, int* __restrict__ seid){
    int e = blockIdx.x * blockDim.x + threadIdx.x;
    if (e >= E2_) return;
    int s, d;
    if (e < E_){ s = ei[e]; d = ei[E_ + e]; }
    else { s = e - E_; d = s; }
    int slot = rs[d] + atomicAdd(&cursor[d], 1);
    ssrc[slot] = s;
    seid[slot] = e;
}

// ---------- one wave per dst node, FOUR independent edge streams (16 lanes each) ----------
// lane = (q = lane>>4, sl = lane&15). Stream q processes CSR slots i0+q, i0+q+4, ...
// lane sl covers 16 features [sl*16, sl*16+16) via 2x uint4 (16 lanes x 32B = 512B row).
// 4 online-softmax states merged with shfl_xor(16) then shfl_xor(32).
#define MERGE4(OFF) { \
    float mo  = __shfl_xor(m,   OFF, 64); \
    float dno = __shfl_xor(den, OFF, 64); \
    float o0=__shfl_xor(a0,OFF,64), o1=__shfl_xor(a1,OFF,64), o2=__shfl_xor(a2,OFF,64), o3=__shfl_xor(a3,OFF,64); \
    float o4=__shfl_xor(a4,OFF,64), o5=__shfl_xor(a5,OFF,64), o6=__shfl_xor(a6,OFF,64), o7=__shfl_xor(a7,OFF,64); \
    float o8=__shfl_xor(a8,OFF,64), o9=__shfl_xor(a9,OFF,64), oA=__shfl_xor(aA,OFF,64), oB=__shfl_xor(aB,OFF,64); \
    float oC=__shfl_xor(aC,OFF,64), oD=__shfl_xor(aD,OFF,64), oE=__shfl_xor(aE,OFF,64), oF=__shfl_xor(aF,OFF,64); \
    float M = fmaxf(m, mo); \
    float sS = __expf(m - M), sO = __expf(mo - M); \
    den = den*sS + dno*sO; \
    a0=a0*sS+o0*sO; a1=a1*sS+o1*sO; a2=a2*sS+o2*sO; a3=a3*sS+o3*sO; \
    a4=a4*sS+o4*sO; a5=a5*sS+o5*sO; a6=a6*sS+o6*sO; a7=a7*sS+o7*sO; \
    a8=a8*sS+o8*sO; a9=a9*sS+o9*sO; aA=aA*sS+oA*sO; aB=aB*sS+oB*sO; \
    aC=aC*sS+oC*sO; aD=aD*sS+oD*sO; aE=aE*sS+oE*sO; aF=aF*sS+oF*sO; \
    m = M; }

template<bool BF16OUT>
__global__ __launch_bounds__(256) void k_aggregate4(const unsigned short* __restrict__ hb,
        const float* __restrict__ als, const float* __restrict__ ald,
        const float* __restrict__ ale, const float* __restrict__ alloop,
        const int* __restrict__ rs, const int* __restrict__ ssrc, const int* __restrict__ seid,
        const float* __restrict__ bias, void* __restrict__ outp){
    int n = blockIdx.x * 4 + (threadIdx.x >> 6);
    if (n >= N_) return;
    int lane = threadIdx.x & 63;
    int q  = lane >> 4;
    int sl = lane & 15;
    int col0 = sl * 16;
    int hd = sl >> 2;
    float aldn = ald[(size_t)n * 4 + hd];
    float alp  = alloop[hd];
    int i0 = rs[n], i1 = rs[n + 1];
    float m = -3.0e38f, den = 0.f;
    float a0=0.f,a1=0.f,a2=0.f,a3=0.f,a4=0.f,a5=0.f,a6=0.f,a7=0.f;
    float a8=0.f,a9=0.f,aA=0.f,aB=0.f,aC=0.f,aD=0.f,aE=0.f,aF=0.f;
    for (int i = i0 + q; i < i1; i += 4){
        int s   = ssrc[i];
        int eid = seid[i];
        float alE = (eid < E_) ? ale[(size_t)eid * 4 + hd] : alp;
        float lg = als[(size_t)s * 4 + hd] + aldn + alE;
        lg = lrelu(lg, NEG_ATT);
        float mn = fmaxf(m, lg);
        float sc = __expf(m - mn);
        float p  = __expf(lg - mn);
        den = den * sc + p;
        const unsigned short* hp = hb + (size_t)s * 256 + col0;
        uint4 g0 = *reinterpret_cast<const uint4*>(hp);
        uint4 g1 = *reinterpret_cast<const uint4*>(hp + 8);
        a0 = a0*sc + p*bf16lo(g0.x);  a1 = a1*sc + p*bf16hi(g0.x);
        a2 = a2*sc + p*bf16lo(g0.y);  a3 = a3*sc + p*bf16hi(g0.y);
        a4 = a4*sc + p*bf16lo(g0.z);  a5 = a5*sc + p*bf16hi(g0.z);
        a6 = a6*sc + p*bf16lo(g0.w);  a7 = a7*sc + p*bf16hi(g0.w);
        a8 = a8*sc + p*bf16lo(g1.x);  a9 = a9*sc + p*bf16hi(g1.x);
        aA = aA*sc + p*bf16lo(g1.y);  aB = aB*sc + p*bf16hi(g1.y);
        aC = aC*sc + p*bf16lo(g1.z);  aD = aD*sc + p*bf16hi(g1.z);
        aE = aE*sc + p*bf16lo(g1.w);  aF = aF*sc + p*bf16hi(g1.w);
        m = mn;
    }
    MERGE4(16)
    MERGE4(32)
    float inv = 1.f / den;
    // quarter q writes features [col0 + q*4, col0 + q*4 + 4)
    float v0, v1, v2, v3;
    if      (q == 0){ v0 = a0; v1 = a1; v2 = a2; v3 = a3; }
    else if (q == 1){ v0 = a4; v1 = a5; v2 = a6; v3 = a7; }
    else if (q == 2){ v0 = a8; v1 = a9; v2 = aA; v3 = aB; }
    else            { v0 = aC; v1 = aD; v2 = aE; v3 = aF; }
    int wc = col0 + q * 4;
    float4 b4 = *reinterpret_cast<const float4*>(bias + wc);
    float r0 = lrelu(v0 * inv + b4.x, NEG_OUT);
    float r1 = lrelu(v1 * inv + b4.y, NEG_OUT);
    float r2 = lrelu(v2 * inv + b4.z, NEG_OUT);
    float r3 = lrelu(v3 * inv + b4.w, NEG_OUT);
    if (BF16OUT){
        ushort4 pk;
        pk.x = bf16rne(r0); pk.y = bf16rne(r1); pk.z = bf16rne(r2); pk.w = bf16rne(r3);
        *reinterpret_cast<ushort4*>((unsigned short*)outp + (size_t)n * 256 + wc) = pk;
    } else {
        *reinterpret_cast<float4*>((float*)outp + (size_t)n * 256 + wc) =
            make_float4(r0, r1, r2, r3);
    }
}

// ---------- edge_index passthrough (fp32, bit-exact) ----------
__global__ void k_edge_store(const int* __restrict__ ei, float* __restrict__ out){
    int j = blockIdx.x * blockDim.x + threadIdx.x;     // 2E
    if (j >= (int)OUT1) return;
    out[j] = (float)ei[j];
}

extern "C" void kernel_launch(void* const* d_in, const int* in_sizes, int n_in,
                              void* d_out, int out_size, void* d_ws, size_t ws_size,
                              hipStream_t stream){
    const float* x    = (const float*)d_in[0];
    const int*   ei   = (const int*)d_in[1];
    const float* ea   = (const float*)d_in[2];
    const float* bn1g = (const float*)d_in[3];
    const float* bn1b = (const float*)d_in[4];
    const float* W1   = (const float*)d_in[5];
    const float* We1  = (const float*)d_in[6];
    const float* as1  = (const float*)d_in[7];
    const float* ad1  = (const float*)d_in[8];
    const float* ae1  = (const float*)d_in[9];
    const float* b1   = (const float*)d_in[10];
    const float* bn2g = (const float*)d_in[11];
    const float* bn2b = (const float*)d_in[12];
    const float* W2   = (const float*)d_in[13];
    const float* We2  = (const float*)d_in[14];
    const float* as2  = (const float*)d_in[15];
    const float* ad2  = (const float*)d_in[16];
    const float* ae2  = (const float*)d_in[17];
    const float* b2   = (const float*)d_in[18];
    float* out = (float*)d_out;

    bool ok = (n_in >= 19)
           && (in_sizes[0] == N_ * FIN)
           && (in_sizes[1] == 2 * E_)
           && (in_sizes[2] == E_ * 16)
           && (out_size == (int)(OUT0 + OUT1));
    if (!ok){ k_sentinel<<<1,1,0,stream>>>(out, 7777.f); return; }

    char* w = (char*)d_ws;
    size_t off = 0;
    auto alloc = [&](size_t bytes) -> void* {
        off = (off + 255) & ~(size_t)255;
        void* p = w + off;
        off += bytes;
        return p;
    };
    float* stats  = (float*)alloc(512 * 4);
    float* asum   = (float*)alloc(16 * 4);
    float* Vbuf   = (float*)alloc(64 * 4);
    float* alloop = (float*)alloc(4 * 4);
    float* als    = (float*)alloc((size_t)N_ * 4 * 4);
    float* ald    = (float*)alloc((size_t)N_ * 4 * 4);
    float* ale    = (float*)alloc((size_t)E_ * 4 * 4);          // 12.8MB
    int*   rs     = (int*)alloc((size_t)(N_ + 1) * 4);
    int*   counts = (int*)alloc((size_t)N_ * 4);
    int*   cursor = (int*)alloc((size_t)N_ * 4);
    int*   ssrc   = (int*)alloc((size_t)E2_ * 4);
    int*   seid   = (int*)alloc((size_t)E2_ * 4);
    unsigned short* WT1 = (unsigned short*)alloc((size_t)256 * FIN * 2);  // 64KB
    unsigned short* WT2 = (unsigned short*)alloc((size_t)256 * FH * 2);   // 128KB
    unsigned short* bufC = (unsigned short*)alloc((size_t)N_ * 256 * 2);  // 25.6MB bf16
    unsigned short* hbuf = (unsigned short*)alloc((size_t)N_ * 256 * 2);  // 25.6MB bf16
    unsigned short* bufB = (unsigned short*)alloc((size_t)N_ * 256 * 2);  // 25.6MB bf16 (layer-1 out)
    if (off > ws_size){ k_sentinel<<<1,1,0,stream>>>(out, 5555.f); return; }

    float* ssum = stats;
    float* ssq  = stats + 256;
    const int GX = cdiv(N_, 64);    // 782

    // ---- CSR build (shared by both layers) ----
    k_zero32<<<cdiv(N_,256),256,0,stream>>>((unsigned*)counts, N_);
    k_zero32<<<cdiv(N_,256),256,0,stream>>>((unsigned*)cursor, N_);
    k_count<<<cdiv(E2_,256),256,0,stream>>>(ei, counts);
    k_scan<<<1,1024,0,stream>>>(counts, rs);
    k_scatter<<<cdiv(E2_,256),256,0,stream>>>(ei, rs, cursor, ssrc, seid);

    // ---- shared precompute ----
    k_zero32<<<2,256,0,stream>>>((unsigned*)stats, 512);
    k_zero32<<<1,64,0,stream>>>((unsigned*)asum, 16);
    k_attr_sum<<<1024,256,0,stream>>>(ea, asum);
    k_w2t<<<FIN,256,0,stream>>>(W1, WT1, FIN);
    k_w2t<<<FH,256,0,stream>>>(W2, WT2, FH);

    // ---- BN1 + lrelu (fp32 -> bf16) ----
    k_bn_stats<<<256,256,0,stream>>>(x, FIN, ssum, ssq);
    k_bn_apply_bf<<<2048,256,0,stream>>>(x, ssum, ssq, bn1g, bn1b, bufC, FIN);

    // ---- GAT layer 1 ----
    k_gemm_mfma<<<dim3(GX,4),256,0,stream>>>(bufC, WT1, hbuf, N_, FIN);
    k_al<<<cdiv(N_,4),256,0,stream>>>(hbuf, as1, ad1, als, ald);
    k_prep<<<1,64,0,stream>>>(We1, ae1, asum, Vbuf, alloop);
    k_al_edge<<<cdiv(E_*4,256),256,0,stream>>>(ea, Vbuf, ale);
    k_aggregate4<true><<<cdiv(N_,4),256,0,stream>>>(hbuf, als, ald, ale, alloop,
                                                    rs, ssrc, seid, b1, bufB);

    // ---- BN2 + lrelu (bf16 -> bf16) ----
    k_zero32<<<2,256,0,stream>>>((unsigned*)stats, 512);
    k_bn_stats_b16<<<256,256,0,stream>>>(bufB, FH, ssum, ssq);
    k_bn_apply_b16<<<2048,256,0,stream>>>(bufB, ssum, ssq, bn2g, bn2b, bufC, FH);

    // ---- GAT layer 2 ----
    k_gemm_mfma<<<dim3(GX,4),256,0,stream>>>(bufC, WT2, hbuf, N_, FH);
    k_al<<<cdiv(N_,4),256,0,stream>>>(hbuf, as2, ad2, als, ald);
    k_prep<<<1,64,0,stream>>>(We2, ae2, asum, Vbuf, alloop);
    k_al_edge<<<cdiv(E_*4,256),256,0,stream>>>(ea, Vbuf, ale);
    k_aggregate4<false><<<cdiv(N_,4),256,0,stream>>>(hbuf, als, ald, ale, alloop,
                                                     rs, ssrc, seid, b2, out);

    // ---- edge_index passthrough ----
    k_edge_store<<<cdiv((int)OUT1,256),256,0,stream>>>(ei, out + OUT0);
}

// Round 11
// 573.962 us; speedup vs baseline: 12.1848x; 1.1445x over previous
//
#include <hip/hip_runtime.h>
#include <hip/hip_bf16.h>

// Problem constants
constexpr int N_  = 50000;
constexpr int E_  = 800000;
constexpr int E2_ = 850000;   // E + N self loops
constexpr int FIN = 128;
constexpr int FH  = 256;      // H * C = 4 * 64
constexpr float BN_EPS = 1e-5f;
constexpr float NEG_ATT = 0.2f;
constexpr float NEG_OUT = 0.1f;
constexpr size_t OUT0 = (size_t)N_ * FH;   // 12.8M feature elems (fp32)
constexpr size_t OUT1 = (size_t)2 * E_;    // 1.6M edge elems (fp32)
constexpr int SCAN_NBLK = (N_ + 255) / 256;   // 196

static inline int cdiv(int a, int b){ return (a + b - 1) / b; }

using short8 = __attribute__((ext_vector_type(8))) short;
using f32x4  = __attribute__((ext_vector_type(4))) float;

__device__ inline float lrelu(float v, float ns){ return v > 0.f ? v : ns * v; }

__device__ inline unsigned short bf16rne(float f){
    unsigned u = __float_as_uint(f);
    u += 0x7fffu + ((u >> 16) & 1u);
    return (unsigned short)(u >> 16);
}
__device__ inline float bf16lo(unsigned u){ return __uint_as_float(u << 16); }
__device__ inline float bf16hi(unsigned u){ return __uint_as_float(u & 0xffff0000u); }
__device__ inline float bf16f(unsigned short v){ return __uint_as_float((unsigned)v << 16); }

__global__ void k_sentinel(float* out, float v){ out[0] = v; }

__global__ void k_zero32(unsigned* p, int n){
    int i = blockIdx.x * blockDim.x + threadIdx.x;
    if (i < n) p[i] = 0u;
}

// ---------- W [K][256] fp32 -> WT [256][K] bf16 ----------
__global__ void k_w2t(const float* __restrict__ W, unsigned short* __restrict__ WT, int K){
    int i = blockIdx.x * blockDim.x + threadIdx.x;
    if (i >= K * 256) return;
    int k = i >> 8, c = i & 255;
    WT[(size_t)c * K + k] = bf16rne(W[i]);
}

// ---------- BatchNorm stats (fp32 input) ----------
__global__ void k_bn_stats(const float* __restrict__ x, int F,
                           float* __restrict__ sum, float* __restrict__ sumsq){
    int gid = blockIdx.x * blockDim.x + threadIdx.x;
    int T = gridDim.x * blockDim.x;      // 65536
    int c = gid % F;
    int r0 = gid / F;
    int rstep = T / F;
    float s = 0.f, s2 = 0.f;
    for (int r = r0; r < N_; r += rstep){
        float v = x[(size_t)r * F + c];
        s += v; s2 += v * v;
    }
    atomicAdd(&sum[c], s);
    atomicAdd(&sumsq[c], s2);
}

// ---------- BatchNorm stats (bf16 input) ----------
__global__ void k_bn_stats_b16(const unsigned short* __restrict__ x, int F,
                               float* __restrict__ sum, float* __restrict__ sumsq){
    int gid = blockIdx.x * blockDim.x + threadIdx.x;
    int T = gridDim.x * blockDim.x;
    int c = gid % F;
    int r0 = gid / F;
    int rstep = T / F;
    float s = 0.f, s2 = 0.f;
    for (int r = r0; r < N_; r += rstep){
        float v = bf16f(x[(size_t)r * F + c]);
        s += v; s2 += v * v;
    }
    atomicAdd(&sum[c], s);
    atomicAdd(&sumsq[c], s2);
}

// BN + lrelu, fp32 in -> bf16 out
__global__ void k_bn_apply_bf(const float* __restrict__ x, const float* __restrict__ sum,
                              const float* __restrict__ sumsq, const float* __restrict__ gamma,
                              const float* __restrict__ beta, unsigned short* __restrict__ out, int F){
    size_t tot = (size_t)N_ * F;
    size_t step = (size_t)gridDim.x * blockDim.x;
    for (size_t i = blockIdx.x * (size_t)blockDim.x + threadIdx.x; i < tot; i += step){
        int c = (int)(i % F);
        float mean = sum[c] / (float)N_;
        float var = sumsq[c] / (float)N_ - mean * mean;
        float v = (x[i] - mean) * rsqrtf(var + BN_EPS) * gamma[c] + beta[c];
        out[i] = bf16rne(lrelu(v, NEG_OUT));
    }
}

// BN + lrelu, bf16 in -> bf16 out
__global__ void k_bn_apply_b16(const unsigned short* __restrict__ x, const float* __restrict__ sum,
                               const float* __restrict__ sumsq, const float* __restrict__ gamma,
                               const float* __restrict__ beta, unsigned short* __restrict__ out, int F){
    size_t tot = (size_t)N_ * F;
    size_t step = (size_t)gridDim.x * blockDim.x;
    for (size_t i = blockIdx.x * (size_t)blockDim.x + threadIdx.x; i < tot; i += step){
        int c = (int)(i % F);
        float mean = sum[c] / (float)N_;
        float var = sumsq[c] / (float)N_ - mean * mean;
        float v = (bf16f(x[i]) - mean) * rsqrtf(var + BN_EPS) * gamma[c] + beta[c];
        out[i] = bf16rne(lrelu(v, NEG_OUT));
    }
}

// ---------- MFMA GEMM: C[M x 256] = A[M x K] @ B[K x 256] (A,WT,C all bf16) ----------
__global__ __launch_bounds__(256) void k_gemm_mfma(const unsigned short* __restrict__ A,
                                                   const unsigned short* __restrict__ WT,
                                                   unsigned short* __restrict__ C, int M, int K){
    __shared__ unsigned short Al[64][32];   // 4KB
    __shared__ unsigned short Bl[64][32];   // 4KB  (Bl[col][k])
    int tid = threadIdx.x;
    int w = tid >> 6;
    int l = tid & 63;
    int row0 = blockIdx.x * 64;
    int col0 = blockIdx.y * 64;
    f32x4 acc[4];
    #pragma unroll
    for (int m = 0; m < 4; ++m) acc[m] = (f32x4){0.f, 0.f, 0.f, 0.f};

    int srow = tid >> 2;
    int skq  = (tid & 3) * 8;

    for (int k0 = 0; k0 < K; k0 += 32){
        {
            short8 v = {0,0,0,0,0,0,0,0};
            if (row0 + srow < M)
                v = *reinterpret_cast<const short8*>(A + (size_t)(row0 + srow) * K + k0 + skq);
            *reinterpret_cast<short8*>(&Al[srow][skq]) = v;
        }
        {
            short8 v = *reinterpret_cast<const short8*>(WT + (size_t)(col0 + srow) * K + k0 + skq);
            *reinterpret_cast<short8*>(&Bl[srow][skq]) = v;
        }
        __syncthreads();
        short8 b = *reinterpret_cast<const short8*>(&Bl[w * 16 + (l & 15)][8 * (l >> 4)]);
        #pragma unroll
        for (int m = 0; m < 4; ++m){
            short8 a = *reinterpret_cast<const short8*>(&Al[m * 16 + (l & 15)][8 * (l >> 4)]);
            acc[m] = __builtin_amdgcn_mfma_f32_16x16x32_bf16(a, b, acc[m], 0, 0, 0);
        }
        __syncthreads();
    }
    int ccol = col0 + w * 16 + (l & 15);
    #pragma unroll
    for (int m = 0; m < 4; ++m){
        #pragma unroll
        for (int r = 0; r < 4; ++r){
            int row = row0 + m * 16 + (l >> 4) * 4 + r;
            if (row < M) C[(size_t)row * 256 + ccol] = bf16rne(acc[m][r]);
        }
    }
}

// ---------- per-node attention terms: one wave per node, bf16 h ----------
__global__ __launch_bounds__(256) void k_al(const unsigned short* __restrict__ hb,
                                            const float* __restrict__ asrc,
                                            const float* __restrict__ adst,
                                            float* __restrict__ als, float* __restrict__ ald){
    int n = blockIdx.x * 4 + (threadIdx.x >> 6);
    if (n >= N_) return;
    int lane = threadIdx.x & 63;
    uint2 g = *reinterpret_cast<const uint2*>(hb + (size_t)n * 256 + lane * 4);
    float h0 = bf16lo(g.x), h1 = bf16hi(g.x), h2 = bf16lo(g.y), h3 = bf16hi(g.y);
    float4 as = *reinterpret_cast<const float4*>(asrc + lane * 4);
    float4 ad = *reinterpret_cast<const float4*>(adst + lane * 4);
    float ps = h0*as.x + h1*as.y + h2*as.z + h3*as.w;
    float pd = h0*ad.x + h1*ad.y + h2*ad.z + h3*ad.w;
    #pragma unroll
    for (int m = 1; m < 16; m <<= 1){
        ps += __shfl_xor(ps, m, 64);
        pd += __shfl_xor(pd, m, 64);
    }
    if ((lane & 15) == 0){
        int hd = lane >> 4;
        als[(size_t)n*4 + hd] = ps;
        ald[(size_t)n*4 + hd] = pd;
    }
}

// ---------- edge_attr column sums ----------
__global__ __launch_bounds__(256) void k_attr_sum(const float* __restrict__ ea,
                                                  float* __restrict__ asum){
    __shared__ float4 sdata[256];
    int tid = threadIdx.x;
    size_t gid = (size_t)blockIdx.x * 256 + tid;
    size_t step = (size_t)gridDim.x * 256;
    const float4* p = reinterpret_cast<const float4*>(ea);
    float4 acc = make_float4(0.f, 0.f, 0.f, 0.f);
    for (size_t j = gid; j < (size_t)E_ * 4; j += step){
        float4 v = p[j];
        acc.x += v.x; acc.y += v.y; acc.z += v.z; acc.w += v.w;
    }
    sdata[tid] = acc;
    __syncthreads();
    #pragma unroll
    for (int s = 128; s >= 4; s >>= 1){
        if (tid < s){
            float4 o = sdata[tid + s];
            float4 m = sdata[tid];
            m.x += o.x; m.y += o.y; m.z += o.z; m.w += o.w;
            sdata[tid] = m;
        }
        __syncthreads();
    }
    if (tid < 4){
        float4 m = sdata[tid];
        atomicAdd(&asum[tid*4+0], m.x);
        atomicAdd(&asum[tid*4+1], m.y);
        atomicAdd(&asum[tid*4+2], m.z);
        atomicAdd(&asum[tid*4+3], m.w);
    }
}

// ---------- V[k][h]; alloop[h] ----------
__global__ void k_prep(const float* __restrict__ We, const float* __restrict__ aedge,
                       const float* __restrict__ asum, float* __restrict__ V,
                       float* __restrict__ alloop){
    __shared__ float Vs[64];
    int t = threadIdx.x;  // 64 threads
    int k = t >> 2, hd = t & 3;
    float s = 0.f;
    for (int c = 0; c < 64; ++c) s += We[k * 256 + hd * 64 + c] * aedge[hd * 64 + c];
    Vs[t] = s;
    V[t] = s;
    __syncthreads();
    if (t < 4){
        float r = 0.f;
        for (int kk = 0; kk < 16; ++kk) r += (asum[kk] / (float)E_) * Vs[kk * 4 + t];
        alloop[t] = r;
    }
}

// ---------- al_edge ----------
__global__ void k_al_edge(const float* __restrict__ ea, const float* __restrict__ V,
                          float* __restrict__ ale){
    int idx = blockIdx.x * blockDim.x + threadIdx.x;   // E*4
    if (idx >= E_ * 4) return;
    int e = idx >> 2, hd = idx & 3;
    const float* ep = ea + (size_t)e * 16;
    float s = 0.f;
    #pragma unroll
    for (int k = 0; k < 16; ++k) s += ep[k] * V[k * 4 + hd];
    ale[idx] = s;
}

// ---------- CSR build ----------
__global__ void k_count(const int* __restrict__ ei, int* __restrict__ counts){
    int e = blockIdx.x * blockDim.x + threadIdx.x;
    if (e >= E2_) return;
    int d = (e < E_) ? ei[E_ + e] : (e - E_);
    atomicAdd(&counts[d], 1);
}

// hierarchical exclusive scan: (1) per-block scan + block sums
__global__ __launch_bounds__(256) void k_scan_local(const int* __restrict__ counts,
                                                    int* __restrict__ rs,
                                                    int* __restrict__ bsum){
    __shared__ int sd[256];
    int t = threadIdx.x;
    int idx = blockIdx.x * 256 + t;
    int c = (idx < N_) ? counts[idx] : 0;
    sd[t] = c;
    __syncthreads();
    #pragma unroll
    for (int off = 1; off < 256; off <<= 1){
        int o = (t >= off) ? sd[t - off] : 0;
        __syncthreads();
        sd[t] += o;
        __syncthreads();
    }
    if (idx < N_) rs[idx] = sd[t] - c;          // exclusive within block
    if (t == 255) bsum[blockIdx.x] = sd[255];   // block total
}

// (2) scan of block sums (SCAN_NBLK <= 256), one block
__global__ __launch_bounds__(256) void k_scan_block(const int* __restrict__ bsum,
                                                    int* __restrict__ boff,
                                                    int* __restrict__ rs){
    __shared__ int sd[256];
    int t = threadIdx.x;
    int v = (t < SCAN_NBLK) ? bsum[t] : 0;
    sd[t] = v;
    __syncthreads();
    #pragma unroll
    for (int off = 1; off < 256; off <<= 1){
        int o = (t >= off) ? sd[t - off] : 0;
        __syncthreads();
        sd[t] += o;
        __syncthreads();
    }
    if (t < SCAN_NBLK) boff[t] = sd[t] - v;     // exclusive block offsets
    if (t == 0) rs[N_] = E2_;
}

// (3) add block offsets
__global__ __launch_bounds__(256) void k_scan_add(int* __restrict__ rs,
                                                  const int* __restrict__ boff){
    int idx = blockIdx.x * 256 + threadIdx.x;
    if (idx < N_) rs[idx] += boff[blockIdx.x];
}

__global__ void k_scatter(const int* __restrict__ ei, const int* __restrict__ rs,
                          int* __restrict__ cursor, int* __restrict__ ssrc, int* __restrict__ seid){
    int e = blockIdx.x * blockDim.x + threadIdx.x;
    if (e >= E2_) return;
    int s, d;
    if (e < E_){ s = ei[e]; d = ei[E_ + e]; }
    else { s = e - E_; d = s; }
    int slot = rs[d] + atomicAdd(&cursor[d], 1);
    ssrc[slot] = s;
    seid[slot] = e;
}

// ---------- one wave per dst node, FOUR independent edge streams (16 lanes each) ----------
#define MERGE4(OFF) { \
    float mo  = __shfl_xor(m,   OFF, 64); \
    float dno = __shfl_xor(den, OFF, 64); \
    float o0=__shfl_xor(a0,OFF,64), o1=__shfl_xor(a1,OFF,64), o2=__shfl_xor(a2,OFF,64), o3=__shfl_xor(a3,OFF,64); \
    float o4=__shfl_xor(a4,OFF,64), o5=__shfl_xor(a5,OFF,64), o6=__shfl_xor(a6,OFF,64), o7=__shfl_xor(a7,OFF,64); \
    float o8=__shfl_xor(a8,OFF,64), o9=__shfl_xor(a9,OFF,64), oA=__shfl_xor(aA,OFF,64), oB=__shfl_xor(aB,OFF,64); \
    float oC=__shfl_xor(aC,OFF,64), oD=__shfl_xor(aD,OFF,64), oE=__shfl_xor(aE,OFF,64), oF=__shfl_xor(aF,OFF,64); \
    float M = fmaxf(m, mo); \
    float sS = __expf(m - M), sO = __expf(mo - M); \
    den = den*sS + dno*sO; \
    a0=a0*sS+o0*sO; a1=a1*sS+o1*sO; a2=a2*sS+o2*sO; a3=a3*sS+o3*sO; \
    a4=a4*sS+o4*sO; a5=a5*sS+o5*sO; a6=a6*sS+o6*sO; a7=a7*sS+o7*sO; \
    a8=a8*sS+o8*sO; a9=a9*sS+o9*sO; aA=aA*sS+oA*sO; aB=aB*sS+oB*sO; \
    aC=aC*sS+oC*sO; aD=aD*sS+oD*sO; aE=aE*sS+oE*sO; aF=aF*sS+oF*sO; \
    m = M; }

template<bool BF16OUT>
__global__ __launch_bounds__(256) void k_aggregate4(const unsigned short* __restrict__ hb,
        const float* __restrict__ als, const float* __restrict__ ald,
        const float* __restrict__ ale, const float* __restrict__ alloop,
        const int* __restrict__ rs, const int* __restrict__ ssrc, const int* __restrict__ seid,
        const float* __restrict__ bias, void* __restrict__ outp){
    int n = blockIdx.x * 4 + (threadIdx.x >> 6);
    if (n >= N_) return;
    int lane = threadIdx.x & 63;
    int q  = lane >> 4;
    int sl = lane & 15;
    int col0 = sl * 16;
    int hd = sl >> 2;
    float aldn = ald[(size_t)n * 4 + hd];
    float alp  = alloop[hd];
    int i0 = rs[n], i1 = rs[n + 1];
    float m = -3.0e38f, den = 0.f;
    float a0=0.f,a1=0.f,a2=0.f,a3=0.f,a4=0.f,a5=0.f,a6=0.f,a7=0.f;
    float a8=0.f,a9=0.f,aA=0.f,aB=0.f,aC=0.f,aD=0.f,aE=0.f,aF=0.f;
    for (int i = i0 + q; i < i1; i += 4){
        int s   = ssrc[i];
        int eid = seid[i];
        float alE = (eid < E_) ? ale[(size_t)eid * 4 + hd] : alp;
        float lg = als[(size_t)s * 4 + hd] + aldn + alE;
        lg = lrelu(lg, NEG_ATT);
        float mn = fmaxf(m, lg);
        float sc = __expf(m - mn);
        float p  = __expf(lg - mn);
        den = den * sc + p;
        const unsigned short* hp = hb + (size_t)s * 256 + col0;
        uint4 g0 = *reinterpret_cast<const uint4*>(hp);
        uint4 g1 = *reinterpret_cast<const uint4*>(hp + 8);
        a0 = a0*sc + p*bf16lo(g0.x);  a1 = a1*sc + p*bf16hi(g0.x);
        a2 = a2*sc + p*bf16lo(g0.y);  a3 = a3*sc + p*bf16hi(g0.y);
        a4 = a4*sc + p*bf16lo(g0.z);  a5 = a5*sc + p*bf16hi(g0.z);
        a6 = a6*sc + p*bf16lo(g0.w);  a7 = a7*sc + p*bf16hi(g0.w);
        a8 = a8*sc + p*bf16lo(g1.x);  a9 = a9*sc + p*bf16hi(g1.x);
        aA = aA*sc + p*bf16lo(g1.y);  aB = aB*sc + p*bf16hi(g1.y);
        aC = aC*sc + p*bf16lo(g1.z);  aD = aD*sc + p*bf16hi(g1.z);
        aE = aE*sc + p*bf16lo(g1.w);  aF = aF*sc + p*bf16hi(g1.w);
        m = mn;
    }
    MERGE4(16)
    MERGE4(32)
    float inv = 1.f / den;
    float v0, v1, v2, v3;
    if      (q == 0){ v0 = a0; v1 = a1; v2 = a2; v3 = a3; }
    else if (q == 1){ v0 = a4; v1 = a5; v2 = a6; v3 = a7; }
    else if (q == 2){ v0 = a8; v1 = a9; v2 = aA; v3 = aB; }
    else            { v0 = aC; v1 = aD; v2 = aE; v3 = aF; }
    int wc = col0 + q * 4;
    float4 b4 = *reinterpret_cast<const float4*>(bias + wc);
    float r0 = lrelu(v0 * inv + b4.x, NEG_OUT);
    float r1 = lrelu(v1 * inv + b4.y, NEG_OUT);
    float r2 = lrelu(v2 * inv + b4.z, NEG_OUT);
    float r3 = lrelu(v3 * inv + b4.w, NEG_OUT);
    if (BF16OUT){
        ushort4 pk;
        pk.x = bf16rne(r0); pk.y = bf16rne(r1); pk.z = bf16rne(r2); pk.w = bf16rne(r3);
        *reinterpret_cast<ushort4*>((unsigned short*)outp + (size_t)n * 256 + wc) = pk;
    } else {
        *reinterpret_cast<float4*>((float*)outp + (size_t)n * 256 + wc) =
            make_float4(r0, r1, r2, r3);
    }
}

// ---------- edge_index passthrough (fp32, bit-exact) ----------
__global__ void k_edge_store(const int* __restrict__ ei, float* __restrict__ out){
    int j = blockIdx.x * blockDim.x + threadIdx.x;     // 2E
    if (j >= (int)OUT1) return;
    out[j] = (float)ei[j];
}

extern "C" void kernel_launch(void* const* d_in, const int* in_sizes, int n_in,
                              void* d_out, int out_size, void* d_ws, size_t ws_size,
                              hipStream_t stream){
    const float* x    = (const float*)d_in[0];
    const int*   ei   = (const int*)d_in[1];
    const float* ea   = (const float*)d_in[2];
    const float* bn1g = (const float*)d_in[3];
    const float* bn1b = (const float*)d_in[4];
    const float* W1   = (const float*)d_in[5];
    const float* We1  = (const float*)d_in[6];
    const float* as1  = (const float*)d_in[7];
    const float* ad1  = (const float*)d_in[8];
    const float* ae1  = (const float*)d_in[9];
    const float* b1   = (const float*)d_in[10];
    const float* bn2g = (const float*)d_in[11];
    const float* bn2b = (const float*)d_in[12];
    const float* W2   = (const float*)d_in[13];
    const float* We2  = (const float*)d_in[14];
    const float* as2  = (const float*)d_in[15];
    const float* ad2  = (const float*)d_in[16];
    const float* ae2  = (const float*)d_in[17];
    const float* b2   = (const float*)d_in[18];
    float* out = (float*)d_out;

    bool ok = (n_in >= 19)
           && (in_sizes[0] == N_ * FIN)
           && (in_sizes[1] == 2 * E_)
           && (in_sizes[2] == E_ * 16)
           && (out_size == (int)(OUT0 + OUT1));
    if (!ok){ k_sentinel<<<1,1,0,stream>>>(out, 7777.f); return; }

    char* w = (char*)d_ws;
    size_t off = 0;
    auto alloc = [&](size_t bytes) -> void* {
        off = (off + 255) & ~(size_t)255;
        void* p = w + off;
        off += bytes;
        return p;
    };
    float* stats  = (float*)alloc(512 * 4);
    float* asum   = (float*)alloc(16 * 4);
    float* Vbuf   = (float*)alloc(64 * 4);
    float* alloop = (float*)alloc(4 * 4);
    float* als    = (float*)alloc((size_t)N_ * 4 * 4);
    float* ald    = (float*)alloc((size_t)N_ * 4 * 4);
    float* ale    = (float*)alloc((size_t)E_ * 4 * 4);          // 12.8MB
    int*   rs     = (int*)alloc((size_t)(N_ + 1) * 4);
    int*   counts = (int*)alloc((size_t)N_ * 4);
    int*   cursor = (int*)alloc((size_t)N_ * 4);
    int*   bsum   = (int*)alloc((size_t)SCAN_NBLK * 4);
    int*   boff   = (int*)alloc((size_t)SCAN_NBLK * 4);
    int*   ssrc   = (int*)alloc((size_t)E2_ * 4);
    int*   seid   = (int*)alloc((size_t)E2_ * 4);
    unsigned short* WT1 = (unsigned short*)alloc((size_t)256 * FIN * 2);  // 64KB
    unsigned short* WT2 = (unsigned short*)alloc((size_t)256 * FH * 2);   // 128KB
    unsigned short* bufC = (unsigned short*)alloc((size_t)N_ * 256 * 2);  // 25.6MB bf16
    unsigned short* hbuf = (unsigned short*)alloc((size_t)N_ * 256 * 2);  // 25.6MB bf16
    unsigned short* bufB = (unsigned short*)alloc((size_t)N_ * 256 * 2);  // 25.6MB bf16
    if (off > ws_size){ k_sentinel<<<1,1,0,stream>>>(out, 5555.f); return; }

    float* ssum = stats;
    float* ssq  = stats + 256;
    const int GX = cdiv(N_, 64);    // 782

    // ---- CSR build (shared by both layers) ----
    k_zero32<<<cdiv(N_,256),256,0,stream>>>((unsigned*)counts, N_);
    k_zero32<<<cdiv(N_,256),256,0,stream>>>((unsigned*)cursor, N_);
    k_count<<<cdiv(E2_,256),256,0,stream>>>(ei, counts);
    k_scan_local<<<SCAN_NBLK,256,0,stream>>>(counts, rs, bsum);
    k_scan_block<<<1,256,0,stream>>>(bsum, boff, rs);
    k_scan_add<<<SCAN_NBLK,256,0,stream>>>(rs, boff);
    k_scatter<<<cdiv(E2_,256),256,0,stream>>>(ei, rs, cursor, ssrc, seid);

    // ---- shared precompute ----
    k_zero32<<<2,256,0,stream>>>((unsigned*)stats, 512);
    k_zero32<<<1,64,0,stream>>>((unsigned*)asum, 16);
    k_attr_sum<<<1024,256,0,stream>>>(ea, asum);
    k_w2t<<<FIN,256,0,stream>>>(W1, WT1, FIN);
    k_w2t<<<FH,256,0,stream>>>(W2, WT2, FH);

    // ---- BN1 + lrelu (fp32 -> bf16) ----
    k_bn_stats<<<256,256,0,stream>>>(x, FIN, ssum, ssq);
    k_bn_apply_bf<<<2048,256,0,stream>>>(x, ssum, ssq, bn1g, bn1b, bufC, FIN);

    // ---- GAT layer 1 ----
    k_gemm_mfma<<<dim3(GX,4),256,0,stream>>>(bufC, WT1, hbuf, N_, FIN);
    k_al<<<cdiv(N_,4),256,0,stream>>>(hbuf, as1, ad1, als, ald);
    k_prep<<<1,64,0,stream>>>(We1, ae1, asum, Vbuf, alloop);
    k_al_edge<<<cdiv(E_*4,256),256,0,stream>>>(ea, Vbuf, ale);
    k_aggregate4<true><<<cdiv(N_,4),256,0,stream>>>(hbuf, als, ald, ale, alloop,
                                                    rs, ssrc, seid, b1, bufB);

    // ---- BN2 + lrelu (bf16 -> bf16) ----
    k_zero32<<<2,256,0,stream>>>((unsigned*)stats, 512);
    k_bn_stats_b16<<<256,256,0,stream>>>(bufB, FH, ssum, ssq);
    k_bn_apply_b16<<<2048,256,0,stream>>>(bufB, ssum, ssq, bn2g, bn2b, bufC, FH);

    // ---- GAT layer 2 ----
    k_gemm_mfma<<<dim3(GX,4),256,0,stream>>>(bufC, WT2, hbuf, N_, FH);
    k_al<<<cdiv(N_,4),256,0,stream>>>(hbuf, as2, ad2, als, ald);
    k_prep<<<1,64,0,stream>>>(We2, ae2, asum, Vbuf, alloop);
    k_al_edge<<<cdiv(E_*4,256),256,0,stream>>>(ea, Vbuf, ale);
    k_aggregate4<false><<<cdiv(N_,4),256,0,stream>>>(hbuf, als, ald, ale, alloop,
                                                     rs, ssrc, seid, b2, out);

    // ---- edge_index passthrough ----
    k_edge_store<<<cdiv((int)OUT1,256),256,0,stream>>>(ei, out + OUT0);
}

// Round 12
// 532.781 us; speedup vs baseline: 13.1266x; 1.0773x over previous
//
#include <hip/hip_runtime.h>
#include <hip/hip_bf16.h>

// Problem constants
constexpr int N_  = 50000;
constexpr int E_  = 800000;
constexpr int E2_ = 850000;   // E + N self loops
constexpr int FIN = 128;
constexpr int FH  = 256;      // H * C = 4 * 64
constexpr float BN_EPS = 1e-5f;
constexpr float NEG_ATT = 0.2f;
constexpr float NEG_OUT = 0.1f;
constexpr size_t OUT0 = (size_t)N_ * FH;   // 12.8M feature elems (fp32)
constexpr size_t OUT1 = (size_t)2 * E_;    // 1.6M edge elems (fp32)
constexpr int SCAN_NBLK = (N_ + 255) / 256;   // 196

static inline int cdiv(int a, int b){ return (a + b - 1) / b; }

using short8 = __attribute__((ext_vector_type(8))) short;
using f32x4  = __attribute__((ext_vector_type(4))) float;
using f32x2  = __attribute__((ext_vector_type(2))) float;

#if __has_builtin(__builtin_amdgcn_cvt_pk_f32_fp8) && __has_builtin(__builtin_amdgcn_cvt_pk_fp8_f32)
#define FP8_HW 1
#else
#define FP8_HW 0
#endif

__device__ inline float lrelu(float v, float ns){ return v > 0.f ? v : ns * v; }

__device__ inline unsigned short bf16rne(float f){
    unsigned u = __float_as_uint(f);
    u += 0x7fffu + ((u >> 16) & 1u);
    return (unsigned short)(u >> 16);
}
__device__ inline float bf16lo(unsigned u){ return __uint_as_float(u << 16); }
__device__ inline float bf16hi(unsigned u){ return __uint_as_float(u & 0xffff0000u); }
__device__ inline float bf16f(unsigned short v){ return __uint_as_float((unsigned)v << 16); }

// ---- software e4m3fn codec (fallback only; HW cvt used when available) ----
__device__ inline float fp8dec1(unsigned b){
    unsigned s = b >> 7;
    unsigned e = (b >> 3) & 15;
    unsigned m = b & 7;
    float v;
    if (e == 0) v = (float)m * 0.001953125f;           // m * 2^-9
    else        v = __uint_as_float(((e + 120u) << 23) | (m << 20));
    return s ? -v : v;
}
__device__ inline unsigned fp8enc1(float f){
    unsigned u = __float_as_uint(f);
    unsigned s = (u >> 31) << 7;
    float af = fabsf(f);
    if (af >= 448.f) return s | 0x7Eu;
    if (af < 0.0009765625f) return s;                   // < 2^-10 -> 0
    if (af < 0.015625f){                                // subnormal range
        int q = (int)(af * 512.f + 0.5f);               // round to m*2^-9 (q<=8 ok)
        return s | (unsigned)q;
    }
    unsigned a = u & 0x7fffffffu;
    a += 0x7FFFFu + ((a >> 20) & 1u);                   // RNE at mantissa bit 20
    int e8 = (int)(a >> 23) - 120;
    unsigned m8 = (a >> 20) & 7u;
    if (e8 > 15 || (e8 == 15 && m8 == 7u)) return s | 0x7Eu;
    return s | ((unsigned)e8 << 3) | m8;
}
__device__ inline void dec4(unsigned g, float& f0, float& f1, float& f2, float& f3){
#if FP8_HW
    f32x2 lo = __builtin_amdgcn_cvt_pk_f32_fp8((int)g, false);
    f32x2 hi = __builtin_amdgcn_cvt_pk_f32_fp8((int)g, true);
    f0 = lo[0]; f1 = lo[1]; f2 = hi[0]; f3 = hi[1];
#else
    f0 = fp8dec1(g & 255u); f1 = fp8dec1((g >> 8) & 255u);
    f2 = fp8dec1((g >> 16) & 255u); f3 = fp8dec1(g >> 24);
#endif
}

__global__ void k_sentinel(float* out, float v){ out[0] = v; }

__global__ void k_zero32(unsigned* p, int n){
    int i = blockIdx.x * blockDim.x + threadIdx.x;
    if (i < n) p[i] = 0u;
}

// ---------- W [K][256] fp32 -> WT [256][K] bf16 ----------
__global__ void k_w2t(const float* __restrict__ W, unsigned short* __restrict__ WT, int K){
    int i = blockIdx.x * blockDim.x + threadIdx.x;
    if (i >= K * 256) return;
    int k = i >> 8, c = i & 255;
    WT[(size_t)c * K + k] = bf16rne(W[i]);
}

// ---------- hbuf bf16 -> hbuf8 fp8 (streaming) ----------
__global__ void k_h2fp8(const unsigned short* __restrict__ hb, unsigned* __restrict__ h8){
    size_t tot = (size_t)N_ * 256 / 4;   // 3.2M uints
    size_t step = (size_t)gridDim.x * blockDim.x;
    for (size_t i = blockIdx.x * (size_t)blockDim.x + threadIdx.x; i < tot; i += step){
        uint2 g = *reinterpret_cast<const uint2*>(hb + i * 4);
        float f0 = bf16lo(g.x), f1 = bf16hi(g.x), f2 = bf16lo(g.y), f3 = bf16hi(g.y);
#if FP8_HW
        int lo = __builtin_amdgcn_cvt_pk_fp8_f32(f0, f1, 0, false);
        int pk = __builtin_amdgcn_cvt_pk_fp8_f32(f2, f3, lo, true);
        h8[i] = (unsigned)pk;
#else
        h8[i] = fp8enc1(f0) | (fp8enc1(f1) << 8) | (fp8enc1(f2) << 16) | (fp8enc1(f3) << 24);
#endif
    }
}

// ---------- BatchNorm stats (fp32 input) ----------
__global__ void k_bn_stats(const float* __restrict__ x, int F,
                           float* __restrict__ sum, float* __restrict__ sumsq){
    int gid = blockIdx.x * blockDim.x + threadIdx.x;
    int T = gridDim.x * blockDim.x;      // 65536
    int c = gid % F;
    int r0 = gid / F;
    int rstep = T / F;
    float s = 0.f, s2 = 0.f;
    for (int r = r0; r < N_; r += rstep){
        float v = x[(size_t)r * F + c];
        s += v; s2 += v * v;
    }
    atomicAdd(&sum[c], s);
    atomicAdd(&sumsq[c], s2);
}

// ---------- BatchNorm stats (bf16 input) ----------
__global__ void k_bn_stats_b16(const unsigned short* __restrict__ x, int F,
                               float* __restrict__ sum, float* __restrict__ sumsq){
    int gid = blockIdx.x * blockDim.x + threadIdx.x;
    int T = gridDim.x * blockDim.x;
    int c = gid % F;
    int r0 = gid / F;
    int rstep = T / F;
    float s = 0.f, s2 = 0.f;
    for (int r = r0; r < N_; r += rstep){
        float v = bf16f(x[(size_t)r * F + c]);
        s += v; s2 += v * v;
    }
    atomicAdd(&sum[c], s);
    atomicAdd(&sumsq[c], s2);
}

// BN + lrelu, fp32 in -> bf16 out
__global__ void k_bn_apply_bf(const float* __restrict__ x, const float* __restrict__ sum,
                              const float* __restrict__ sumsq, const float* __restrict__ gamma,
                              const float* __restrict__ beta, unsigned short* __restrict__ out, int F){
    size_t tot = (size_t)N_ * F;
    size_t step = (size_t)gridDim.x * blockDim.x;
    for (size_t i = blockIdx.x * (size_t)blockDim.x + threadIdx.x; i < tot; i += step){
        int c = (int)(i % F);
        float mean = sum[c] / (float)N_;
        float var = sumsq[c] / (float)N_ - mean * mean;
        float v = (x[i] - mean) * rsqrtf(var + BN_EPS) * gamma[c] + beta[c];
        out[i] = bf16rne(lrelu(v, NEG_OUT));
    }
}

// BN + lrelu, bf16 in -> bf16 out
__global__ void k_bn_apply_b16(const unsigned short* __restrict__ x, const float* __restrict__ sum,
                               const float* __restrict__ sumsq, const float* __restrict__ gamma,
                               const float* __restrict__ beta, unsigned short* __restrict__ out, int F){
    size_t tot = (size_t)N_ * F;
    size_t step = (size_t)gridDim.x * blockDim.x;
    for (size_t i = blockIdx.x * (size_t)blockDim.x + threadIdx.x; i < tot; i += step){
        int c = (int)(i % F);
        float mean = sum[c] / (float)N_;
        float var = sumsq[c] / (float)N_ - mean * mean;
        float v = (bf16f(x[i]) - mean) * rsqrtf(var + BN_EPS) * gamma[c] + beta[c];
        out[i] = bf16rne(lrelu(v, NEG_OUT));
    }
}

// ---------- MFMA GEMM: C[M x 256] = A[M x K] @ B[K x 256] (A,WT,C all bf16) ----------
__global__ __launch_bounds__(256) void k_gemm_mfma(const unsigned short* __restrict__ A,
                                                   const unsigned short* __restrict__ WT,
                                                   unsigned short* __restrict__ C, int M, int K){
    __shared__ unsigned short Al[64][32];   // 4KB
    __shared__ unsigned short Bl[64][32];   // 4KB  (Bl[col][k])
    int tid = threadIdx.x;
    int w = tid >> 6;
    int l = tid & 63;
    int row0 = blockIdx.x * 64;
    int col0 = blockIdx.y * 64;
    f32x4 acc[4];
    #pragma unroll
    for (int m = 0; m < 4; ++m) acc[m] = (f32x4){0.f, 0.f, 0.f, 0.f};

    int srow = tid >> 2;
    int skq  = (tid & 3) * 8;

    for (int k0 = 0; k0 < K; k0 += 32){
        {
            short8 v = {0,0,0,0,0,0,0,0};
            if (row0 + srow < M)
                v = *reinterpret_cast<const short8*>(A + (size_t)(row0 + srow) * K + k0 + skq);
            *reinterpret_cast<short8*>(&Al[srow][skq]) = v;
        }
        {
            short8 v = *reinterpret_cast<const short8*>(WT + (size_t)(col0 + srow) * K + k0 + skq);
            *reinterpret_cast<short8*>(&Bl[srow][skq]) = v;
        }
        __syncthreads();
        short8 b = *reinterpret_cast<const short8*>(&Bl[w * 16 + (l & 15)][8 * (l >> 4)]);
        #pragma unroll
        for (int m = 0; m < 4; ++m){
            short8 a = *reinterpret_cast<const short8*>(&Al[m * 16 + (l & 15)][8 * (l >> 4)]);
            acc[m] = __builtin_amdgcn_mfma_f32_16x16x32_bf16(a, b, acc[m], 0, 0, 0);
        }
        __syncthreads();
    }
    int ccol = col0 + w * 16 + (l & 15);
    #pragma unroll
    for (int m = 0; m < 4; ++m){
        #pragma unroll
        for (int r = 0; r < 4; ++r){
            int row = row0 + m * 16 + (l >> 4) * 4 + r;
            if (row < M) C[(size_t)row * 256 + ccol] = bf16rne(acc[m][r]);
        }
    }
}

// ---------- per-node attention terms: one wave per node, bf16 h ----------
__global__ __launch_bounds__(256) void k_al(const unsigned short* __restrict__ hb,
                                            const float* __restrict__ asrc,
                                            const float* __restrict__ adst,
                                            float* __restrict__ als, float* __restrict__ ald){
    int n = blockIdx.x * 4 + (threadIdx.x >> 6);
    if (n >= N_) return;
    int lane = threadIdx.x & 63;
    uint2 g = *reinterpret_cast<const uint2*>(hb + (size_t)n * 256 + lane * 4);
    float h0 = bf16lo(g.x), h1 = bf16hi(g.x), h2 = bf16lo(g.y), h3 = bf16hi(g.y);
    float4 as = *reinterpret_cast<const float4*>(asrc + lane * 4);
    float4 ad = *reinterpret_cast<const float4*>(adst + lane * 4);
    float ps = h0*as.x + h1*as.y + h2*as.z + h3*as.w;
    float pd = h0*ad.x + h1*ad.y + h2*ad.z + h3*ad.w;
    #pragma unroll
    for (int m = 1; m < 16; m <<= 1){
        ps += __shfl_xor(ps, m, 64);
        pd += __shfl_xor(pd, m, 64);
    }
    if ((lane & 15) == 0){
        int hd = lane >> 4;
        als[(size_t)n*4 + hd] = ps;
        ald[(size_t)n*4 + hd] = pd;
    }
}

// ---------- edge_attr column sums ----------
__global__ __launch_bounds__(256) void k_attr_sum(const float* __restrict__ ea,
                                                  float* __restrict__ asum){
    __shared__ float4 sdata[256];
    int tid = threadIdx.x;
    size_t gid = (size_t)blockIdx.x * 256 + tid;
    size_t step = (size_t)gridDim.x * 256;
    const float4* p = reinterpret_cast<const float4*>(ea);
    float4 acc = make_float4(0.f, 0.f, 0.f, 0.f);
    for (size_t j = gid; j < (size_t)E_ * 4; j += step){
        float4 v = p[j];
        acc.x += v.x; acc.y += v.y; acc.z += v.z; acc.w += v.w;
    }
    sdata[tid] = acc;
    __syncthreads();
    #pragma unroll
    for (int s = 128; s >= 4; s >>= 1){
        if (tid < s){
            float4 o = sdata[tid + s];
            float4 m = sdata[tid];
            m.x += o.x; m.y += o.y; m.z += o.z; m.w += o.w;
            sdata[tid] = m;
        }
        __syncthreads();
    }
    if (tid < 4){
        float4 m = sdata[tid];
        atomicAdd(&asum[tid*4+0], m.x);
        atomicAdd(&asum[tid*4+1], m.y);
        atomicAdd(&asum[tid*4+2], m.z);
        atomicAdd(&asum[tid*4+3], m.w);
    }
}

// ---------- V[k][h]; alloop[h] ----------
__global__ void k_prep(const float* __restrict__ We, const float* __restrict__ aedge,
                       const float* __restrict__ asum, float* __restrict__ V,
                       float* __restrict__ alloop){
    __shared__ float Vs[64];
    int t = threadIdx.x;  // 64 threads
    int k = t >> 2, hd = t & 3;
    float s = 0.f;
    for (int c = 0; c < 64; ++c) s += We[k * 256 + hd * 64 + c] * aedge[hd * 64 + c];
    Vs[t] = s;
    V[t] = s;
    __syncthreads();
    if (t < 4){
        float r = 0.f;
        for (int kk = 0; kk < 16; ++kk) r += (asum[kk] / (float)E_) * Vs[kk * 4 + t];
        alloop[t] = r;
    }
}

// ---------- al_edge ----------
__global__ void k_al_edge(const float* __restrict__ ea, const float* __restrict__ V,
                          float* __restrict__ ale){
    int idx = blockIdx.x * blockDim.x + threadIdx.x;   // E*4
    if (idx >= E_ * 4) return;
    int e = idx >> 2, hd = idx & 3;
    const float* ep = ea + (size_t)e * 16;
    float s = 0.f;
    #pragma unroll
    for (int k = 0; k < 16; ++k) s += ep[k] * V[k * 4 + hd];
    ale[idx] = s;
}

// ---------- CSR build ----------
__global__ void k_count(const int* __restrict__ ei, int* __restrict__ counts){
    int e = blockIdx.x * blockDim.x + threadIdx.x;
    if (e >= E2_) return;
    int d = (e < E_) ? ei[E_ + e] : (e - E_);
    atomicAdd(&counts[d], 1);
}

__global__ __launch_bounds__(256) void k_scan_local(const int* __restrict__ counts,
                                                    int* __restrict__ rs,
                                                    int* __restrict__ bsum){
    __shared__ int sd[256];
    int t = threadIdx.x;
    int idx = blockIdx.x * 256 + t;
    int c = (idx < N_) ? counts[idx] : 0;
    sd[t] = c;
    __syncthreads();
    #pragma unroll
    for (int off = 1; off < 256; off <<= 1){
        int o = (t >= off) ? sd[t - off] : 0;
        __syncthreads();
        sd[t] += o;
        __syncthreads();
    }
    if (idx < N_) rs[idx] = sd[t] - c;
    if (t == 255) bsum[blockIdx.x] = sd[255];
}

__global__ __launch_bounds__(256) void k_scan_block(const int* __restrict__ bsum,
                                                    int* __restrict__ boff,
                                                    int* __restrict__ rs){
    __shared__ int sd[256];
    int t = threadIdx.x;
    int v = (t < SCAN_NBLK) ? bsum[t] : 0;
    sd[t] = v;
    __syncthreads();
    #pragma unroll
    for (int off = 1; off < 256; off <<= 1){
        int o = (t >= off) ? sd[t - off] : 0;
        __syncthreads();
        sd[t] += o;
        __syncthreads();
    }
    if (t < SCAN_NBLK) boff[t] = sd[t] - v;
    if (t == 0) rs[N_] = E2_;
}

__global__ __launch_bounds__(256) void k_scan_add(int* __restrict__ rs,
                                                  const int* __restrict__ boff){
    int idx = blockIdx.x * 256 + threadIdx.x;
    if (idx < N_) rs[idx] += boff[blockIdx.x];
}

__global__ void k_scatter(const int* __restrict__ ei, const int* __restrict__ rs,
                          int* __restrict__ cursor, int* __restrict__ ssrc, int* __restrict__ seid){
    int e = blockIdx.x * blockDim.x + threadIdx.x;
    if (e >= E2_) return;
    int s, d;
    if (e < E_){ s = ei[e]; d = ei[E_ + e]; }
    else { s = e - E_; d = s; }
    int slot = rs[d] + atomicAdd(&cursor[d], 1);
    ssrc[slot] = s;
    seid[slot] = e;
}

// ---------- one wave per dst node, FOUR independent edge streams, fp8 gather ----------
#define MERGE4(OFF) { \
    float mo  = __shfl_xor(m,   OFF, 64); \
    float dno = __shfl_xor(den, OFF, 64); \
    float o0=__shfl_xor(a0,OFF,64), o1=__shfl_xor(a1,OFF,64), o2=__shfl_xor(a2,OFF,64), o3=__shfl_xor(a3,OFF,64); \
    float o4=__shfl_xor(a4,OFF,64), o5=__shfl_xor(a5,OFF,64), o6=__shfl_xor(a6,OFF,64), o7=__shfl_xor(a7,OFF,64); \
    float o8=__shfl_xor(a8,OFF,64), o9=__shfl_xor(a9,OFF,64), oA=__shfl_xor(aA,OFF,64), oB=__shfl_xor(aB,OFF,64); \
    float oC=__shfl_xor(aC,OFF,64), oD=__shfl_xor(aD,OFF,64), oE=__shfl_xor(aE,OFF,64), oF=__shfl_xor(aF,OFF,64); \
    float M = fmaxf(m, mo); \
    float sS = __expf(m - M), sO = __expf(mo - M); \
    den = den*sS + dno*sO; \
    a0=a0*sS+o0*sO; a1=a1*sS+o1*sO; a2=a2*sS+o2*sO; a3=a3*sS+o3*sO; \
    a4=a4*sS+o4*sO; a5=a5*sS+o5*sO; a6=a6*sS+o6*sO; a7=a7*sS+o7*sO; \
    a8=a8*sS+o8*sO; a9=a9*sS+o9*sO; aA=aA*sS+oA*sO; aB=aB*sS+oB*sO; \
    aC=aC*sS+oC*sO; aD=aD*sS+oD*sO; aE=aE*sS+oE*sO; aF=aF*sS+oF*sO; \
    m = M; }

template<bool BF16OUT>
__global__ __launch_bounds__(256) void k_aggregate4(const unsigned char* __restrict__ hb8,
        const float* __restrict__ als, const float* __restrict__ ald,
        const float* __restrict__ ale, const float* __restrict__ alloop,
        const int* __restrict__ rs, const int* __restrict__ ssrc, const int* __restrict__ seid,
        const float* __restrict__ bias, void* __restrict__ outp){
    int n = blockIdx.x * 4 + (threadIdx.x >> 6);
    if (n >= N_) return;
    int lane = threadIdx.x & 63;
    int q  = lane >> 4;
    int sl = lane & 15;
    int col0 = sl * 16;
    int hd = sl >> 2;
    float aldn = ald[(size_t)n * 4 + hd];
    float alp  = alloop[hd];
    int i0 = rs[n], i1 = rs[n + 1];
    float m = -3.0e38f, den = 0.f;
    float a0=0.f,a1=0.f,a2=0.f,a3=0.f,a4=0.f,a5=0.f,a6=0.f,a7=0.f;
    float a8=0.f,a9=0.f,aA=0.f,aB=0.f,aC=0.f,aD=0.f,aE=0.f,aF=0.f;
    for (int i = i0 + q; i < i1; i += 4){
        int s   = ssrc[i];
        int eid = seid[i];
        float alE = (eid < E_) ? ale[(size_t)eid * 4 + hd] : alp;
        float lg = als[(size_t)s * 4 + hd] + aldn + alE;
        lg = lrelu(lg, NEG_ATT);
        float mn = fmaxf(m, lg);
        float sc = __expf(m - mn);
        float p  = __expf(lg - mn);
        den = den * sc + p;
        uint4 g = *reinterpret_cast<const uint4*>(hb8 + (size_t)s * 256 + col0);
        float t0, t1, t2, t3;
        dec4(g.x, t0, t1, t2, t3);
        a0 = a0*sc + p*t0;  a1 = a1*sc + p*t1;  a2 = a2*sc + p*t2;  a3 = a3*sc + p*t3;
        dec4(g.y, t0, t1, t2, t3);
        a4 = a4*sc + p*t0;  a5 = a5*sc + p*t1;  a6 = a6*sc + p*t2;  a7 = a7*sc + p*t3;
        dec4(g.z, t0, t1, t2, t3);
        a8 = a8*sc + p*t0;  a9 = a9*sc + p*t1;  aA = aA*sc + p*t2;  aB = aB*sc + p*t3;
        dec4(g.w, t0, t1, t2, t3);
        aC = aC*sc + p*t0;  aD = aD*sc + p*t1;  aE = aE*sc + p*t2;  aF = aF*sc + p*t3;
        m = mn;
    }
    MERGE4(16)
    MERGE4(32)
    float inv = 1.f / den;
    float v0, v1, v2, v3;
    if      (q == 0){ v0 = a0; v1 = a1; v2 = a2; v3 = a3; }
    else if (q == 1){ v0 = a4; v1 = a5; v2 = a6; v3 = a7; }
    else if (q == 2){ v0 = a8; v1 = a9; v2 = aA; v3 = aB; }
    else            { v0 = aC; v1 = aD; v2 = aE; v3 = aF; }
    int wc = col0 + q * 4;
    float4 b4 = *reinterpret_cast<const float4*>(bias + wc);
    float r0 = lrelu(v0 * inv + b4.x, NEG_OUT);
    float r1 = lrelu(v1 * inv + b4.y, NEG_OUT);
    float r2 = lrelu(v2 * inv + b4.z, NEG_OUT);
    float r3 = lrelu(v3 * inv + b4.w, NEG_OUT);
    if (BF16OUT){
        ushort4 pk;
        pk.x = bf16rne(r0); pk.y = bf16rne(r1); pk.z = bf16rne(r2); pk.w = bf16rne(r3);
        *reinterpret_cast<ushort4*>((unsigned short*)outp + (size_t)n * 256 + wc) = pk;
    } else {
        *reinterpret_cast<float4*>((float*)outp + (size_t)n * 256 + wc) =
            make_float4(r0, r1, r2, r3);
    }
}

// ---------- edge_index passthrough (fp32, bit-exact) ----------
__global__ void k_edge_store(const int* __restrict__ ei, float* __restrict__ out){
    int j = blockIdx.x * blockDim.x + threadIdx.x;     // 2E
    if (j >= (int)OUT1) return;
    out[j] = (float)ei[j];
}

extern "C" void kernel_launch(void* const* d_in, const int* in_sizes, int n_in,
                              void* d_out, int out_size, void* d_ws, size_t ws_size,
                              hipStream_t stream){
    const float* x    = (const float*)d_in[0];
    const int*   ei   = (const int*)d_in[1];
    const float* ea   = (const float*)d_in[2];
    const float* bn1g = (const float*)d_in[3];
    const float* bn1b = (const float*)d_in[4];
    const float* W1   = (const float*)d_in[5];
    const float* We1  = (const float*)d_in[6];
    const float* as1  = (const float*)d_in[7];
    const float* ad1  = (const float*)d_in[8];
    const float* ae1  = (const float*)d_in[9];
    const float* b1   = (const float*)d_in[10];
    const float* bn2g = (const float*)d_in[11];
    const float* bn2b = (const float*)d_in[12];
    const float* W2   = (const float*)d_in[13];
    const float* We2  = (const float*)d_in[14];
    const float* as2  = (const float*)d_in[15];
    const float* ad2  = (const float*)d_in[16];
    const float* ae2  = (const float*)d_in[17];
    const float* b2   = (const float*)d_in[18];
    float* out = (float*)d_out;

    bool ok = (n_in >= 19)
           && (in_sizes[0] == N_ * FIN)
           && (in_sizes[1] == 2 * E_)
           && (in_sizes[2] == E_ * 16)
           && (out_size == (int)(OUT0 + OUT1));
    if (!ok){ k_sentinel<<<1,1,0,stream>>>(out, 7777.f); return; }

    char* w = (char*)d_ws;
    size_t off = 0;
    auto alloc = [&](size_t bytes) -> void* {
        off = (off + 255) & ~(size_t)255;
        void* p = w + off;
        off += bytes;
        return p;
    };
    float* stats  = (float*)alloc(512 * 4);
    float* asum   = (float*)alloc(16 * 4);
    float* Vbuf   = (float*)alloc(64 * 4);
    float* alloop = (float*)alloc(4 * 4);
    float* als    = (float*)alloc((size_t)N_ * 4 * 4);
    float* ald    = (float*)alloc((size_t)N_ * 4 * 4);
    float* ale    = (float*)alloc((size_t)E_ * 4 * 4);          // 12.8MB
    int*   rs     = (int*)alloc((size_t)(N_ + 1) * 4);
    int*   counts = (int*)alloc((size_t)N_ * 4);
    int*   cursor = (int*)alloc((size_t)N_ * 4);
    int*   bsum   = (int*)alloc((size_t)SCAN_NBLK * 4);
    int*   boff   = (int*)alloc((size_t)SCAN_NBLK * 4);
    int*   ssrc   = (int*)alloc((size_t)E2_ * 4);
    int*   seid   = (int*)alloc((size_t)E2_ * 4);
    unsigned short* WT1 = (unsigned short*)alloc((size_t)256 * FIN * 2);  // 64KB
    unsigned short* WT2 = (unsigned short*)alloc((size_t)256 * FH * 2);   // 128KB
    unsigned short* bufC = (unsigned short*)alloc((size_t)N_ * 256 * 2);  // 25.6MB bf16
    unsigned short* hbuf = (unsigned short*)alloc((size_t)N_ * 256 * 2);  // 25.6MB bf16
    unsigned char*  hbuf8 = (unsigned char*)alloc((size_t)N_ * 256);      // 12.8MB fp8
    unsigned short* bufB = (unsigned short*)alloc((size_t)N_ * 256 * 2);  // 25.6MB bf16
    if (off > ws_size){ k_sentinel<<<1,1,0,stream>>>(out, 5555.f); return; }

    float* ssum = stats;
    float* ssq  = stats + 256;
    const int GX = cdiv(N_, 64);    // 782

    // ---- CSR build (shared by both layers) ----
    k_zero32<<<cdiv(N_,256),256,0,stream>>>((unsigned*)counts, N_);
    k_zero32<<<cdiv(N_,256),256,0,stream>>>((unsigned*)cursor, N_);
    k_count<<<cdiv(E2_,256),256,0,stream>>>(ei, counts);
    k_scan_local<<<SCAN_NBLK,256,0,stream>>>(counts, rs, bsum);
    k_scan_block<<<1,256,0,stream>>>(bsum, boff, rs);
    k_scan_add<<<SCAN_NBLK,256,0,stream>>>(rs, boff);
    k_scatter<<<cdiv(E2_,256),256,0,stream>>>(ei, rs, cursor, ssrc, seid);

    // ---- shared precompute ----
    k_zero32<<<2,256,0,stream>>>((unsigned*)stats, 512);
    k_zero32<<<1,64,0,stream>>>((unsigned*)asum, 16);
    k_attr_sum<<<1024,256,0,stream>>>(ea, asum);
    k_w2t<<<FIN,256,0,stream>>>(W1, WT1, FIN);
    k_w2t<<<FH,256,0,stream>>>(W2, WT2, FH);

    // ---- BN1 + lrelu (fp32 -> bf16) ----
    k_bn_stats<<<256,256,0,stream>>>(x, FIN, ssum, ssq);
    k_bn_apply_bf<<<2048,256,0,stream>>>(x, ssum, ssq, bn1g, bn1b, bufC, FIN);

    // ---- GAT layer 1 ----
    k_gemm_mfma<<<dim3(GX,4),256,0,stream>>>(bufC, WT1, hbuf, N_, FIN);
    k_h2fp8<<<2048,256,0,stream>>>(hbuf, (unsigned*)hbuf8);
    k_al<<<cdiv(N_,4),256,0,stream>>>(hbuf, as1, ad1, als, ald);
    k_prep<<<1,64,0,stream>>>(We1, ae1, asum, Vbuf, alloop);
    k_al_edge<<<cdiv(E_*4,256),256,0,stream>>>(ea, Vbuf, ale);
    k_aggregate4<true><<<cdiv(N_,4),256,0,stream>>>(hbuf8, als, ald, ale, alloop,
                                                    rs, ssrc, seid, b1, bufB);

    // ---- BN2 + lrelu (bf16 -> bf16) ----
    k_zero32<<<2,256,0,stream>>>((unsigned*)stats, 512);
    k_bn_stats_b16<<<256,256,0,stream>>>(bufB, FH, ssum, ssq);
    k_bn_apply_b16<<<2048,256,0,stream>>>(bufB, ssum, ssq, bn2g, bn2b, bufC, FH);

    // ---- GAT layer 2 ----
    k_gemm_mfma<<<dim3(GX,4),256,0,stream>>>(bufC, WT2, hbuf, N_, FH);
    k_h2fp8<<<2048,256,0,stream>>>(hbuf, (unsigned*)hbuf8);
    k_al<<<cdiv(N_,4),256,0,stream>>>(hbuf, as2, ad2, als, ald);
    k_prep<<<1,64,0,stream>>>(We2, ae2, asum, Vbuf, alloop);
    k_al_edge<<<cdiv(E_*4,256),256,0,stream>>>(ea, Vbuf, ale);
    k_aggregate4<false><<<cdiv(N_,4),256,0,stream>>>(hbuf8, als, ald, ale, alloop,
                                                     rs, ssrc, seid, b2, out);

    // ---- edge_index passthrough ----
    k_edge_store<<<cdiv((int)OUT1,256),256,0,stream>>>(ei, out + OUT0);
}

// Round 13
// 503.345 us; speedup vs baseline: 13.8942x; 1.0585x over previous
//
#include <hip/hip_runtime.h>
#include <hip/hip_bf16.h>

// Problem constants
constexpr int N_  = 50000;
constexpr int E_  = 800000;
constexpr int E2_ = 850000;   // E + N self loops
constexpr int FIN = 128;
constexpr int FH  = 256;      // H * C = 4 * 64
constexpr float BN_EPS = 1e-5f;
constexpr float NEG_ATT = 0.2f;
constexpr float NEG_OUT = 0.1f;
constexpr size_t OUT0 = (size_t)N_ * FH;   // 12.8M feature elems (fp32)
constexpr size_t OUT1 = (size_t)2 * E_;    // 1.6M edge elems (fp32)
constexpr int SCAN_NBLK = (N_ + 255) / 256;   // 196
constexpr int ATTR_NBLK = 1024;

static inline int cdiv(int a, int b){ return (a + b - 1) / b; }

using short8 = __attribute__((ext_vector_type(8))) short;
using f32x4  = __attribute__((ext_vector_type(4))) float;
using f32x2  = __attribute__((ext_vector_type(2))) float;

#if __has_builtin(__builtin_amdgcn_cvt_pk_f32_fp8) && __has_builtin(__builtin_amdgcn_cvt_pk_fp8_f32)
#define FP8_HW 1
#else
#define FP8_HW 0
#endif

__device__ inline float lrelu(float v, float ns){ return v > 0.f ? v : ns * v; }

__device__ inline unsigned short bf16rne(float f){
    unsigned u = __float_as_uint(f);
    u += 0x7fffu + ((u >> 16) & 1u);
    return (unsigned short)(u >> 16);
}
__device__ inline float bf16lo(unsigned u){ return __uint_as_float(u << 16); }
__device__ inline float bf16hi(unsigned u){ return __uint_as_float(u & 0xffff0000u); }
__device__ inline float bf16f(unsigned short v){ return __uint_as_float((unsigned)v << 16); }

// ---- software e4m3fn codec (fallback only; HW cvt used when available) ----
__device__ inline float fp8dec1(unsigned b){
    unsigned s = b >> 7;
    unsigned e = (b >> 3) & 15;
    unsigned m = b & 7;
    float v;
    if (e == 0) v = (float)m * 0.001953125f;           // m * 2^-9
    else        v = __uint_as_float(((e + 120u) << 23) | (m << 20));
    return s ? -v : v;
}
__device__ inline unsigned fp8enc1(float f){
    unsigned u = __float_as_uint(f);
    unsigned s = (u >> 31) << 7;
    float af = fabsf(f);
    if (af >= 448.f) return s | 0x7Eu;
    if (af < 0.0009765625f) return s;                   // < 2^-10 -> 0
    if (af < 0.015625f){                                // subnormal range
        int q = (int)(af * 512.f + 0.5f);               // round to m*2^-9
        return s | (unsigned)q;
    }
    unsigned a = u & 0x7fffffffu;
    a += 0x7FFFFu + ((a >> 20) & 1u);                   // RNE at mantissa bit 20
    int e8 = (int)(a >> 23) - 120;
    unsigned m8 = (a >> 20) & 7u;
    if (e8 > 15 || (e8 == 15 && m8 == 7u)) return s | 0x7Eu;
    return s | ((unsigned)e8 << 3) | m8;
}
__device__ inline void dec4(unsigned g, float& f0, float& f1, float& f2, float& f3){
#if FP8_HW
    f32x2 lo = __builtin_amdgcn_cvt_pk_f32_fp8((int)g, false);
    f32x2 hi = __builtin_amdgcn_cvt_pk_f32_fp8((int)g, true);
    f0 = lo[0]; f1 = lo[1]; f2 = hi[0]; f3 = hi[1];
#else
    f0 = fp8dec1(g & 255u); f1 = fp8dec1((g >> 8) & 255u);
    f2 = fp8dec1((g >> 16) & 255u); f3 = fp8dec1(g >> 24);
#endif
}

__global__ void k_sentinel(float* out, float v){ out[0] = v; }

__global__ void k_zero32(unsigned* p, int n){
    int i = blockIdx.x * blockDim.x + threadIdx.x;
    if (i < n) p[i] = 0u;
}

// ---------- W [K][256] fp32 -> WT [256][K] bf16 ----------
__global__ void k_w2t(const float* __restrict__ W, unsigned short* __restrict__ WT, int K){
    int i = blockIdx.x * blockDim.x + threadIdx.x;
    if (i >= K * 256) return;
    int k = i >> 8, c = i & 255;
    WT[(size_t)c * K + k] = bf16rne(W[i]);
}

// ---------- hbuf bf16 -> hbuf8 fp8 (streaming) ----------
__global__ void k_h2fp8(const unsigned short* __restrict__ hb, unsigned* __restrict__ h8){
    size_t tot = (size_t)N_ * 256 / 4;   // 3.2M uints
    size_t step = (size_t)gridDim.x * blockDim.x;
    for (size_t i = blockIdx.x * (size_t)blockDim.x + threadIdx.x; i < tot; i += step){
        uint2 g = *reinterpret_cast<const uint2*>(hb + i * 4);
        float f0 = bf16lo(g.x), f1 = bf16hi(g.x), f2 = bf16lo(g.y), f3 = bf16hi(g.y);
#if FP8_HW
        int lo = __builtin_amdgcn_cvt_pk_fp8_f32(f0, f1, 0, false);
        int pk = __builtin_amdgcn_cvt_pk_fp8_f32(f2, f3, lo, true);
        h8[i] = (unsigned)pk;
#else
        h8[i] = fp8enc1(f0) | (fp8enc1(f1) << 8) | (fp8enc1(f2) << 16) | (fp8enc1(f3) << 24);
#endif
    }
}

// ---------- BatchNorm stats (fp32 input) ----------
__global__ void k_bn_stats(const float* __restrict__ x, int F,
                           float* __restrict__ sum, float* __restrict__ sumsq){
    int gid = blockIdx.x * blockDim.x + threadIdx.x;
    int T = gridDim.x * blockDim.x;      // 65536
    int c = gid % F;
    int r0 = gid / F;
    int rstep = T / F;
    float s = 0.f, s2 = 0.f;
    for (int r = r0; r < N_; r += rstep){
        float v = x[(size_t)r * F + c];
        s += v; s2 += v * v;
    }
    atomicAdd(&sum[c], s);
    atomicAdd(&sumsq[c], s2);
}

// ---------- BatchNorm stats (bf16 input) ----------
__global__ void k_bn_stats_b16(const unsigned short* __restrict__ x, int F,
                               float* __restrict__ sum, float* __restrict__ sumsq){
    int gid = blockIdx.x * blockDim.x + threadIdx.x;
    int T = gridDim.x * blockDim.x;
    int c = gid % F;
    int r0 = gid / F;
    int rstep = T / F;
    float s = 0.f, s2 = 0.f;
    for (int r = r0; r < N_; r += rstep){
        float v = bf16f(x[(size_t)r * F + c]);
        s += v; s2 += v * v;
    }
    atomicAdd(&sum[c], s);
    atomicAdd(&sumsq[c], s2);
}

// BN + lrelu, fp32 in -> bf16 out
__global__ void k_bn_apply_bf(const float* __restrict__ x, const float* __restrict__ sum,
                              const float* __restrict__ sumsq, const float* __restrict__ gamma,
                              const float* __restrict__ beta, unsigned short* __restrict__ out, int F){
    size_t tot = (size_t)N_ * F;
    size_t step = (size_t)gridDim.x * blockDim.x;
    for (size_t i = blockIdx.x * (size_t)blockDim.x + threadIdx.x; i < tot; i += step){
        int c = (int)(i % F);
        float mean = sum[c] / (float)N_;
        float var = sumsq[c] / (float)N_ - mean * mean;
        float v = (x[i] - mean) * rsqrtf(var + BN_EPS) * gamma[c] + beta[c];
        out[i] = bf16rne(lrelu(v, NEG_OUT));
    }
}

// BN + lrelu, bf16 in -> bf16 out
__global__ void k_bn_apply_b16(const unsigned short* __restrict__ x, const float* __restrict__ sum,
                               const float* __restrict__ sumsq, const float* __restrict__ gamma,
                               const float* __restrict__ beta, unsigned short* __restrict__ out, int F){
    size_t tot = (size_t)N_ * F;
    size_t step = (size_t)gridDim.x * blockDim.x;
    for (size_t i = blockIdx.x * (size_t)blockDim.x + threadIdx.x; i < tot; i += step){
        int c = (int)(i % F);
        float mean = sum[c] / (float)N_;
        float var = sumsq[c] / (float)N_ - mean * mean;
        float v = (bf16f(x[i]) - mean) * rsqrtf(var + BN_EPS) * gamma[c] + beta[c];
        out[i] = bf16rne(lrelu(v, NEG_OUT));
    }
}

// ---------- MFMA GEMM: C[M x 256] = A[M x K] @ B[K x 256] (A,WT,C all bf16) ----------
__global__ __launch_bounds__(256) void k_gemm_mfma(const unsigned short* __restrict__ A,
                                                   const unsigned short* __restrict__ WT,
                                                   unsigned short* __restrict__ C, int M, int K){
    __shared__ unsigned short Al[64][32];   // 4KB
    __shared__ unsigned short Bl[64][32];   // 4KB  (Bl[col][k])
    int tid = threadIdx.x;
    int w = tid >> 6;
    int l = tid & 63;
    int row0 = blockIdx.x * 64;
    int col0 = blockIdx.y * 64;
    f32x4 acc[4];
    #pragma unroll
    for (int m = 0; m < 4; ++m) acc[m] = (f32x4){0.f, 0.f, 0.f, 0.f};

    int srow = tid >> 2;
    int skq  = (tid & 3) * 8;

    for (int k0 = 0; k0 < K; k0 += 32){
        {
            short8 v = {0,0,0,0,0,0,0,0};
            if (row0 + srow < M)
                v = *reinterpret_cast<const short8*>(A + (size_t)(row0 + srow) * K + k0 + skq);
            *reinterpret_cast<short8*>(&Al[srow][skq]) = v;
        }
        {
            short8 v = *reinterpret_cast<const short8*>(WT + (size_t)(col0 + srow) * K + k0 + skq);
            *reinterpret_cast<short8*>(&Bl[srow][skq]) = v;
        }
        __syncthreads();
        short8 b = *reinterpret_cast<const short8*>(&Bl[w * 16 + (l & 15)][8 * (l >> 4)]);
        #pragma unroll
        for (int m = 0; m < 4; ++m){
            short8 a = *reinterpret_cast<const short8*>(&Al[m * 16 + (l & 15)][8 * (l >> 4)]);
            acc[m] = __builtin_amdgcn_mfma_f32_16x16x32_bf16(a, b, acc[m], 0, 0, 0);
        }
        __syncthreads();
    }
    int ccol = col0 + w * 16 + (l & 15);
    #pragma unroll
    for (int m = 0; m < 4; ++m){
        #pragma unroll
        for (int r = 0; r < 4; ++r){
            int row = row0 + m * 16 + (l >> 4) * 4 + r;
            if (row < M) C[(size_t)row * 256 + ccol] = bf16rne(acc[m][r]);
        }
    }
}

// ---------- per-node attention terms: one wave per node, bf16 h ----------
__global__ __launch_bounds__(256) void k_al(const unsigned short* __restrict__ hb,
                                            const float* __restrict__ asrc,
                                            const float* __restrict__ adst,
                                            float* __restrict__ als, float* __restrict__ ald){
    int n = blockIdx.x * 4 + (threadIdx.x >> 6);
    if (n >= N_) return;
    int lane = threadIdx.x & 63;
    uint2 g = *reinterpret_cast<const uint2*>(hb + (size_t)n * 256 + lane * 4);
    float h0 = bf16lo(g.x), h1 = bf16hi(g.x), h2 = bf16lo(g.y), h3 = bf16hi(g.y);
    float4 as = *reinterpret_cast<const float4*>(asrc + lane * 4);
    float4 ad = *reinterpret_cast<const float4*>(adst + lane * 4);
    float ps = h0*as.x + h1*as.y + h2*as.z + h3*as.w;
    float pd = h0*ad.x + h1*ad.y + h2*ad.z + h3*ad.w;
    #pragma unroll
    for (int m = 1; m < 16; m <<= 1){
        ps += __shfl_xor(ps, m, 64);
        pd += __shfl_xor(pd, m, 64);
    }
    if ((lane & 15) == 0){
        int hd = lane >> 4;
        als[(size_t)n*4 + hd] = ps;
        ald[(size_t)n*4 + hd] = pd;
    }
}

// ---------- edge_attr column sums: block partials (NO global atomics) ----------
__global__ __launch_bounds__(256) void k_attr_sum(const float* __restrict__ ea,
                                                  float* __restrict__ part){
    __shared__ float4 sdata[256];
    int tid = threadIdx.x;
    const float4* p = reinterpret_cast<const float4*>(ea);
    size_t step = (size_t)gridDim.x * 256;
    size_t end = (size_t)E_ * 4;
    size_t j = (size_t)blockIdx.x * 256 + tid;
    float4 a0 = make_float4(0.f,0.f,0.f,0.f), a1 = a0, a2 = a0, a3 = a0;
    for (; j + 3 * step < end; j += 4 * step){
        float4 v0 = p[j], v1 = p[j + step], v2 = p[j + 2*step], v3 = p[j + 3*step];
        a0.x += v0.x; a0.y += v0.y; a0.z += v0.z; a0.w += v0.w;
        a1.x += v1.x; a1.y += v1.y; a1.z += v1.z; a1.w += v1.w;
        a2.x += v2.x; a2.y += v2.y; a2.z += v2.z; a2.w += v2.w;
        a3.x += v3.x; a3.y += v3.y; a3.z += v3.z; a3.w += v3.w;
    }
    for (; j < end; j += step){
        float4 v = p[j];
        a0.x += v.x; a0.y += v.y; a0.z += v.z; a0.w += v.w;
    }
    a0.x += a1.x + a2.x + a3.x;  a0.y += a1.y + a2.y + a3.y;
    a0.z += a1.z + a2.z + a3.z;  a0.w += a1.w + a2.w + a3.w;
    sdata[tid] = a0;
    __syncthreads();
    #pragma unroll
    for (int s = 128; s >= 4; s >>= 1){
        if (tid < s){
            float4 o = sdata[tid + s];
            float4 m = sdata[tid];
            m.x += o.x; m.y += o.y; m.z += o.z; m.w += o.w;
            sdata[tid] = m;
        }
        __syncthreads();
    }
    if (tid < 4){   // thread tid holds column-quad tid -> columns [tid*4, tid*4+4)
        float4 m = sdata[tid];
        float* pp = part + (size_t)blockIdx.x * 16 + tid * 4;
        pp[0] = m.x; pp[1] = m.y; pp[2] = m.z; pp[3] = m.w;
    }
}

// final reduce of part[ATTR_NBLK][16] -> asum[16]
__global__ __launch_bounds__(256) void k_attr_fin(const float* __restrict__ part,
                                                  float* __restrict__ asum){
    __shared__ float sd[256];
    int t = threadIdx.x;
    int col = t & 15, seg = t >> 4;   // 16 segments
    float s = 0.f;
    for (int b = seg; b < ATTR_NBLK; b += 16) s += part[(size_t)b * 16 + col];
    sd[t] = s;
    __syncthreads();
    #pragma unroll
    for (int off = 128; off >= 16; off >>= 1){
        if (t < off) sd[t] += sd[t + off];
        __syncthreads();
    }
    if (t < 16) asum[t] = sd[t];
}

// ---------- V[k][h]; alloop[h] ----------
__global__ void k_prep(const float* __restrict__ We, const float* __restrict__ aedge,
                       const float* __restrict__ asum, float* __restrict__ V,
                       float* __restrict__ alloop){
    __shared__ float Vs[64];
    int t = threadIdx.x;  // 64 threads
    int k = t >> 2, hd = t & 3;
    float s = 0.f;
    for (int c = 0; c < 64; ++c) s += We[k * 256 + hd * 64 + c] * aedge[hd * 64 + c];
    Vs[t] = s;
    V[t] = s;
    __syncthreads();
    if (t < 4){
        float r = 0.f;
        for (int kk = 0; kk < 16; ++kk) r += (asum[kk] / (float)E_) * Vs[kk * 4 + t];
        alloop[t] = r;
    }
}

// ---------- al_edge ----------
__global__ void k_al_edge(const float* __restrict__ ea, const float* __restrict__ V,
                          float* __restrict__ ale){
    int idx = blockIdx.x * blockDim.x + threadIdx.x;   // E*4
    if (idx >= E_ * 4) return;
    int e = idx >> 2, hd = idx & 3;
    const float* ep = ea + (size_t)e * 16;
    float s = 0.f;
    #pragma unroll
    for (int k = 0; k < 16; ++k) s += ep[k] * V[k * 4 + hd];
    ale[idx] = s;
}

// ---------- CSR build ----------
__global__ void k_count(const int* __restrict__ ei, int* __restrict__ counts){
    int e = blockIdx.x * blockDim.x + threadIdx.x;
    if (e >= E2_) return;
    int d = (e < E_) ? ei[E_ + e] : (e - E_);
    atomicAdd(&counts[d], 1);
}

__global__ __launch_bounds__(256) void k_scan_local(const int* __restrict__ counts,
                                                    int* __restrict__ rs,
                                                    int* __restrict__ bsum){
    __shared__ int sd[256];
    int t = threadIdx.x;
    int idx = blockIdx.x * 256 + t;
    int c = (idx < N_) ? counts[idx] : 0;
    sd[t] = c;
    __syncthreads();
    #pragma unroll
    for (int off = 1; off < 256; off <<= 1){
        int o = (t >= off) ? sd[t - off] : 0;
        __syncthreads();
        sd[t] += o;
        __syncthreads();
    }
    if (idx < N_) rs[idx] = sd[t] - c;
    if (t == 255) bsum[blockIdx.x] = sd[255];
}

__global__ __launch_bounds__(256) void k_scan_block(const int* __restrict__ bsum,
                                                    int* __restrict__ boff,
                                                    int* __restrict__ rs){
    __shared__ int sd[256];
    int t = threadIdx.x;
    int v = (t < SCAN_NBLK) ? bsum[t] : 0;
    sd[t] = v;
    __syncthreads();
    #pragma unroll
    for (int off = 1; off < 256; off <<= 1){
        int o = (t >= off) ? sd[t - off] : 0;
        __syncthreads();
        sd[t] += o;
        __syncthreads();
    }
    if (t < SCAN_NBLK) boff[t] = sd[t] - v;
    if (t == 0) rs[N_] = E2_;
}

__global__ __launch_bounds__(256) void k_scan_add(int* __restrict__ rs,
                                                  const int* __restrict__ boff){
    int idx = blockIdx.x * 256 + threadIdx.x;
    if (idx < N_) rs[idx] += boff[blockIdx.x];
}

__global__ void k_scatter(const int* __restrict__ ei, const int* __restrict__ rs,
                          int* __restrict__ cursor, int* __restrict__ ssrc, int* __restrict__ seid){
    int e = blockIdx.x * blockDim.x + threadIdx.x;
    if (e >= E2_) return;
    int s, d;
    if (e < E_){ s = ei[e]; d = ei[E_ + e]; }
    else { s = e - E_; d = s; }
    int slot = rs[d] + atomicAdd(&cursor[d], 1);
    ssrc[slot] = s;
    seid[slot] = e;
}

// ---------- one wave per dst node, FOUR independent edge streams, fp8 gather ----------
#define MERGE4(OFF) { \
    float mo  = __shfl_xor(m,   OFF, 64); \
    float dno = __shfl_xor(den, OFF, 64); \
    float o0=__shfl_xor(a0,OFF,64), o1=__shfl_xor(a1,OFF,64), o2=__shfl_xor(a2,OFF,64), o3=__shfl_xor(a3,OFF,64); \
    float o4=__shfl_xor(a4,OFF,64), o5=__shfl_xor(a5,OFF,64), o6=__shfl_xor(a6,OFF,64), o7=__shfl_xor(a7,OFF,64); \
    float o8=__shfl_xor(a8,OFF,64), o9=__shfl_xor(a9,OFF,64), oA=__shfl_xor(aA,OFF,64), oB=__shfl_xor(aB,OFF,64); \
    float oC=__shfl_xor(aC,OFF,64), oD=__shfl_xor(aD,OFF,64), oE=__shfl_xor(aE,OFF,64), oF=__shfl_xor(aF,OFF,64); \
    float M = fmaxf(m, mo); \
    float sS = __expf(m - M), sO = __expf(mo - M); \
    den = den*sS + dno*sO; \
    a0=a0*sS+o0*sO; a1=a1*sS+o1*sO; a2=a2*sS+o2*sO; a3=a3*sS+o3*sO; \
    a4=a4*sS+o4*sO; a5=a5*sS+o5*sO; a6=a6*sS+o6*sO; a7=a7*sS+o7*sO; \
    a8=a8*sS+o8*sO; a9=a9*sS+o9*sO; aA=aA*sS+oA*sO; aB=aB*sS+oB*sO; \
    aC=aC*sS+oC*sO; aD=aD*sS+oD*sO; aE=aE*sS+oE*sO; aF=aF*sS+oF*sO; \
    m = M; }

template<bool BF16OUT>
__global__ __launch_bounds__(256) void k_aggregate4(const unsigned char* __restrict__ hb8,
        const float* __restrict__ als, const float* __restrict__ ald,
        const float* __restrict__ ale, const float* __restrict__ alloop,
        const int* __restrict__ rs, const int* __restrict__ ssrc, const int* __restrict__ seid,
        const float* __restrict__ bias, void* __restrict__ outp){
    int n = blockIdx.x * 4 + (threadIdx.x >> 6);
    if (n >= N_) return;
    int lane = threadIdx.x & 63;
    int q  = lane >> 4;
    int sl = lane & 15;
    int col0 = sl * 16;
    int hd = sl >> 2;
    float aldn = ald[(size_t)n * 4 + hd];
    float alp  = alloop[hd];
    int i0 = rs[n], i1 = rs[n + 1];
    float m = -3.0e38f, den = 0.f;
    float a0=0.f,a1=0.f,a2=0.f,a3=0.f,a4=0.f,a5=0.f,a6=0.f,a7=0.f;
    float a8=0.f,a9=0.f,aA=0.f,aB=0.f,aC=0.f,aD=0.f,aE=0.f,aF=0.f;
    for (int i = i0 + q; i < i1; i += 4){
        int s   = ssrc[i];
        int eid = seid[i];
        float alE = (eid < E_) ? ale[(size_t)eid * 4 + hd] : alp;
        float lg = als[(size_t)s * 4 + hd] + aldn + alE;
        lg = lrelu(lg, NEG_ATT);
        float mn = fmaxf(m, lg);
        float sc = __expf(m - mn);
        float p  = __expf(lg - mn);
        den = den * sc + p;
        uint4 g = *reinterpret_cast<const uint4*>(hb8 + (size_t)s * 256 + col0);
        float t0, t1, t2, t3;
        dec4(g.x, t0, t1, t2, t3);
        a0 = a0*sc + p*t0;  a1 = a1*sc + p*t1;  a2 = a2*sc + p*t2;  a3 = a3*sc + p*t3;
        dec4(g.y, t0, t1, t2, t3);
        a4 = a4*sc + p*t0;  a5 = a5*sc + p*t1;  a6 = a6*sc + p*t2;  a7 = a7*sc + p*t3;
        dec4(g.z, t0, t1, t2, t3);
        a8 = a8*sc + p*t0;  a9 = a9*sc + p*t1;  aA = aA*sc + p*t2;  aB = aB*sc + p*t3;
        dec4(g.w, t0, t1, t2, t3);
        aC = aC*sc + p*t0;  aD = aD*sc + p*t1;  aE = aE*sc + p*t2;  aF = aF*sc + p*t3;
        m = mn;
    }
    MERGE4(16)
    MERGE4(32)
    float inv = 1.f / den;
    float v0, v1, v2, v3;
    if      (q == 0){ v0 = a0; v1 = a1; v2 = a2; v3 = a3; }
    else if (q == 1){ v0 = a4; v1 = a5; v2 = a6; v3 = a7; }
    else if (q == 2){ v0 = a8; v1 = a9; v2 = aA; v3 = aB; }
    else            { v0 = aC; v1 = aD; v2 = aE; v3 = aF; }
    int wc = col0 + q * 4;
    float4 b4 = *reinterpret_cast<const float4*>(bias + wc);
    float r0 = lrelu(v0 * inv + b4.x, NEG_OUT);
    float r1 = lrelu(v1 * inv + b4.y, NEG_OUT);
    float r2 = lrelu(v2 * inv + b4.z, NEG_OUT);
    float r3 = lrelu(v3 * inv + b4.w, NEG_OUT);
    if (BF16OUT){
        ushort4 pk;
        pk.x = bf16rne(r0); pk.y = bf16rne(r1); pk.z = bf16rne(r2); pk.w = bf16rne(r3);
        *reinterpret_cast<ushort4*>((unsigned short*)outp + (size_t)n * 256 + wc) = pk;
    } else {
        *reinterpret_cast<float4*>((float*)outp + (size_t)n * 256 + wc) =
            make_float4(r0, r1, r2, r3);
    }
}

// ---------- edge_index passthrough (fp32, bit-exact) ----------
__global__ void k_edge_store(const int* __restrict__ ei, float* __restrict__ out){
    int j = blockIdx.x * blockDim.x + threadIdx.x;     // 2E
    if (j >= (int)OUT1) return;
    out[j] = (float)ei[j];
}

extern "C" void kernel_launch(void* const* d_in, const int* in_sizes, int n_in,
                              void* d_out, int out_size, void* d_ws, size_t ws_size,
                              hipStream_t stream){
    const float* x    = (const float*)d_in[0];
    const int*   ei   = (const int*)d_in[1];
    const float* ea   = (const float*)d_in[2];
    const float* bn1g = (const float*)d_in[3];
    const float* bn1b = (const float*)d_in[4];
    const float* W1   = (const float*)d_in[5];
    const float* We1  = (const float*)d_in[6];
    const float* as1  = (const float*)d_in[7];
    const float* ad1  = (const float*)d_in[8];
    const float* ae1  = (const float*)d_in[9];
    const float* b1   = (const float*)d_in[10];
    const float* bn2g = (const float*)d_in[11];
    const float* bn2b = (const float*)d_in[12];
    const float* W2   = (const float*)d_in[13];
    const float* We2  = (const float*)d_in[14];
    const float* as2  = (const float*)d_in[15];
    const float* ad2  = (const float*)d_in[16];
    const float* ae2  = (const float*)d_in[17];
    const float* b2   = (const float*)d_in[18];
    float* out = (float*)d_out;

    bool ok = (n_in >= 19)
           && (in_sizes[0] == N_ * FIN)
           && (in_sizes[1] == 2 * E_)
           && (in_sizes[2] == E_ * 16)
           && (out_size == (int)(OUT0 + OUT1));
    if (!ok){ k_sentinel<<<1,1,0,stream>>>(out, 7777.f); return; }

    char* w = (char*)d_ws;
    size_t off = 0;
    auto alloc = [&](size_t bytes) -> void* {
        off = (off + 255) & ~(size_t)255;
        void* p = w + off;
        off += bytes;
        return p;
    };
    float* stats  = (float*)alloc(512 * 4);
    float* asum   = (float*)alloc(16 * 4);
    float* apart  = (float*)alloc((size_t)ATTR_NBLK * 16 * 4);   // 64KB
    float* Vbuf   = (float*)alloc(64 * 4);
    float* alloop = (float*)alloc(4 * 4);
    float* als    = (float*)alloc((size_t)N_ * 4 * 4);
    float* ald    = (float*)alloc((size_t)N_ * 4 * 4);
    float* ale    = (float*)alloc((size_t)E_ * 4 * 4);          // 12.8MB
    int*   rs     = (int*)alloc((size_t)(N_ + 1) * 4);
    int*   counts = (int*)alloc((size_t)N_ * 4);
    int*   cursor = (int*)alloc((size_t)N_ * 4);
    int*   bsum   = (int*)alloc((size_t)SCAN_NBLK * 4);
    int*   boff   = (int*)alloc((size_t)SCAN_NBLK * 4);
    int*   ssrc   = (int*)alloc((size_t)E2_ * 4);
    int*   seid   = (int*)alloc((size_t)E2_ * 4);
    unsigned short* WT1 = (unsigned short*)alloc((size_t)256 * FIN * 2);  // 64KB
    unsigned short* WT2 = (unsigned short*)alloc((size_t)256 * FH * 2);   // 128KB
    unsigned short* bufC = (unsigned short*)alloc((size_t)N_ * 256 * 2);  // 25.6MB bf16
    unsigned short* hbuf = (unsigned short*)alloc((size_t)N_ * 256 * 2);  // 25.6MB bf16
    unsigned char*  hbuf8 = (unsigned char*)alloc((size_t)N_ * 256);      // 12.8MB fp8
    unsigned short* bufB = (unsigned short*)alloc((size_t)N_ * 256 * 2);  // 25.6MB bf16
    if (off > ws_size){ k_sentinel<<<1,1,0,stream>>>(out, 5555.f); return; }

    float* ssum = stats;
    float* ssq  = stats + 256;
    const int GX = cdiv(N_, 64);    // 782

    // ---- CSR build (shared by both layers) ----
    k_zero32<<<cdiv(N_,256),256,0,stream>>>((unsigned*)counts, N_);
    k_zero32<<<cdiv(N_,256),256,0,stream>>>((unsigned*)cursor, N_);
    k_count<<<cdiv(E2_,256),256,0,stream>>>(ei, counts);
    k_scan_local<<<SCAN_NBLK,256,0,stream>>>(counts, rs, bsum);
    k_scan_block<<<1,256,0,stream>>>(bsum, boff, rs);
    k_scan_add<<<SCAN_NBLK,256,0,stream>>>(rs, boff);
    k_scatter<<<cdiv(E2_,256),256,0,stream>>>(ei, rs, cursor, ssrc, seid);

    // ---- shared precompute ----
    k_zero32<<<2,256,0,stream>>>((unsigned*)stats, 512);
    k_attr_sum<<<ATTR_NBLK,256,0,stream>>>(ea, apart);
    k_attr_fin<<<1,256,0,stream>>>(apart, asum);
    k_w2t<<<FIN,256,0,stream>>>(W1, WT1, FIN);
    k_w2t<<<FH,256,0,stream>>>(W2, WT2, FH);

    // ---- BN1 + lrelu (fp32 -> bf16) ----
    k_bn_stats<<<256,256,0,stream>>>(x, FIN, ssum, ssq);
    k_bn_apply_bf<<<2048,256,0,stream>>>(x, ssum, ssq, bn1g, bn1b, bufC, FIN);

    // ---- GAT layer 1 ----
    k_gemm_mfma<<<dim3(GX,4),256,0,stream>>>(bufC, WT1, hbuf, N_, FIN);
    k_h2fp8<<<2048,256,0,stream>>>(hbuf, (unsigned*)hbuf8);
    k_al<<<cdiv(N_,4),256,0,stream>>>(hbuf, as1, ad1, als, ald);
    k_prep<<<1,64,0,stream>>>(We1, ae1, asum, Vbuf, alloop);
    k_al_edge<<<cdiv(E_*4,256),256,0,stream>>>(ea, Vbuf, ale);
    k_aggregate4<true><<<cdiv(N_,4),256,0,stream>>>(hbuf8, als, ald, ale, alloop,
                                                    rs, ssrc, seid, b1, bufB);

    // ---- BN2 + lrelu (bf16 -> bf16) ----
    k_zero32<<<2,256,0,stream>>>((unsigned*)stats, 512);
    k_bn_stats_b16<<<256,256,0,stream>>>(bufB, FH, ssum, ssq);
    k_bn_apply_b16<<<2048,256,0,stream>>>(bufB, ssum, ssq, bn2g, bn2b, bufC, FH);

    // ---- GAT layer 2 ----
    k_gemm_mfma<<<dim3(GX,4),256,0,stream>>>(bufC, WT2, hbuf, N_, FH);
    k_h2fp8<<<2048,256,0,stream>>>(hbuf, (unsigned*)hbuf8);
    k_al<<<cdiv(N_,4),256,0,stream>>>(hbuf, as2, ad2, als, ald);
    k_prep<<<1,64,0,stream>>>(We2, ae2, asum, Vbuf, alloop);
    k_al_edge<<<cdiv(E_*4,256),256,0,stream>>>(ea, Vbuf, ale);
    k_aggregate4<false><<<cdiv(N_,4),256,0,stream>>>(hbuf8, als, ald, ale, alloop,
                                                     rs, ssrc, seid, b2, out);

    // ---- edge_index passthrough ----
    k_edge_store<<<cdiv((int)OUT1,256),256,0,stream>>>(ei, out + OUT0);
}

// Round 14
// 473.684 us; speedup vs baseline: 14.7642x; 1.0626x over previous
//
#include <hip/hip_runtime.h>
#include <hip/hip_bf16.h>

// Problem constants
constexpr int N_  = 50000;
constexpr int E_  = 800000;
constexpr int E2_ = 850000;   // E + N self loops
constexpr int FIN = 128;
constexpr int FH  = 256;      // H * C = 4 * 64
constexpr float BN_EPS = 1e-5f;
constexpr float NEG_ATT = 0.2f;
constexpr float NEG_OUT = 0.1f;
constexpr size_t OUT0 = (size_t)N_ * FH;   // 12.8M feature elems (fp32)
constexpr size_t OUT1 = (size_t)2 * E_;    // 1.6M edge elems (fp32)
constexpr int SCAN_NBLK = (N_ + 255) / 256;   // 196
constexpr int ATTR_NBLK = 1024;

static inline int cdiv(int a, int b){ return (a + b - 1) / b; }

using short8 = __attribute__((ext_vector_type(8))) short;
using f32x4  = __attribute__((ext_vector_type(4))) float;
using f32x2  = __attribute__((ext_vector_type(2))) float;

#if __has_builtin(__builtin_amdgcn_cvt_pk_f32_fp8) && __has_builtin(__builtin_amdgcn_cvt_pk_fp8_f32)
#define FP8_HW 1
#else
#define FP8_HW 0
#endif

__device__ inline float lrelu(float v, float ns){ return v > 0.f ? v : ns * v; }

__device__ inline unsigned short bf16rne(float f){
    unsigned u = __float_as_uint(f);
    u += 0x7fffu + ((u >> 16) & 1u);
    return (unsigned short)(u >> 16);
}
__device__ inline float bf16lo(unsigned u){ return __uint_as_float(u << 16); }
__device__ inline float bf16hi(unsigned u){ return __uint_as_float(u & 0xffff0000u); }
__device__ inline float bf16f(unsigned short v){ return __uint_as_float((unsigned)v << 16); }

// ---- software e4m3fn codec (fallback only; HW cvt used when available) ----
__device__ inline float fp8dec1(unsigned b){
    unsigned s = b >> 7;
    unsigned e = (b >> 3) & 15;
    unsigned m = b & 7;
    float v;
    if (e == 0) v = (float)m * 0.001953125f;           // m * 2^-9
    else        v = __uint_as_float(((e + 120u) << 23) | (m << 20));
    return s ? -v : v;
}
__device__ inline unsigned fp8enc1(float f){
    unsigned u = __float_as_uint(f);
    unsigned s = (u >> 31) << 7;
    float af = fabsf(f);
    if (af >= 448.f) return s | 0x7Eu;
    if (af < 0.0009765625f) return s;                   // < 2^-10 -> 0
    if (af < 0.015625f){                                // subnormal range
        int q = (int)(af * 512.f + 0.5f);               // round to m*2^-9
        return s | (unsigned)q;
    }
    unsigned a = u & 0x7fffffffu;
    a += 0x7FFFFu + ((a >> 20) & 1u);                   // RNE at mantissa bit 20
    int e8 = (int)(a >> 23) - 120;
    unsigned m8 = (a >> 20) & 7u;
    if (e8 > 15 || (e8 == 15 && m8 == 7u)) return s | 0x7Eu;
    return s | ((unsigned)e8 << 3) | m8;
}
__device__ inline void dec4(unsigned g, float& f0, float& f1, float& f2, float& f3){
#if FP8_HW
    f32x2 lo = __builtin_amdgcn_cvt_pk_f32_fp8((int)g, false);
    f32x2 hi = __builtin_amdgcn_cvt_pk_f32_fp8((int)g, true);
    f0 = lo[0]; f1 = lo[1]; f2 = hi[0]; f3 = hi[1];
#else
    f0 = fp8dec1(g & 255u); f1 = fp8dec1((g >> 8) & 255u);
    f2 = fp8dec1((g >> 16) & 255u); f3 = fp8dec1(g >> 24);
#endif
}

__global__ void k_sentinel(float* out, float v){ out[0] = v; }

__global__ void k_zero32(unsigned* p, int n){
    int i = blockIdx.x * blockDim.x + threadIdx.x;
    if (i < n) p[i] = 0u;
}

// ---------- W [K][256] fp32 -> WT [256][K] bf16 ----------
__global__ void k_w2t(const float* __restrict__ W, unsigned short* __restrict__ WT, int K){
    int i = blockIdx.x * blockDim.x + threadIdx.x;
    if (i >= K * 256) return;
    int k = i >> 8, c = i & 255;
    WT[(size_t)c * K + k] = bf16rne(W[i]);
}

// ---------- hbuf bf16 -> hbuf8 fp8 (streaming) ----------
__global__ void k_h2fp8(const unsigned short* __restrict__ hb, unsigned* __restrict__ h8){
    size_t tot = (size_t)N_ * 256 / 4;   // 3.2M uints
    size_t step = (size_t)gridDim.x * blockDim.x;
    for (size_t i = blockIdx.x * (size_t)blockDim.x + threadIdx.x; i < tot; i += step){
        uint2 g = *reinterpret_cast<const uint2*>(hb + i * 4);
        float f0 = bf16lo(g.x), f1 = bf16hi(g.x), f2 = bf16lo(g.y), f3 = bf16hi(g.y);
#if FP8_HW
        int lo = __builtin_amdgcn_cvt_pk_fp8_f32(f0, f1, 0, false);
        int pk = __builtin_amdgcn_cvt_pk_fp8_f32(f2, f3, lo, true);
        h8[i] = (unsigned)pk;
#else
        h8[i] = fp8enc1(f0) | (fp8enc1(f1) << 8) | (fp8enc1(f2) << 16) | (fp8enc1(f3) << 24);
#endif
    }
}

// ---------- BatchNorm stats (fp32 input) ----------
__global__ void k_bn_stats(const float* __restrict__ x, int F,
                           float* __restrict__ sum, float* __restrict__ sumsq){
    int gid = blockIdx.x * blockDim.x + threadIdx.x;
    int T = gridDim.x * blockDim.x;      // 65536
    int c = gid % F;
    int r0 = gid / F;
    int rstep = T / F;
    float s = 0.f, s2 = 0.f;
    for (int r = r0; r < N_; r += rstep){
        float v = x[(size_t)r * F + c];
        s += v; s2 += v * v;
    }
    atomicAdd(&sum[c], s);
    atomicAdd(&sumsq[c], s2);
}

// ---------- BatchNorm stats (bf16 input) ----------
__global__ void k_bn_stats_b16(const unsigned short* __restrict__ x, int F,
                               float* __restrict__ sum, float* __restrict__ sumsq){
    int gid = blockIdx.x * blockDim.x + threadIdx.x;
    int T = gridDim.x * blockDim.x;
    int c = gid % F;
    int r0 = gid / F;
    int rstep = T / F;
    float s = 0.f, s2 = 0.f;
    for (int r = r0; r < N_; r += rstep){
        float v = bf16f(x[(size_t)r * F + c]);
        s += v; s2 += v * v;
    }
    atomicAdd(&sum[c], s);
    atomicAdd(&sumsq[c], s2);
}

// BN + lrelu, fp32 in -> bf16 out
__global__ void k_bn_apply_bf(const float* __restrict__ x, const float* __restrict__ sum,
                              const float* __restrict__ sumsq, const float* __restrict__ gamma,
                              const float* __restrict__ beta, unsigned short* __restrict__ out, int F){
    size_t tot = (size_t)N_ * F;
    size_t step = (size_t)gridDim.x * blockDim.x;
    for (size_t i = blockIdx.x * (size_t)blockDim.x + threadIdx.x; i < tot; i += step){
        int c = (int)(i % F);
        float mean = sum[c] / (float)N_;
        float var = sumsq[c] / (float)N_ - mean * mean;
        float v = (x[i] - mean) * rsqrtf(var + BN_EPS) * gamma[c] + beta[c];
        out[i] = bf16rne(lrelu(v, NEG_OUT));
    }
}

// BN + lrelu, bf16 in -> bf16 out
__global__ void k_bn_apply_b16(const unsigned short* __restrict__ x, const float* __restrict__ sum,
                               const float* __restrict__ sumsq, const float* __restrict__ gamma,
                               const float* __restrict__ beta, unsigned short* __restrict__ out, int F){
    size_t tot = (size_t)N_ * F;
    size_t step = (size_t)gridDim.x * blockDim.x;
    for (size_t i = blockIdx.x * (size_t)blockDim.x + threadIdx.x; i < tot; i += step){
        int c = (int)(i % F);
        float mean = sum[c] / (float)N_;
        float var = sumsq[c] / (float)N_ - mean * mean;
        float v = (bf16f(x[i]) - mean) * rsqrtf(var + BN_EPS) * gamma[c] + beta[c];
        out[i] = bf16rne(lrelu(v, NEG_OUT));
    }
}

// ---------- MFMA GEMM: C[M x 256] = A[M x K] @ B[K x 256] (A,WT,C all bf16) ----------
__global__ __launch_bounds__(256) void k_gemm_mfma(const unsigned short* __restrict__ A,
                                                   const unsigned short* __restrict__ WT,
                                                   unsigned short* __restrict__ C, int M, int K){
    __shared__ unsigned short Al[64][32];   // 4KB
    __shared__ unsigned short Bl[64][32];   // 4KB  (Bl[col][k])
    int tid = threadIdx.x;
    int w = tid >> 6;
    int l = tid & 63;
    int row0 = blockIdx.x * 64;
    int col0 = blockIdx.y * 64;
    f32x4 acc[4];
    #pragma unroll
    for (int m = 0; m < 4; ++m) acc[m] = (f32x4){0.f, 0.f, 0.f, 0.f};

    int srow = tid >> 2;
    int skq  = (tid & 3) * 8;

    for (int k0 = 0; k0 < K; k0 += 32){
        {
            short8 v = {0,0,0,0,0,0,0,0};
            if (row0 + srow < M)
                v = *reinterpret_cast<const short8*>(A + (size_t)(row0 + srow) * K + k0 + skq);
            *reinterpret_cast<short8*>(&Al[srow][skq]) = v;
        }
        {
            short8 v = *reinterpret_cast<const short8*>(WT + (size_t)(col0 + srow) * K + k0 + skq);
            *reinterpret_cast<short8*>(&Bl[srow][skq]) = v;
        }
        __syncthreads();
        short8 b = *reinterpret_cast<const short8*>(&Bl[w * 16 + (l & 15)][8 * (l >> 4)]);
        #pragma unroll
        for (int m = 0; m < 4; ++m){
            short8 a = *reinterpret_cast<const short8*>(&Al[m * 16 + (l & 15)][8 * (l >> 4)]);
            acc[m] = __builtin_amdgcn_mfma_f32_16x16x32_bf16(a, b, acc[m], 0, 0, 0);
        }
        __syncthreads();
    }
    int ccol = col0 + w * 16 + (l & 15);
    #pragma unroll
    for (int m = 0; m < 4; ++m){
        #pragma unroll
        for (int r = 0; r < 4; ++r){
            int row = row0 + m * 16 + (l >> 4) * 4 + r;
            if (row < M) C[(size_t)row * 256 + ccol] = bf16rne(acc[m][r]);
        }
    }
}

// ---------- per-node attention terms: one wave per node, bf16 h ----------
__global__ __launch_bounds__(256) void k_al(const unsigned short* __restrict__ hb,
                                            const float* __restrict__ asrc,
                                            const float* __restrict__ adst,
                                            float* __restrict__ als, float* __restrict__ ald){
    int n = blockIdx.x * 4 + (threadIdx.x >> 6);
    if (n >= N_) return;
    int lane = threadIdx.x & 63;
    uint2 g = *reinterpret_cast<const uint2*>(hb + (size_t)n * 256 + lane * 4);
    float h0 = bf16lo(g.x), h1 = bf16hi(g.x), h2 = bf16lo(g.y), h3 = bf16hi(g.y);
    float4 as = *reinterpret_cast<const float4*>(asrc + lane * 4);
    float4 ad = *reinterpret_cast<const float4*>(adst + lane * 4);
    float ps = h0*as.x + h1*as.y + h2*as.z + h3*as.w;
    float pd = h0*ad.x + h1*ad.y + h2*ad.z + h3*ad.w;
    #pragma unroll
    for (int m = 1; m < 16; m <<= 1){
        ps += __shfl_xor(ps, m, 64);
        pd += __shfl_xor(pd, m, 64);
    }
    if ((lane & 15) == 0){
        int hd = lane >> 4;
        als[(size_t)n*4 + hd] = ps;
        ald[(size_t)n*4 + hd] = pd;
    }
}

// ---------- edge_attr column sums: block partials (NO global atomics) ----------
__global__ __launch_bounds__(256) void k_attr_sum(const float* __restrict__ ea,
                                                  float* __restrict__ part){
    __shared__ float4 sdata[256];
    int tid = threadIdx.x;
    const float4* p = reinterpret_cast<const float4*>(ea);
    size_t step = (size_t)gridDim.x * 256;
    size_t end = (size_t)E_ * 4;
    size_t j = (size_t)blockIdx.x * 256 + tid;
    float4 a0 = make_float4(0.f,0.f,0.f,0.f), a1 = a0, a2 = a0, a3 = a0;
    for (; j + 3 * step < end; j += 4 * step){
        float4 v0 = p[j], v1 = p[j + step], v2 = p[j + 2*step], v3 = p[j + 3*step];
        a0.x += v0.x; a0.y += v0.y; a0.z += v0.z; a0.w += v0.w;
        a1.x += v1.x; a1.y += v1.y; a1.z += v1.z; a1.w += v1.w;
        a2.x += v2.x; a2.y += v2.y; a2.z += v2.z; a2.w += v2.w;
        a3.x += v3.x; a3.y += v3.y; a3.z += v3.z; a3.w += v3.w;
    }
    for (; j < end; j += step){
        float4 v = p[j];
        a0.x += v.x; a0.y += v.y; a0.z += v.z; a0.w += v.w;
    }
    a0.x += a1.x + a2.x + a3.x;  a0.y += a1.y + a2.y + a3.y;
    a0.z += a1.z + a2.z + a3.z;  a0.w += a1.w + a2.w + a3.w;
    sdata[tid] = a0;
    __syncthreads();
    #pragma unroll
    for (int s = 128; s >= 4; s >>= 1){
        if (tid < s){
            float4 o = sdata[tid + s];
            float4 m = sdata[tid];
            m.x += o.x; m.y += o.y; m.z += o.z; m.w += o.w;
            sdata[tid] = m;
        }
        __syncthreads();
    }
    if (tid < 4){
        float4 m = sdata[tid];
        float* pp = part + (size_t)blockIdx.x * 16 + tid * 4;
        pp[0] = m.x; pp[1] = m.y; pp[2] = m.z; pp[3] = m.w;
    }
}

// final reduce of part[ATTR_NBLK][16] -> asum[16]
__global__ __launch_bounds__(256) void k_attr_fin(const float* __restrict__ part,
                                                  float* __restrict__ asum){
    __shared__ float sd[256];
    int t = threadIdx.x;
    int col = t & 15, seg = t >> 4;   // 16 segments
    float s = 0.f;
    for (int b = seg; b < ATTR_NBLK; b += 16) s += part[(size_t)b * 16 + col];
    sd[t] = s;
    __syncthreads();
    #pragma unroll
    for (int off = 128; off >= 16; off >>= 1){
        if (t < off) sd[t] += sd[t + off];
        __syncthreads();
    }
    if (t < 16) asum[t] = sd[t];
}

// ---------- V[k][h]; alloop[h] ----------
__global__ void k_prep(const float* __restrict__ We, const float* __restrict__ aedge,
                       const float* __restrict__ asum, float* __restrict__ V,
                       float* __restrict__ alloop){
    __shared__ float Vs[64];
    int t = threadIdx.x;  // 64 threads
    int k = t >> 2, hd = t & 3;
    float s = 0.f;
    for (int c = 0; c < 64; ++c) s += We[k * 256 + hd * 64 + c] * aedge[hd * 64 + c];
    Vs[t] = s;
    V[t] = s;
    __syncthreads();
    if (t < 4){
        float r = 0.f;
        for (int kk = 0; kk < 16; ++kk) r += (asum[kk] / (float)E_) * Vs[kk * 4 + t];
        alloop[t] = r;
    }
}

// ---------- al_edge ----------
__global__ void k_al_edge(const float* __restrict__ ea, const float* __restrict__ V,
                          float* __restrict__ ale){
    int idx = blockIdx.x * blockDim.x + threadIdx.x;   // E*4
    if (idx >= E_ * 4) return;
    int e = idx >> 2, hd = idx & 3;
    const float* ep = ea + (size_t)e * 16;
    float s = 0.f;
    #pragma unroll
    for (int k = 0; k < 16; ++k) s += ep[k] * V[k * 4 + hd];
    ale[idx] = s;
}

// ---------- CSR build ----------
__global__ void k_count(const int* __restrict__ ei, int* __restrict__ counts){
    int e = blockIdx.x * blockDim.x + threadIdx.x;
    if (e >= E2_) return;
    int d = (e < E_) ? ei[E_ + e] : (e - E_);
    atomicAdd(&counts[d], 1);
}

__global__ __launch_bounds__(256) void k_scan_local(const int* __restrict__ counts,
                                                    int* __restrict__ rs,
                                                    int* __restrict__ bsum){
    __shared__ int sd[256];
    int t = threadIdx.x;
    int idx = blockIdx.x * 256 + t;
    int c = (idx < N_) ? counts[idx] : 0;
    sd[t] = c;
    __syncthreads();
    #pragma unroll
    for (int off = 1; off < 256; off <<= 1){
        int o = (t >= off) ? sd[t - off] : 0;
        __syncthreads();
        sd[t] += o;
        __syncthreads();
    }
    if (idx < N_) rs[idx] = sd[t] - c;
    if (t == 255) bsum[blockIdx.x] = sd[255];
}

__global__ __launch_bounds__(256) void k_scan_block(const int* __restrict__ bsum,
                                                    int* __restrict__ boff,
                                                    int* __restrict__ rs){
    __shared__ int sd[256];
    int t = threadIdx.x;
    int v = (t < SCAN_NBLK) ? bsum[t] : 0;
    sd[t] = v;
    __syncthreads();
    #pragma unroll
    for (int off = 1; off < 256; off <<= 1){
        int o = (t >= off) ? sd[t - off] : 0;
        __syncthreads();
        sd[t] += o;
        __syncthreads();
    }
    if (t < SCAN_NBLK) boff[t] = sd[t] - v;
    if (t == 0) rs[N_] = E2_;
}

__global__ __launch_bounds__(256) void k_scan_add(int* __restrict__ rs,
                                                  const int* __restrict__ boff){
    int idx = blockIdx.x * 256 + threadIdx.x;
    if (idx < N_) rs[idx] += boff[blockIdx.x];
}

// scatter packed (src, eid) in ONE 8B store: halves dirty-cacheline traffic
__global__ void k_scatter(const int* __restrict__ ei, const int* __restrict__ rs,
                          int* __restrict__ cursor, int2* __restrict__ sedge){
    int e = blockIdx.x * blockDim.x + threadIdx.x;
    if (e >= E2_) return;
    int s, d;
    if (e < E_){ s = ei[e]; d = ei[E_ + e]; }
    else { s = e - E_; d = s; }
    int slot = rs[d] + atomicAdd(&cursor[d], 1);
    sedge[slot] = make_int2(s, e);
}

// ---------- one wave per dst node, FOUR independent edge streams, fp8 gather ----------
#define MERGE4(OFF) { \
    float mo  = __shfl_xor(m,   OFF, 64); \
    float dno = __shfl_xor(den, OFF, 64); \
    float o0=__shfl_xor(a0,OFF,64), o1=__shfl_xor(a1,OFF,64), o2=__shfl_xor(a2,OFF,64), o3=__shfl_xor(a3,OFF,64); \
    float o4=__shfl_xor(a4,OFF,64), o5=__shfl_xor(a5,OFF,64), o6=__shfl_xor(a6,OFF,64), o7=__shfl_xor(a7,OFF,64); \
    float o8=__shfl_xor(a8,OFF,64), o9=__shfl_xor(a9,OFF,64), oA=__shfl_xor(aA,OFF,64), oB=__shfl_xor(aB,OFF,64); \
    float oC=__shfl_xor(aC,OFF,64), oD=__shfl_xor(aD,OFF,64), oE=__shfl_xor(aE,OFF,64), oF=__shfl_xor(aF,OFF,64); \
    float M = fmaxf(m, mo); \
    float sS = __expf(m - M), sO = __expf(mo - M); \
    den = den*sS + dno*sO; \
    a0=a0*sS+o0*sO; a1=a1*sS+o1*sO; a2=a2*sS+o2*sO; a3=a3*sS+o3*sO; \
    a4=a4*sS+o4*sO; a5=a5*sS+o5*sO; a6=a6*sS+o6*sO; a7=a7*sS+o7*sO; \
    a8=a8*sS+o8*sO; a9=a9*sS+o9*sO; aA=aA*sS+oA*sO; aB=aB*sS+oB*sO; \
    aC=aC*sS+oC*sO; aD=aD*sS+oD*sO; aE=aE*sS+oE*sO; aF=aF*sS+oF*sO; \
    m = M; }

template<bool BF16OUT>
__global__ __launch_bounds__(256) void k_aggregate4(const unsigned char* __restrict__ hb8,
        const float* __restrict__ als, const float* __restrict__ ald,
        const float* __restrict__ ale, const float* __restrict__ alloop,
        const int* __restrict__ rs, const int2* __restrict__ sedge,
        const float* __restrict__ bias, void* __restrict__ outp){
    int n = blockIdx.x * 4 + (threadIdx.x >> 6);
    if (n >= N_) return;
    int lane = threadIdx.x & 63;
    int q  = lane >> 4;
    int sl = lane & 15;
    int col0 = sl * 16;
    int hd = sl >> 2;
    float aldn = ald[(size_t)n * 4 + hd];
    float alp  = alloop[hd];
    int i0 = rs[n], i1 = rs[n + 1];
    float m = -3.0e38f, den = 0.f;
    float a0=0.f,a1=0.f,a2=0.f,a3=0.f,a4=0.f,a5=0.f,a6=0.f,a7=0.f;
    float a8=0.f,a9=0.f,aA=0.f,aB=0.f,aC=0.f,aD=0.f,aE=0.f,aF=0.f;
    for (int i = i0 + q; i < i1; i += 4){
        int2 se = sedge[i];
        int s   = se.x;
        int eid = se.y;
        float alE = (eid < E_) ? ale[(size_t)eid * 4 + hd] : alp;
        float lg = als[(size_t)s * 4 + hd] + aldn + alE;
        lg = lrelu(lg, NEG_ATT);
        float mn = fmaxf(m, lg);
        float sc = __expf(m - mn);
        float p  = __expf(lg - mn);
        den = den * sc + p;
        uint4 g = *reinterpret_cast<const uint4*>(hb8 + (size_t)s * 256 + col0);
        float t0, t1, t2, t3;
        dec4(g.x, t0, t1, t2, t3);
        a0 = a0*sc + p*t0;  a1 = a1*sc + p*t1;  a2 = a2*sc + p*t2;  a3 = a3*sc + p*t3;
        dec4(g.y, t0, t1, t2, t3);
        a4 = a4*sc + p*t0;  a5 = a5*sc + p*t1;  a6 = a6*sc + p*t2;  a7 = a7*sc + p*t3;
        dec4(g.z, t0, t1, t2, t3);
        a8 = a8*sc + p*t0;  a9 = a9*sc + p*t1;  aA = aA*sc + p*t2;  aB = aB*sc + p*t3;
        dec4(g.w, t0, t1, t2, t3);
        aC = aC*sc + p*t0;  aD = aD*sc + p*t1;  aE = aE*sc + p*t2;  aF = aF*sc + p*t3;
        m = mn;
    }
    MERGE4(16)
    MERGE4(32)
    float inv = 1.f / den;
    float v0, v1, v2, v3;
    if      (q == 0){ v0 = a0; v1 = a1; v2 = a2; v3 = a3; }
    else if (q == 1){ v0 = a4; v1 = a5; v2 = a6; v3 = a7; }
    else if (q == 2){ v0 = a8; v1 = a9; v2 = aA; v3 = aB; }
    else            { v0 = aC; v1 = aD; v2 = aE; v3 = aF; }
    int wc = col0 + q * 4;
    float4 b4 = *reinterpret_cast<const float4*>(bias + wc);
    float r0 = lrelu(v0 * inv + b4.x, NEG_OUT);
    float r1 = lrelu(v1 * inv + b4.y, NEG_OUT);
    float r2 = lrelu(v2 * inv + b4.z, NEG_OUT);
    float r3 = lrelu(v3 * inv + b4.w, NEG_OUT);
    if (BF16OUT){
        ushort4 pk;
        pk.x = bf16rne(r0); pk.y = bf16rne(r1); pk.z = bf16rne(r2); pk.w = bf16rne(r3);
        *reinterpret_cast<ushort4*>((unsigned short*)outp + (size_t)n * 256 + wc) = pk;
    } else {
        *reinterpret_cast<float4*>((float*)outp + (size_t)n * 256 + wc) =
            make_float4(r0, r1, r2, r3);
    }
}

// ---------- edge_index passthrough (fp32, bit-exact) ----------
__global__ void k_edge_store(const int* __restrict__ ei, float* __restrict__ out){
    int j = blockIdx.x * blockDim.x + threadIdx.x;     // 2E
    if (j >= (int)OUT1) return;
    out[j] = (float)ei[j];
}

extern "C" void kernel_launch(void* const* d_in, const int* in_sizes, int n_in,
                              void* d_out, int out_size, void* d_ws, size_t ws_size,
                              hipStream_t stream){
    const float* x    = (const float*)d_in[0];
    const int*   ei   = (const int*)d_in[1];
    const float* ea   = (const float*)d_in[2];
    const float* bn1g = (const float*)d_in[3];
    const float* bn1b = (const float*)d_in[4];
    const float* W1   = (const float*)d_in[5];
    const float* We1  = (const float*)d_in[6];
    const float* as1  = (const float*)d_in[7];
    const float* ad1  = (const float*)d_in[8];
    const float* ae1  = (const float*)d_in[9];
    const float* b1   = (const float*)d_in[10];
    const float* bn2g = (const float*)d_in[11];
    const float* bn2b = (const float*)d_in[12];
    const float* W2   = (const float*)d_in[13];
    const float* We2  = (const float*)d_in[14];
    const float* as2  = (const float*)d_in[15];
    const float* ad2  = (const float*)d_in[16];
    const float* ae2  = (const float*)d_in[17];
    const float* b2   = (const float*)d_in[18];
    float* out = (float*)d_out;

    bool ok = (n_in >= 19)
           && (in_sizes[0] == N_ * FIN)
           && (in_sizes[1] == 2 * E_)
           && (in_sizes[2] == E_ * 16)
           && (out_size == (int)(OUT0 + OUT1));
    if (!ok){ k_sentinel<<<1,1,0,stream>>>(out, 7777.f); return; }

    char* w = (char*)d_ws;
    size_t off = 0;
    auto alloc = [&](size_t bytes) -> void* {
        off = (off + 255) & ~(size_t)255;
        void* p = w + off;
        off += bytes;
        return p;
    };
    float* stats  = (float*)alloc(512 * 4);
    float* asum   = (float*)alloc(16 * 4);
    float* apart  = (float*)alloc((size_t)ATTR_NBLK * 16 * 4);   // 64KB
    float* Vbuf   = (float*)alloc(64 * 4);
    float* alloop = (float*)alloc(4 * 4);
    float* als    = (float*)alloc((size_t)N_ * 4 * 4);
    float* ald    = (float*)alloc((size_t)N_ * 4 * 4);
    float* ale    = (float*)alloc((size_t)E_ * 4 * 4);          // 12.8MB
    int*   rs     = (int*)alloc((size_t)(N_ + 1) * 4);
    int*   counts = (int*)alloc((size_t)N_ * 4);
    int*   cursor = (int*)alloc((size_t)N_ * 4);
    int*   bsum   = (int*)alloc((size_t)SCAN_NBLK * 4);
    int*   boff   = (int*)alloc((size_t)SCAN_NBLK * 4);
    int2*  sedge  = (int2*)alloc((size_t)E2_ * 8);               // 6.8MB packed (src,eid)
    unsigned short* WT1 = (unsigned short*)alloc((size_t)256 * FIN * 2);  // 64KB
    unsigned short* WT2 = (unsigned short*)alloc((size_t)256 * FH * 2);   // 128KB
    unsigned short* bufC = (unsigned short*)alloc((size_t)N_ * 256 * 2);  // 25.6MB bf16
    unsigned short* hbuf = (unsigned short*)alloc((size_t)N_ * 256 * 2);  // 25.6MB bf16
    unsigned char*  hbuf8 = (unsigned char*)alloc((size_t)N_ * 256);      // 12.8MB fp8
    unsigned short* bufB = (unsigned short*)alloc((size_t)N_ * 256 * 2);  // 25.6MB bf16
    if (off > ws_size){ k_sentinel<<<1,1,0,stream>>>(out, 5555.f); return; }

    float* ssum = stats;
    float* ssq  = stats + 256;
    const int GX = cdiv(N_, 64);    // 782

    // ---- CSR build (shared by both layers) ----
    k_zero32<<<cdiv(N_,256),256,0,stream>>>((unsigned*)counts, N_);
    k_zero32<<<cdiv(N_,256),256,0,stream>>>((unsigned*)cursor, N_);
    k_count<<<cdiv(E2_,256),256,0,stream>>>(ei, counts);
    k_scan_local<<<SCAN_NBLK,256,0,stream>>>(counts, rs, bsum);
    k_scan_block<<<1,256,0,stream>>>(bsum, boff, rs);
    k_scan_add<<<SCAN_NBLK,256,0,stream>>>(rs, boff);
    k_scatter<<<cdiv(E2_,256),256,0,stream>>>(ei, rs, cursor, sedge);

    // ---- shared precompute ----
    k_zero32<<<2,256,0,stream>>>((unsigned*)stats, 512);
    k_attr_sum<<<ATTR_NBLK,256,0,stream>>>(ea, apart);
    k_attr_fin<<<1,256,0,stream>>>(apart, asum);
    k_w2t<<<FIN,256,0,stream>>>(W1, WT1, FIN);
    k_w2t<<<FH,256,0,stream>>>(W2, WT2, FH);

    // ---- BN1 + lrelu (fp32 -> bf16) ----
    k_bn_stats<<<256,256,0,stream>>>(x, FIN, ssum, ssq);
    k_bn_apply_bf<<<2048,256,0,stream>>>(x, ssum, ssq, bn1g, bn1b, bufC, FIN);

    // ---- GAT layer 1 ----
    k_gemm_mfma<<<dim3(GX,4),256,0,stream>>>(bufC, WT1, hbuf, N_, FIN);
    k_h2fp8<<<2048,256,0,stream>>>(hbuf, (unsigned*)hbuf8);
    k_al<<<cdiv(N_,4),256,0,stream>>>(hbuf, as1, ad1, als, ald);
    k_prep<<<1,64,0,stream>>>(We1, ae1, asum, Vbuf, alloop);
    k_al_edge<<<cdiv(E_*4,256),256,0,stream>>>(ea, Vbuf, ale);
    k_aggregate4<true><<<cdiv(N_,4),256,0,stream>>>(hbuf8, als, ald, ale, alloop,
                                                    rs, sedge, b1, bufB);

    // ---- BN2 + lrelu (bf16 -> bf16) ----
    k_zero32<<<2,256,0,stream>>>((unsigned*)stats, 512);
    k_bn_stats_b16<<<256,256,0,stream>>>(bufB, FH, ssum, ssq);
    k_bn_apply_b16<<<2048,256,0,stream>>>(bufB, ssum, ssq, bn2g, bn2b, bufC, FH);

    // ---- GAT layer 2 ----
    k_gemm_mfma<<<dim3(GX,4),256,0,stream>>>(bufC, WT2, hbuf, N_, FH);
    k_h2fp8<<<2048,256,0,stream>>>(hbuf, (unsigned*)hbuf8);
    k_al<<<cdiv(N_,4),256,0,stream>>>(hbuf, as2, ad2, als, ald);
    k_prep<<<1,64,0,stream>>>(We2, ae2, asum, Vbuf, alloop);
    k_al_edge<<<cdiv(E_*4,256),256,0,stream>>>(ea, Vbuf, ale);
    k_aggregate4<false><<<cdiv(N_,4),256,0,stream>>>(hbuf8, als, ald, ale, alloop,
                                                     rs, sedge, b2, out);

    // ---- edge_index passthrough ----
    k_edge_store<<<cdiv((int)OUT1,256),256,0,stream>>>(ei, out + OUT0);
}